// Round 2
// baseline (1026.217 us; speedup 1.0000x reference)
//
#include <hip/hip_runtime.h>
#include <hip/hip_bf16.h>

// AutoCorrelation layer: QKV proj (bf16x3 MFMA GEMM) -> packed FFT cross-corr
// -> top-8 + softmax -> delay-gather of V -> output proj.
// B=4, L=4096, D_MODEL=512, NHEAD=8, DH=64, TOPK=8.

#define MiB (1024ull * 1024ull)

typedef __attribute__((ext_vector_type(8))) short bf16x8;
typedef __attribute__((ext_vector_type(4))) float f32x4;
static_assert(sizeof(bf16x8) == 16, "bf16x8 must be 16B");

__device__ __forceinline__ unsigned short f2bf(float f) {
  unsigned u = __float_as_uint(f);
  unsigned r = (u + 0x7FFFu + ((u >> 16) & 1u)) >> 16;  // RN-even
  return (unsigned short)r;
}
__device__ __forceinline__ float bf2f(unsigned short h) {
  return __uint_as_float(((unsigned)h) << 16);
}
// base-4 digit reversal of a 12-bit index (involution)
__device__ __forceinline__ int rev4_12(int x) {
  unsigned r = __brev((unsigned)x) >> 20;
  return (int)(((r & 0xAAAu) >> 1) | ((r & 0x555u) << 1));
}
// LDS pad: +1 float per 32 to break power-of-2 bank patterns
#define IDX(e) ((e) + ((e) >> 5))
#define LDSN (4095 + (4095 >> 5) + 1)

// ---------------- conversion kernels ----------------

// x (f32) -> hi/lo bf16 split (A = hi + lo exactly to ~16 mantissa bits)
__global__ void conv_split(const float* __restrict__ x, unsigned short* __restrict__ hi,
                           unsigned short* __restrict__ lo, int n4) {
  int i = blockIdx.x * 256 + threadIdx.x;
  if (i >= n4) return;
  float4 v = ((const float4*)x)[i];
  ushort4 h, l;
  float f;
  f = v.x; h.x = f2bf(f); l.x = f2bf(f - bf2f(h.x));
  f = v.y; h.y = f2bf(f); l.y = f2bf(f - bf2f(h.y));
  f = v.z; h.z = f2bf(f); l.z = f2bf(f - bf2f(h.z));
  f = v.w; h.w = f2bf(f); l.w = f2bf(f - bf2f(h.w));
  ((ushort4*)hi)[i] = h;
  ((ushort4*)lo)[i] = l;
}

// W (512x512 f32, [k][n]) -> transposed hi/lo bf16 Wt[n][k]
__global__ void conv_wt(const float* __restrict__ W, unsigned short* __restrict__ hi,
                        unsigned short* __restrict__ lo) {
  int idx = blockIdx.x * 256 + threadIdx.x;  // 262144
  int n = idx >> 9, k = idx & 511;
  float f = W[k * 512 + n];
  unsigned short h = f2bf(f);
  hi[idx] = h;
  lo[idx] = f2bf(f - bf2f(h));
}

// twiddle table T[r] = exp(-2*pi*i*r/4096), r=0..3071 (double-precision generated)
__global__ void make_tw(float2* __restrict__ T) {
  int r = blockIdx.x * 256 + threadIdx.x;
  if (r < 3072) {
    double a = -2.0 * 3.14159265358979323846 * (double)r / 4096.0;
    T[r] = make_float2((float)cos(a), (float)sin(a));
  }
}

// ---------------- GEMM: C(16384x512) = A(16384x512) @ W(512x512) + bias ----------------
// bf16x3 split: segments [Ahi*Bhi, Ahi*Blo, Alo*Bhi] (nseg=3) or plain hi*hi (nseg=1).
// B is pre-transposed: Bt[n][k]. 128x128 tile, BK=64, 4 waves (2x2), mfma 16x16x32.
// mode 0: C[(b*512+n)*4096 + t]   (Q^T/K^T layout, float4 stores along t)
// mode 1: C[((b*8+h)*4096+t)*64+d] (V layout, n = h*64+d)
// mode 2: C[m*512+n]               (row-major output)
__global__ __launch_bounds__(256, 2)
void gemm_bf16(const unsigned short* __restrict__ Ahi, const unsigned short* __restrict__ Alo,
               const unsigned short* __restrict__ Bhi, const unsigned short* __restrict__ Blo,
               const float* __restrict__ bias, float* __restrict__ C,
               int nseg, int mode) {
  __shared__ short As[128 * 64];
  __shared__ short Bs[128 * 64];
  int bx = blockIdx.x;
  int bm = bx >> 2, bn = bx & 3;
  int m0 = bm << 7, n0 = bn << 7;
  int tid = threadIdx.x;
  int lane = tid & 63, wv = tid >> 6;
  int wm = wv >> 1, wn = wv & 1;

  const f32x4 zz = {0.f, 0.f, 0.f, 0.f};
  f32x4 acc[4][4];
#pragma unroll
  for (int i = 0; i < 4; ++i)
#pragma unroll
    for (int j = 0; j < 4; ++j) acc[i][j] = zz;

  int srow = tid >> 3;          // 0..31 (row within 32-row chunk)
  int sk = (tid & 7) << 3;      // 0..56 (k offset, 8 elems = 16B)
  int nks = nseg << 3;          // K-steps of 64 within each 512-segment
  for (int ks = 0; ks < nks; ++ks) {
    int seg = ks >> 3;
    int kb = (ks & 7) << 6;
    const unsigned short* Aseg = (seg == 2) ? Alo : Ahi;
    const unsigned short* Bseg = (seg == 1) ? Blo : Bhi;
#pragma unroll
    for (int i = 0; i < 4; ++i) {
      int r = (i << 5) + srow;
      const unsigned short* ga = Aseg + (size_t)(m0 + r) * 512 + kb + sk;
      const unsigned short* gb = Bseg + (size_t)(n0 + r) * 512 + kb + sk;
      char* la = (char*)As + (i << 12) + (wv << 10);  // wave-uniform LDS base
      char* lb = (char*)Bs + (i << 12) + (wv << 10);
      __builtin_amdgcn_global_load_lds((const __attribute__((address_space(1))) void*)ga,
                                       (__attribute__((address_space(3))) void*)la, 16, 0, 0);
      __builtin_amdgcn_global_load_lds((const __attribute__((address_space(1))) void*)gb,
                                       (__attribute__((address_space(3))) void*)lb, 16, 0, 0);
    }
    __syncthreads();
#pragma unroll
    for (int kk = 0; kk < 2; ++kk) {
      bf16x8 af[4], bfr[4];
      int krd = (kk << 5) + ((lane >> 4) << 3);
#pragma unroll
      for (int mi = 0; mi < 4; ++mi)
        af[mi] = *(const bf16x8*)&As[((wm << 6) + (mi << 4) + (lane & 15)) * 64 + krd];
#pragma unroll
      for (int ni = 0; ni < 4; ++ni)
        bfr[ni] = *(const bf16x8*)&Bs[((wn << 6) + (ni << 4) + (lane & 15)) * 64 + krd];
#pragma unroll
      for (int mi = 0; mi < 4; ++mi)
#pragma unroll
        for (int ni = 0; ni < 4; ++ni)
          acc[mi][ni] = __builtin_amdgcn_mfma_f32_16x16x32_bf16(af[mi], bfr[ni], acc[mi][ni], 0, 0, 0);
    }
    __syncthreads();
  }

  // epilogue: D lane l reg r -> row=(l>>4)*4+r, col=l&15 (per 16x16 fragment)
#pragma unroll
  for (int mi = 0; mi < 4; ++mi) {
    int mrow0 = m0 + (wm << 6) + (mi << 4) + ((lane >> 4) << 2);
    int bq = mrow0 >> 12;
    int t0 = mrow0 & 4095;
#pragma unroll
    for (int ni = 0; ni < 4; ++ni) {
      int col = n0 + (wn << 6) + (ni << 4) + (lane & 15);
      float bv = bias[col];
      f32x4 v = acc[mi][ni];
      v.x += bv; v.y += bv; v.z += bv; v.w += bv;
      if (mode == 0) {
        *(f32x4*)&C[((size_t)(bq * 512 + col)) * 4096 + t0] = v;
      } else if (mode == 1) {
        size_t base = (size_t)(bq * 8 + (col >> 6)) * 4096;
        int d = col & 63;
        C[(base + t0 + 0) * 64 + d] = v.x;
        C[(base + t0 + 1) * 64 + d] = v.y;
        C[(base + t0 + 2) * 64 + d] = v.z;
        C[(base + t0 + 3) * 64 + d] = v.w;
      } else {
        C[(size_t)(mrow0 + 0) * 512 + col] = v.x;
        C[(size_t)(mrow0 + 1) * 512 + col] = v.y;
        C[(size_t)(mrow0 + 2) * 512 + col] = v.z;
        C[(size_t)(mrow0 + 3) * 512 + col] = v.w;
      }
    }
  }
}

// ---------------- FFT: 6-stage radix-4 DIF (natural in -> digit-reversed out) ----------------
__device__ void dif_fft(float* re, float* im, const float2* __restrict__ TW, int tid) {
  int m = 1024, lm = 10;
#pragma unroll
  for (int s = 0; s < 6; ++s) {
    int stw = 1 << (2 * s);
    for (int bb = tid; bb < 1024; bb += 256) {
      int j = bb & (m - 1);
      int g = bb >> lm;
      int i0 = (g << (lm + 2)) + j;
      int p0 = IDX(i0), p1 = IDX(i0 + m), p2 = IDX(i0 + 2 * m), p3 = IDX(i0 + 3 * m);
      float are = re[p0], aim = im[p0];
      float cre = re[p1], cim = im[p1];
      float ere = re[p2], eim = im[p2];
      float gre = re[p3], gim = im[p3];
      float Are = are + ere, Aim = aim + eim;
      float Bre = are - ere, Bim = aim - eim;
      float Cre = cre + gre, Cim = cim + gim;
      float dre = cre - gre, dim_ = cim - gim;
      float Dre = dim_, Dim = -dre;  // -i*(c-g)
      re[p0] = Are + Cre; im[p0] = Aim + Cim;
      float2 w1 = TW[j * stw], w2 = TW[2 * j * stw], w3 = TW[3 * j * stw];
      float xr = Bre + Dre, xi = Bim + Dim;
      re[p1] = xr * w1.x - xi * w1.y; im[p1] = xr * w1.y + xi * w1.x;
      xr = Are - Cre; xi = Aim - Cim;
      re[p2] = xr * w2.x - xi * w2.y; im[p2] = xr * w2.y + xi * w2.x;
      xr = Bre - Dre; xi = Bim - Dim;
      re[p3] = xr * w3.x - xi * w3.y; im[p3] = xr * w3.y + xi * w3.x;
    }
    __syncthreads();
    m >>= 2; lm -= 2;
  }
}

// Packed FFT of z = q + i*k for ONE (b,h,d); extract Qf*conj(Kf) and atomicAdd
// into P[b,h,f]. One workgroup per (b,h,d) -> 2048 wgs, 33.8 KB LDS, 4 blocks/CU.
__global__ __launch_bounds__(256, 4)
void fft_corr(const float* __restrict__ QT, const float* __restrict__ KT,
              const float2* __restrict__ TW, float* __restrict__ Pre, float* __restrict__ Pim) {
  __shared__ float re[LDSN];
  __shared__ float im[LDSN];
  int wg = blockIdx.x;        // 2048 = 32 (b,h) x 64 d
  int bh = wg >> 6;
  int d = wg & 63;
  int tid = threadIdx.x;
  const float* q = QT + ((size_t)bh * 64 + d) * 4096;
  const float* k = KT + ((size_t)bh * 64 + d) * 4096;
  for (int e = tid; e < 4096; e += 256) {
    re[IDX(e)] = q[e];
    im[IDX(e)] = k[e];
  }
  __syncthreads();
  dif_fft(re, im, TW, tid);
  // position p holds Z[f], f = rev4(p); pair with f' = (N-f)%N at position rev4(f')
  float* PreB = Pre + (size_t)bh * 4096;
  float* PimB = Pim + (size_t)bh * 4096;
  for (int p = tid; p < 4096; p += 256) {
    int f = rev4_12(p);
    int fn = (4096 - f) & 4095;
    int pn = rev4_12(fn);
    float zr = re[IDX(p)], zi = im[IDX(p)];
    float wr = re[IDX(pn)], wi = im[IDX(pn)];
    float qre = 0.5f * (zr + wr), qim = 0.5f * (zi - wi);
    float kre = 0.5f * (zi + wi), kim = 0.5f * (wr - zr);
    atomicAdd(&PreB[f], qre * kre + qim * kim);   // Re(Qf*conj(Kf))
    atomicAdd(&PimB[f], qim * kre - qre * kim);   // Im(Qf*conj(Kf))
  }
}

// Inverse FFT via conj + forward DIF; corr(tau=rev4(p)) = re[p]/(4096*64). Then top-8 + softmax.
__global__ __launch_bounds__(256, 2)
void ifft_topk(const float* __restrict__ Pre, const float* __restrict__ Pim,
               const float2* __restrict__ TW, float* __restrict__ attnW, int* __restrict__ delays) {
  __shared__ float re[LDSN];
  __shared__ float im[LDSN];
  __shared__ float sval[256];
  __shared__ int sidx[256];
  __shared__ int spos[256];
  int bh = blockIdx.x, tid = threadIdx.x;
  for (int e = tid; e < 4096; e += 256) {
    re[IDX(e)] = Pre[bh * 4096 + e];
    im[IDX(e)] = -Pim[bh * 4096 + e];  // conj
  }
  __syncthreads();
  dif_fft(re, im, TW, tid);
  const float SC = 1.0f / 262144.0f;  // 1/(L*Dh)
  float topv[8]; int topi[8];
  for (int pass = 0; pass < 8; ++pass) {
    float bv = -3.4e38f; int bi = 1 << 30; int bp = 0;
    for (int p = tid; p < 4096; p += 256) {
      float v = re[IDX(p)];
      int tau = rev4_12(p);
      if (v > bv || (v == bv && tau < bi)) { bv = v; bi = tau; bp = p; }
    }
    sval[tid] = bv; sidx[tid] = bi; spos[tid] = bp;
    __syncthreads();
    for (int off = 128; off > 0; off >>= 1) {
      if (tid < off) {
        float ov = sval[tid + off]; int oi = sidx[tid + off];
        if (ov > sval[tid] || (ov == sval[tid] && oi < sidx[tid])) {
          sval[tid] = ov; sidx[tid] = oi; spos[tid] = spos[tid + off];
        }
      }
      __syncthreads();
    }
    topv[pass] = sval[0] * SC;
    topi[pass] = sidx[0];
    if (tid == 0) re[IDX(spos[0])] = -3.4e38f;
    __syncthreads();
  }
  if (tid == 0) {
    float mx = topv[0];  // pass 0 = global max
    float ex[8], s = 0.f;
    for (int k = 0; k < 8; ++k) { ex[k] = expf(topv[k] - mx); s += ex[k]; }
    float inv = 1.0f / s;
    for (int k = 0; k < 8; ++k) {
      attnW[bh * 8 + k] = ex[k] * inv;
      delays[bh * 8 + k] = topi[k];
    }
  }
}

// out[b,h,t,:] = sum_k attn_k * V[b,h,(t-d_k)%L,:]; write bf16 into final-GEMM A layout.
__global__ void gather_av(const float* __restrict__ V, const float* __restrict__ attnW,
                          const int* __restrict__ delays, unsigned short* __restrict__ Ahi) {
  int blk = blockIdx.x;
  int bh = blk >> 8, tb = blk & 255;
  int tid = threadIdx.x;
  int tt = tid >> 4, dq = tid & 15;
  int t = (tb << 4) + tt;
  const float4* Vb = (const float4*)(V + (size_t)bh * 4096 * 64);
  float4 acc = make_float4(0.f, 0.f, 0.f, 0.f);
#pragma unroll
  for (int kk = 0; kk < 8; ++kk) {
    float w = attnW[bh * 8 + kk];
    int dl = delays[bh * 8 + kk];
    int row = (t - dl) & 4095;
    float4 x = Vb[row * 16 + dq];
    acc.x += w * x.x; acc.y += w * x.y; acc.z += w * x.z; acc.w += w * x.w;
  }
  int b = bh >> 3, h = bh & 7;
  size_t o = ((size_t)((b << 12) + t)) * 512 + (h << 6) + (dq << 2);
  ushort4 hv;
  hv.x = f2bf(acc.x); hv.y = f2bf(acc.y); hv.z = f2bf(acc.z); hv.w = f2bf(acc.w);
  *(ushort4*)(Ahi + o) = hv;
}

// ---------------- orchestration ----------------
extern "C" void kernel_launch(void* const* d_in, const int* in_sizes, int n_in,
                              void* d_out, int out_size, void* d_ws, size_t ws_size,
                              hipStream_t stream) {
  (void)in_sizes; (void)n_in; (void)out_size; (void)ws_size;
  const float* x_q = (const float*)d_in[0];
  const float* x_kv = (const float*)d_in[1];
  const float* Wq = (const float*)d_in[2];
  const float* bq = (const float*)d_in[3];
  const float* Wk = (const float*)d_in[4];
  const float* bk = (const float*)d_in[5];
  const float* Wv = (const float*)d_in[6];
  const float* bv = (const float*)d_in[7];
  const float* Wo = (const float*)d_in[8];
  const float* bo = (const float*)d_in[9];
  float* out = (float*)d_out;
  char* ws = (char*)d_ws;

  // workspace layout (regions reused over the pipeline; total ~137.1 MiB)
  unsigned short* AqHi  = (unsigned short*)(ws + 0 * MiB);
  unsigned short* AqLo  = (unsigned short*)(ws + 16 * MiB);
  float*          Vbuf  = (float*)(ws + 0 * MiB);          // reuses Aq region after GEMM-Q
  unsigned short* AkvHi = (unsigned short*)(ws + 36 * MiB);
  unsigned short* AkvLo = (unsigned short*)(ws + 52 * MiB);
  unsigned short* Aattn = (unsigned short*)(ws + 36 * MiB); // reuses Akv region after GEMM-V
  unsigned short* WTb   = (unsigned short*)(ws + 68 * MiB); // 8 x 512x512 bf16
  float* QT    = (float*)(ws + 72 * MiB);
  float* KT    = (float*)(ws + 104 * MiB);
  float* PreB  = (float*)(ws + 136 * MiB);
  float* PimB  = (float*)(ws + 136 * MiB + 524288);
  float* attnW = (float*)(ws + 137 * MiB);
  int*   delays = (int*)(ws + 137 * MiB + 4096);
  float2* TW   = (float2*)(ws + 137 * MiB + 8192);

  int n4 = (16384 * 512) / 4;
  conv_split<<<dim3(n4 / 256), dim3(256), 0, stream>>>(x_q, AqHi, AqLo, n4);
  conv_split<<<dim3(n4 / 256), dim3(256), 0, stream>>>(x_kv, AkvHi, AkvLo, n4);
  conv_wt<<<dim3(1024), dim3(256), 0, stream>>>(Wq, WTb + 0 * 262144, WTb + 1 * 262144);
  conv_wt<<<dim3(1024), dim3(256), 0, stream>>>(Wk, WTb + 2 * 262144, WTb + 3 * 262144);
  conv_wt<<<dim3(1024), dim3(256), 0, stream>>>(Wv, WTb + 4 * 262144, WTb + 5 * 262144);
  conv_wt<<<dim3(1024), dim3(256), 0, stream>>>(Wo, WTb + 6 * 262144, WTb + 7 * 262144);
  make_tw<<<dim3(12), dim3(256), 0, stream>>>(TW);
  hipMemsetAsync(PreB, 0, 2 * 524288, stream);

  // Q = x_q @ Wq (bf16x3, -> Q^T layout), K likewise, V plain bf16 (-> (b,h,t,d))
  gemm_bf16<<<dim3(512), dim3(256), 0, stream>>>(AqHi, AqLo, WTb + 0 * 262144, WTb + 1 * 262144, bq, QT, 3, 0);
  gemm_bf16<<<dim3(512), dim3(256), 0, stream>>>(AkvHi, AkvLo, WTb + 2 * 262144, WTb + 3 * 262144, bk, KT, 3, 0);
  gemm_bf16<<<dim3(512), dim3(256), 0, stream>>>(AkvHi, AkvLo, WTb + 4 * 262144, WTb + 5 * 262144, bv, Vbuf, 1, 1);

  fft_corr<<<dim3(2048), dim3(256), 0, stream>>>(QT, KT, TW, PreB, PimB);
  ifft_topk<<<dim3(32), dim3(256), 0, stream>>>(PreB, PimB, TW, attnW, delays);
  gather_av<<<dim3(8192), dim3(256), 0, stream>>>(Vbuf, attnW, delays, Aattn);

  // out = gathered @ Wo + bo (plain bf16)
  gemm_bf16<<<dim3(512), dim3(256), 0, stream>>>(Aattn, Aattn, WTb + 6 * 262144, WTb + 7 * 262144, bo, out, 1, 2);
}

// Round 3
// 280.334 us; speedup vs baseline: 3.6607x; 3.6607x over previous
//
#include <hip/hip_runtime.h>
#include <hip/hip_bf16.h>

// AutoCorrelation layer: QKV proj (bf16x3 MFMA GEMM) -> packed FFT cross-corr
// (partials + fused reduce, NO global atomics) -> top-8 + softmax -> delay-gather
// of V -> output proj.  B=4, L=4096, D_MODEL=512, NHEAD=8, DH=64, TOPK=8.

#define MiB (1024ull * 1024ull)

typedef __attribute__((ext_vector_type(8))) short bf16x8;
typedef __attribute__((ext_vector_type(4))) float f32x4;
static_assert(sizeof(bf16x8) == 16, "bf16x8 must be 16B");

__device__ __forceinline__ unsigned short f2bf(float f) {
  unsigned u = __float_as_uint(f);
  unsigned r = (u + 0x7FFFu + ((u >> 16) & 1u)) >> 16;  // RN-even
  return (unsigned short)r;
}
__device__ __forceinline__ float bf2f(unsigned short h) {
  return __uint_as_float(((unsigned)h) << 16);
}
// base-4 digit reversal of a 12-bit index (involution)
__device__ __forceinline__ int rev4_12(int x) {
  unsigned r = __brev((unsigned)x) >> 20;
  return (int)(((r & 0xAAAu) >> 1) | ((r & 0x555u) << 1));
}
// LDS pad: +1 float per 32 to break power-of-2 bank patterns
#define IDX(e) ((e) + ((e) >> 5))
#define LDSN (4095 + (4095 >> 5) + 1)

// ---------------- conversion kernels ----------------

// x (f32) -> hi/lo bf16 split (A = hi + lo exactly to ~16 mantissa bits)
__global__ void conv_split(const float* __restrict__ x, unsigned short* __restrict__ hi,
                           unsigned short* __restrict__ lo, int n4) {
  int i = blockIdx.x * 256 + threadIdx.x;
  if (i >= n4) return;
  float4 v = ((const float4*)x)[i];
  ushort4 h, l;
  float f;
  f = v.x; h.x = f2bf(f); l.x = f2bf(f - bf2f(h.x));
  f = v.y; h.y = f2bf(f); l.y = f2bf(f - bf2f(h.y));
  f = v.z; h.z = f2bf(f); l.z = f2bf(f - bf2f(h.z));
  f = v.w; h.w = f2bf(f); l.w = f2bf(f - bf2f(h.w));
  ((ushort4*)hi)[i] = h;
  ((ushort4*)lo)[i] = l;
}

// W (512x512 f32, [k][n]) -> transposed hi/lo bf16 Wt[n][k]
__global__ void conv_wt(const float* __restrict__ W, unsigned short* __restrict__ hi,
                        unsigned short* __restrict__ lo) {
  int idx = blockIdx.x * 256 + threadIdx.x;  // 262144
  int n = idx >> 9, k = idx & 511;
  float f = W[k * 512 + n];
  unsigned short h = f2bf(f);
  hi[idx] = h;
  lo[idx] = f2bf(f - bf2f(h));
}

// twiddle table T[r] = exp(-2*pi*i*r/4096), r=0..3071 (double-precision generated)
__global__ void make_tw(float2* __restrict__ T) {
  int r = blockIdx.x * 256 + threadIdx.x;
  if (r < 3072) {
    double a = -2.0 * 3.14159265358979323846 * (double)r / 4096.0;
    T[r] = make_float2((float)cos(a), (float)sin(a));
  }
}

// ---------------- GEMM: C(16384x512) = A(16384x512) @ W(512x512) + bias ----------------
// bf16x3 split: segments [Ahi*Bhi, Ahi*Blo, Alo*Bhi] (nseg=3) or plain hi*hi (nseg=1).
// B is pre-transposed: Bt[n][k]. 128x128 tile, BK=64, 4 waves (2x2), mfma 16x16x32.
// mode 0: C[(b*512+n)*4096 + t]   (Q^T/K^T layout, float4 stores along t)
// mode 1: C[((b*8+h)*4096+t)*64+d] (V layout, n = h*64+d)
// mode 2: C[m*512+n]               (row-major output)
__global__ __launch_bounds__(256, 2)
void gemm_bf16(const unsigned short* __restrict__ Ahi, const unsigned short* __restrict__ Alo,
               const unsigned short* __restrict__ Bhi, const unsigned short* __restrict__ Blo,
               const float* __restrict__ bias, float* __restrict__ C,
               int nseg, int mode) {
  __shared__ short As[128 * 64];
  __shared__ short Bs[128 * 64];
  int bx = blockIdx.x;
  int bm = bx >> 2, bn = bx & 3;
  int m0 = bm << 7, n0 = bn << 7;
  int tid = threadIdx.x;
  int lane = tid & 63, wv = tid >> 6;
  int wm = wv >> 1, wn = wv & 1;

  const f32x4 zz = {0.f, 0.f, 0.f, 0.f};
  f32x4 acc[4][4];
#pragma unroll
  for (int i = 0; i < 4; ++i)
#pragma unroll
    for (int j = 0; j < 4; ++j) acc[i][j] = zz;

  int srow = tid >> 3;          // 0..31 (row within 32-row chunk)
  int sk = (tid & 7) << 3;      // 0..56 (k offset, 8 elems = 16B)
  int nks = nseg << 3;          // K-steps of 64 within each 512-segment
  for (int ks = 0; ks < nks; ++ks) {
    int seg = ks >> 3;
    int kb = (ks & 7) << 6;
    const unsigned short* Aseg = (seg == 2) ? Alo : Ahi;
    const unsigned short* Bseg = (seg == 1) ? Blo : Bhi;
#pragma unroll
    for (int i = 0; i < 4; ++i) {
      int r = (i << 5) + srow;
      const unsigned short* ga = Aseg + (size_t)(m0 + r) * 512 + kb + sk;
      const unsigned short* gb = Bseg + (size_t)(n0 + r) * 512 + kb + sk;
      char* la = (char*)As + (i << 12) + (wv << 10);  // wave-uniform LDS base
      char* lb = (char*)Bs + (i << 12) + (wv << 10);
      __builtin_amdgcn_global_load_lds((const __attribute__((address_space(1))) void*)ga,
                                       (__attribute__((address_space(3))) void*)la, 16, 0, 0);
      __builtin_amdgcn_global_load_lds((const __attribute__((address_space(1))) void*)gb,
                                       (__attribute__((address_space(3))) void*)lb, 16, 0, 0);
    }
    __syncthreads();
#pragma unroll
    for (int kk = 0; kk < 2; ++kk) {
      bf16x8 af[4], bfr[4];
      int krd = (kk << 5) + ((lane >> 4) << 3);
#pragma unroll
      for (int mi = 0; mi < 4; ++mi)
        af[mi] = *(const bf16x8*)&As[((wm << 6) + (mi << 4) + (lane & 15)) * 64 + krd];
#pragma unroll
      for (int ni = 0; ni < 4; ++ni)
        bfr[ni] = *(const bf16x8*)&Bs[((wn << 6) + (ni << 4) + (lane & 15)) * 64 + krd];
#pragma unroll
      for (int mi = 0; mi < 4; ++mi)
#pragma unroll
        for (int ni = 0; ni < 4; ++ni)
          acc[mi][ni] = __builtin_amdgcn_mfma_f32_16x16x32_bf16(af[mi], bfr[ni], acc[mi][ni], 0, 0, 0);
    }
    __syncthreads();
  }

  // epilogue: D lane l reg r -> row=(l>>4)*4+r, col=l&15 (per 16x16 fragment)
#pragma unroll
  for (int mi = 0; mi < 4; ++mi) {
    int mrow0 = m0 + (wm << 6) + (mi << 4) + ((lane >> 4) << 2);
    int bq = mrow0 >> 12;
    int t0 = mrow0 & 4095;
#pragma unroll
    for (int ni = 0; ni < 4; ++ni) {
      int col = n0 + (wn << 6) + (ni << 4) + (lane & 15);
      float bv = bias[col];
      f32x4 v = acc[mi][ni];
      v.x += bv; v.y += bv; v.z += bv; v.w += bv;
      if (mode == 0) {
        *(f32x4*)&C[((size_t)(bq * 512 + col)) * 4096 + t0] = v;
      } else if (mode == 1) {
        size_t base = (size_t)(bq * 8 + (col >> 6)) * 4096;
        int d = col & 63;
        C[(base + t0 + 0) * 64 + d] = v.x;
        C[(base + t0 + 1) * 64 + d] = v.y;
        C[(base + t0 + 2) * 64 + d] = v.z;
        C[(base + t0 + 3) * 64 + d] = v.w;
      } else {
        C[(size_t)(mrow0 + 0) * 512 + col] = v.x;
        C[(size_t)(mrow0 + 1) * 512 + col] = v.y;
        C[(size_t)(mrow0 + 2) * 512 + col] = v.z;
        C[(size_t)(mrow0 + 3) * 512 + col] = v.w;
      }
    }
  }
}

// ---------------- FFT: 6-stage radix-4 DIF (natural in -> digit-reversed out) ----------------
__device__ void dif_fft(float* re, float* im, const float2* __restrict__ TW, int tid) {
  int m = 1024, lm = 10;
#pragma unroll
  for (int s = 0; s < 6; ++s) {
    int stw = 1 << (2 * s);
    for (int bb = tid; bb < 1024; bb += 256) {
      int j = bb & (m - 1);
      int g = bb >> lm;
      int i0 = (g << (lm + 2)) + j;
      int p0 = IDX(i0), p1 = IDX(i0 + m), p2 = IDX(i0 + 2 * m), p3 = IDX(i0 + 3 * m);
      float are = re[p0], aim = im[p0];
      float cre = re[p1], cim = im[p1];
      float ere = re[p2], eim = im[p2];
      float gre = re[p3], gim = im[p3];
      float Are = are + ere, Aim = aim + eim;
      float Bre = are - ere, Bim = aim - eim;
      float Cre = cre + gre, Cim = cim + gim;
      float dre = cre - gre, dim_ = cim - gim;
      float Dre = dim_, Dim = -dre;  // -i*(c-g)
      re[p0] = Are + Cre; im[p0] = Aim + Cim;
      float2 w1 = TW[j * stw], w2 = TW[2 * j * stw], w3 = TW[3 * j * stw];
      float xr = Bre + Dre, xi = Bim + Dim;
      re[p1] = xr * w1.x - xi * w1.y; im[p1] = xr * w1.y + xi * w1.x;
      xr = Are - Cre; xi = Aim - Cim;
      re[p2] = xr * w2.x - xi * w2.y; im[p2] = xr * w2.y + xi * w2.x;
      xr = Bre - Dre; xi = Bim - Dim;
      re[p3] = xr * w3.x - xi * w3.y; im[p3] = xr * w3.y + xi * w3.x;
    }
    __syncthreads();
    m >>= 2; lm -= 2;
  }
}

// Packed FFT of z = q + i*k per (b,h,d); one wg handles (b,h) x 4 d's, accumulating
// Qf*conj(Kf) in 32 registers, then writes its partial (indexed by LDS position p,
// coalesced) to Ppart[wg][p].  512 wgs; NO atomics.
__global__ __launch_bounds__(256, 4)
void fft_corr(const float* __restrict__ QT, const float* __restrict__ KT,
              const float2* __restrict__ TW, float* __restrict__ PpartRe,
              float* __restrict__ PpartIm) {
  __shared__ float re[LDSN];
  __shared__ float im[LDSN];
  int wg = blockIdx.x;        // 512 = 32 (b,h) x 16 parts
  int bh = wg >> 4;
  int d0 = (wg & 15) << 2;
  int tid = threadIdx.x;
  const float* qb = QT + (size_t)bh * 64 * 4096;
  const float* kb = KT + (size_t)bh * 64 * 4096;
  float accR[16], accI[16];
#pragma unroll
  for (int i = 0; i < 16; ++i) { accR[i] = 0.f; accI[i] = 0.f; }
  for (int dd = 0; dd < 4; ++dd) {
    __syncthreads();  // prior extraction reads of re/im done
    const float* q = qb + (size_t)(d0 + dd) * 4096;
    const float* k = kb + (size_t)(d0 + dd) * 4096;
    for (int e = tid; e < 4096; e += 256) {
      re[IDX(e)] = q[e];
      im[IDX(e)] = k[e];
    }
    __syncthreads();
    dif_fft(re, im, TW, tid);
    // position p holds Z[f], f = rev4(p); pair with f' = (N-f)%N at position rev4(f')
#pragma unroll
    for (int i = 0; i < 16; ++i) {
      int p = tid + (i << 8);
      int f = rev4_12(p);
      int fn = (4096 - f) & 4095;
      int pn = rev4_12(fn);
      float zr = re[IDX(p)], zi = im[IDX(p)];
      float wr = re[IDX(pn)], wi = im[IDX(pn)];
      float qre = 0.5f * (zr + wr), qim = 0.5f * (zi - wi);
      float kre = 0.5f * (zi + wi), kim = 0.5f * (wr - zr);
      accR[i] += qre * kre + qim * kim;   // Re(Qf*conj(Kf))
      accI[i] += qim * kre - qre * kim;   // Im(Qf*conj(Kf))
    }
  }
  float* pR = PpartRe + (size_t)wg * 4096;
  float* pI = PpartIm + (size_t)wg * 4096;
#pragma unroll
  for (int i = 0; i < 16; ++i) {
    int p = tid + (i << 8);
    pR[p] = accR[i];
    pI[p] = accI[i];
  }
}

// Fused reduce(16 partials) + inverse FFT (conj + forward DIF) + top-8 + softmax.
// Partials are stored by position p; natural frequency f = rev4(p) -> LDS scatter.
__global__ __launch_bounds__(256, 2)
void ifft_topk(const float* __restrict__ PpartRe, const float* __restrict__ PpartIm,
               const float2* __restrict__ TW, float* __restrict__ attnW, int* __restrict__ delays) {
  __shared__ float re[LDSN];
  __shared__ float im[LDSN];
  __shared__ float sval[256];
  __shared__ int sidx[256];
  __shared__ int spos[256];
  int bh = blockIdx.x, tid = threadIdx.x;
  const float* bR = PpartRe + (size_t)bh * 16 * 4096;
  const float* bI = PpartIm + (size_t)bh * 16 * 4096;
#pragma unroll
  for (int i = 0; i < 16; ++i) {
    int p = tid + (i << 8);
    float sr = 0.f, si = 0.f;
#pragma unroll
    for (int part = 0; part < 16; ++part) {
      sr += bR[part * 4096 + p];
      si += bI[part * 4096 + p];
    }
    int f = rev4_12(p);
    re[IDX(f)] = sr;
    im[IDX(f)] = -si;  // conj
  }
  __syncthreads();
  dif_fft(re, im, TW, tid);
  const float SC = 1.0f / 262144.0f;  // 1/(L*Dh)
  float topv[8]; int topi[8];
  for (int pass = 0; pass < 8; ++pass) {
    float bv = -3.4e38f; int bi = 1 << 30; int bp = 0;
    for (int p = tid; p < 4096; p += 256) {
      float v = re[IDX(p)];
      int tau = rev4_12(p);
      if (v > bv || (v == bv && tau < bi)) { bv = v; bi = tau; bp = p; }
    }
    sval[tid] = bv; sidx[tid] = bi; spos[tid] = bp;
    __syncthreads();
    for (int off = 128; off > 0; off >>= 1) {
      if (tid < off) {
        float ov = sval[tid + off]; int oi = sidx[tid + off];
        if (ov > sval[tid] || (ov == sval[tid] && oi < sidx[tid])) {
          sval[tid] = ov; sidx[tid] = oi; spos[tid] = spos[tid + off];
        }
      }
      __syncthreads();
    }
    topv[pass] = sval[0] * SC;
    topi[pass] = sidx[0];
    if (tid == 0) re[IDX(spos[0])] = -3.4e38f;
    __syncthreads();
  }
  if (tid == 0) {
    float mx = topv[0];  // pass 0 = global max
    float ex[8], s = 0.f;
    for (int k = 0; k < 8; ++k) { ex[k] = expf(topv[k] - mx); s += ex[k]; }
    float inv = 1.0f / s;
    for (int k = 0; k < 8; ++k) {
      attnW[bh * 8 + k] = ex[k] * inv;
      delays[bh * 8 + k] = topi[k];
    }
  }
}

// out[b,h,t,:] = sum_k attn_k * V[b,h,(t-d_k)%L,:]; write bf16 into final-GEMM A layout.
__global__ void gather_av(const float* __restrict__ V, const float* __restrict__ attnW,
                          const int* __restrict__ delays, unsigned short* __restrict__ Ahi) {
  int blk = blockIdx.x;
  int bh = blk >> 8, tb = blk & 255;
  int tid = threadIdx.x;
  int tt = tid >> 4, dq = tid & 15;
  int t = (tb << 4) + tt;
  const float4* Vb = (const float4*)(V + (size_t)bh * 4096 * 64);
  float4 acc = make_float4(0.f, 0.f, 0.f, 0.f);
#pragma unroll
  for (int kk = 0; kk < 8; ++kk) {
    float w = attnW[bh * 8 + kk];
    int dl = delays[bh * 8 + kk];
    int row = (t - dl) & 4095;
    float4 x = Vb[row * 16 + dq];
    acc.x += w * x.x; acc.y += w * x.y; acc.z += w * x.z; acc.w += w * x.w;
  }
  int b = bh >> 3, h = bh & 7;
  size_t o = ((size_t)((b << 12) + t)) * 512 + (h << 6) + (dq << 2);
  ushort4 hv;
  hv.x = f2bf(acc.x); hv.y = f2bf(acc.y); hv.z = f2bf(acc.z); hv.w = f2bf(acc.w);
  *(ushort4*)(Ahi + o) = hv;
}

// ---------------- orchestration ----------------
extern "C" void kernel_launch(void* const* d_in, const int* in_sizes, int n_in,
                              void* d_out, int out_size, void* d_ws, size_t ws_size,
                              hipStream_t stream) {
  (void)in_sizes; (void)n_in; (void)out_size; (void)ws_size;
  const float* x_q = (const float*)d_in[0];
  const float* x_kv = (const float*)d_in[1];
  const float* Wq = (const float*)d_in[2];
  const float* bq = (const float*)d_in[3];
  const float* Wk = (const float*)d_in[4];
  const float* bk = (const float*)d_in[5];
  const float* Wv = (const float*)d_in[6];
  const float* bv = (const float*)d_in[7];
  const float* Wo = (const float*)d_in[8];
  const float* bo = (const float*)d_in[9];
  float* out = (float*)d_out;
  char* ws = (char*)d_ws;

  // workspace layout (regions reused over the pipeline; total ~137.1 MiB)
  unsigned short* AqHi  = (unsigned short*)(ws + 0 * MiB);
  unsigned short* AqLo  = (unsigned short*)(ws + 16 * MiB);
  float*          Vbuf  = (float*)(ws + 0 * MiB);          // reuses Aq region after GEMM-Q
  unsigned short* AkvHi = (unsigned short*)(ws + 36 * MiB);
  unsigned short* AkvLo = (unsigned short*)(ws + 52 * MiB);
  unsigned short* Aattn = (unsigned short*)(ws + 36 * MiB); // reuses Akv region after GEMM-V
  float* PpartRe = (float*)(ws + 52 * MiB);                 // reuses AkvLo after GEMM-V (8 MiB)
  float* PpartIm = (float*)(ws + 60 * MiB);                 // (8 MiB)
  unsigned short* WTb   = (unsigned short*)(ws + 68 * MiB); // 8 x 512x512 bf16
  float* QT    = (float*)(ws + 72 * MiB);
  float* KT    = (float*)(ws + 104 * MiB);
  float* attnW = (float*)(ws + 137 * MiB);
  int*   delays = (int*)(ws + 137 * MiB + 4096);
  float2* TW   = (float2*)(ws + 137 * MiB + 8192);

  int n4 = (16384 * 512) / 4;
  conv_split<<<dim3(n4 / 256), dim3(256), 0, stream>>>(x_q, AqHi, AqLo, n4);
  conv_split<<<dim3(n4 / 256), dim3(256), 0, stream>>>(x_kv, AkvHi, AkvLo, n4);
  conv_wt<<<dim3(1024), dim3(256), 0, stream>>>(Wq, WTb + 0 * 262144, WTb + 1 * 262144);
  conv_wt<<<dim3(1024), dim3(256), 0, stream>>>(Wk, WTb + 2 * 262144, WTb + 3 * 262144);
  conv_wt<<<dim3(1024), dim3(256), 0, stream>>>(Wv, WTb + 4 * 262144, WTb + 5 * 262144);
  conv_wt<<<dim3(1024), dim3(256), 0, stream>>>(Wo, WTb + 6 * 262144, WTb + 7 * 262144);
  make_tw<<<dim3(12), dim3(256), 0, stream>>>(TW);

  // Q = x_q @ Wq (bf16x3, -> Q^T layout), K likewise, V plain bf16 (-> (b,h,t,d))
  gemm_bf16<<<dim3(512), dim3(256), 0, stream>>>(AqHi, AqLo, WTb + 0 * 262144, WTb + 1 * 262144, bq, QT, 3, 0);
  gemm_bf16<<<dim3(512), dim3(256), 0, stream>>>(AkvHi, AkvLo, WTb + 2 * 262144, WTb + 3 * 262144, bk, KT, 3, 0);
  gemm_bf16<<<dim3(512), dim3(256), 0, stream>>>(AkvHi, AkvLo, WTb + 4 * 262144, WTb + 5 * 262144, bv, Vbuf, 1, 1);

  fft_corr<<<dim3(512), dim3(256), 0, stream>>>(QT, KT, TW, PpartRe, PpartIm);
  ifft_topk<<<dim3(32), dim3(256), 0, stream>>>(PpartRe, PpartIm, TW, attnW, delays);
  gather_av<<<dim3(8192), dim3(256), 0, stream>>>(Vbuf, attnW, delays, Aattn);

  // out = gathered @ Wo + bo (plain bf16)
  gemm_bf16<<<dim3(512), dim3(256), 0, stream>>>(Aattn, Aattn, WTb + 6 * 262144, WTb + 7 * 262144, bo, out, 1, 2);
}

// Round 4
// 259.160 us; speedup vs baseline: 3.9598x; 1.0817x over previous
//
#include <hip/hip_runtime.h>
#include <hip/hip_bf16.h>

// AutoCorrelation layer: QKV proj (bf16x3 MFMA GEMM) -> packed FFT cross-corr
// (partials + reduce + ifft, NO global atomics) -> top-8 + softmax -> delay-gather
// of V -> output proj.  B=4, L=4096, D_MODEL=512, NHEAD=8, DH=64, TOPK=8.

#define MiB (1024ull * 1024ull)

typedef __attribute__((ext_vector_type(8))) short bf16x8;
typedef __attribute__((ext_vector_type(4))) float f32x4;
static_assert(sizeof(bf16x8) == 16, "bf16x8 must be 16B");

__device__ __forceinline__ unsigned short f2bf(float f) {
  unsigned u = __float_as_uint(f);
  unsigned r = (u + 0x7FFFu + ((u >> 16) & 1u)) >> 16;  // RN-even
  return (unsigned short)r;
}
__device__ __forceinline__ float bf2f(unsigned short h) {
  return __uint_as_float(((unsigned)h) << 16);
}
// base-4 digit reversal of a 12-bit index (involution)
__device__ __forceinline__ int rev4_12(int x) {
  unsigned r = __brev((unsigned)x) >> 20;
  return (int)(((r & 0xAAAu) >> 1) | ((r & 0x555u) << 1));
}
// LDS pad: +1 float per 32 to break power-of-2 bank patterns
#define IDX(e) ((e) + ((e) >> 5))
#define LDSN (4095 + (4095 >> 5) + 1)

// ---------------- conversion kernels ----------------

// x (f32) -> hi/lo bf16 split (A = hi + lo exactly to ~16 mantissa bits)
__global__ void conv_split(const float* __restrict__ x, unsigned short* __restrict__ hi,
                           unsigned short* __restrict__ lo, int n4) {
  int i = blockIdx.x * 256 + threadIdx.x;
  if (i >= n4) return;
  float4 v = ((const float4*)x)[i];
  ushort4 h, l;
  float f;
  f = v.x; h.x = f2bf(f); l.x = f2bf(f - bf2f(h.x));
  f = v.y; h.y = f2bf(f); l.y = f2bf(f - bf2f(h.y));
  f = v.z; h.z = f2bf(f); l.z = f2bf(f - bf2f(h.z));
  f = v.w; h.w = f2bf(f); l.w = f2bf(f - bf2f(h.w));
  ((ushort4*)hi)[i] = h;
  ((ushort4*)lo)[i] = l;
}

// All four W (512x512 f32 [k][n]) -> transposed hi/lo bf16 Wt[n][k], via LDS tile
// transpose (coalesced reads AND writes). Grid: 4 mats x 64 tiles of 64x64.
__global__ void conv_wt4(const float* __restrict__ W0, const float* __restrict__ W1,
                         const float* __restrict__ W2, const float* __restrict__ W3,
                         unsigned short* __restrict__ WT) {
  __shared__ float t[64][65];
  int bx = blockIdx.x;
  int w = bx >> 6, tile = bx & 63;
  int k0 = (tile >> 3) << 6, n0 = (tile & 7) << 6;
  const float* W = (w == 0) ? W0 : (w == 1) ? W1 : (w == 2) ? W2 : W3;
  unsigned short* hi = WT + (size_t)(2 * w) * 262144;
  unsigned short* lo = hi + 262144;
  int tid = threadIdx.x;
#pragma unroll
  for (int j = 0; j < 4; ++j) {
    int i = tid + (j << 8);
    int rr = i >> 4, c4 = (i & 15) << 2;
    float4 v = *(const float4*)&W[(size_t)(k0 + rr) * 512 + n0 + c4];
    t[rr][c4 + 0] = v.x; t[rr][c4 + 1] = v.y;
    t[rr][c4 + 2] = v.z; t[rr][c4 + 3] = v.w;
  }
  __syncthreads();
#pragma unroll
  for (int j = 0; j < 4; ++j) {
    int i = tid + (j << 8);
    int nn = i >> 4, k4 = (i & 15) << 2;
    ushort4 h, l;
    float f;
    f = t[k4 + 0][nn]; h.x = f2bf(f); l.x = f2bf(f - bf2f(h.x));
    f = t[k4 + 1][nn]; h.y = f2bf(f); l.y = f2bf(f - bf2f(h.y));
    f = t[k4 + 2][nn]; h.z = f2bf(f); l.z = f2bf(f - bf2f(h.z));
    f = t[k4 + 3][nn]; h.w = f2bf(f); l.w = f2bf(f - bf2f(h.w));
    size_t o = (size_t)(n0 + nn) * 512 + k0 + k4;
    *(ushort4*)(hi + o) = h;
    *(ushort4*)(lo + o) = l;
  }
}

// twiddle table T[r] = exp(-2*pi*i*r/4096), r=0..3071 (double-precision generated)
__global__ void make_tw(float2* __restrict__ T) {
  int r = blockIdx.x * 256 + threadIdx.x;
  if (r < 3072) {
    double a = -2.0 * 3.14159265358979323846 * (double)r / 4096.0;
    T[r] = make_float2((float)cos(a), (float)sin(a));
  }
}

// ---------------- fused Q+K GEMM (bf16x3, mode 0), 1024 wgs ----------------
// C(16384x512) = A @ W + bias with A=[Ahi|Alo|Ahi], B=[Bhi|Bhi|Blo] along K (3 segs).
// 128x128 tile, BK=64, 4 waves (2x2), mfma 16x16x32. C layout: C[(b*512+n)*4096+t].
__global__ __launch_bounds__(256, 2)
void qk_gemm(const unsigned short* __restrict__ AqHi, const unsigned short* __restrict__ AqLo,
             const unsigned short* __restrict__ AkvHi, const unsigned short* __restrict__ AkvLo,
             const unsigned short* __restrict__ WT,
             const float* __restrict__ bq, const float* __restrict__ bk,
             float* __restrict__ QT, float* __restrict__ KT) {
  __shared__ short As[128 * 64];
  __shared__ short Bs[128 * 64];
  int bx = blockIdx.x;
  int op = bx >> 9;  // 0 = Q, 1 = K
  bx &= 511;
  const unsigned short* Ahi = op ? AkvHi : AqHi;
  const unsigned short* Alo = op ? AkvLo : AqLo;
  const unsigned short* Bhi = WT + (op ? 2 * 262144 : 0);
  const unsigned short* Blo = Bhi + 262144;
  const float* bias = op ? bk : bq;
  float* C = op ? KT : QT;

  int bm = bx >> 2, bn = bx & 3;
  int m0 = bm << 7, n0 = bn << 7;
  int tid = threadIdx.x;
  int lane = tid & 63, wv = tid >> 6;
  int wm = wv >> 1, wn = wv & 1;

  const f32x4 zz = {0.f, 0.f, 0.f, 0.f};
  f32x4 acc[4][4];
#pragma unroll
  for (int i = 0; i < 4; ++i)
#pragma unroll
    for (int j = 0; j < 4; ++j) acc[i][j] = zz;

  int srow = tid >> 3;
  int sk = (tid & 7) << 3;
  for (int ks = 0; ks < 24; ++ks) {
    int seg = ks >> 3;
    int kb = (ks & 7) << 6;
    const unsigned short* Aseg = (seg == 2) ? Alo : Ahi;
    const unsigned short* Bseg = (seg == 1) ? Blo : Bhi;
#pragma unroll
    for (int i = 0; i < 4; ++i) {
      int r = (i << 5) + srow;
      const unsigned short* ga = Aseg + (size_t)(m0 + r) * 512 + kb + sk;
      const unsigned short* gb = Bseg + (size_t)(n0 + r) * 512 + kb + sk;
      char* la = (char*)As + (i << 12) + (wv << 10);
      char* lb = (char*)Bs + (i << 12) + (wv << 10);
      __builtin_amdgcn_global_load_lds((const __attribute__((address_space(1))) void*)ga,
                                       (__attribute__((address_space(3))) void*)la, 16, 0, 0);
      __builtin_amdgcn_global_load_lds((const __attribute__((address_space(1))) void*)gb,
                                       (__attribute__((address_space(3))) void*)lb, 16, 0, 0);
    }
    __syncthreads();
#pragma unroll
    for (int kk = 0; kk < 2; ++kk) {
      bf16x8 af[4], bfr[4];
      int krd = (kk << 5) + ((lane >> 4) << 3);
#pragma unroll
      for (int mi = 0; mi < 4; ++mi)
        af[mi] = *(const bf16x8*)&As[((wm << 6) + (mi << 4) + (lane & 15)) * 64 + krd];
#pragma unroll
      for (int ni = 0; ni < 4; ++ni)
        bfr[ni] = *(const bf16x8*)&Bs[((wn << 6) + (ni << 4) + (lane & 15)) * 64 + krd];
#pragma unroll
      for (int mi = 0; mi < 4; ++mi)
#pragma unroll
        for (int ni = 0; ni < 4; ++ni)
          acc[mi][ni] = __builtin_amdgcn_mfma_f32_16x16x32_bf16(af[mi], bfr[ni], acc[mi][ni], 0, 0, 0);
    }
    __syncthreads();
  }

#pragma unroll
  for (int mi = 0; mi < 4; ++mi) {
    int mrow0 = m0 + (wm << 6) + (mi << 4) + ((lane >> 4) << 2);
    int bq_ = mrow0 >> 12;
    int t0 = mrow0 & 4095;
#pragma unroll
    for (int ni = 0; ni < 4; ++ni) {
      int col = n0 + (wn << 6) + (ni << 4) + (lane & 15);
      float bv = bias[col];
      f32x4 v = acc[mi][ni];
      v.x += bv; v.y += bv; v.z += bv; v.w += bv;
      *(f32x4*)&C[((size_t)(bq_ * 512 + col)) * 4096 + t0] = v;
    }
  }
}

// ---------------- generic GEMM for V (mode 1) and OUT (mode 2), nseg=1 ----------------
__global__ __launch_bounds__(256, 2)
void gemm_bf16(const unsigned short* __restrict__ Ahi,
               const unsigned short* __restrict__ Bhi,
               const float* __restrict__ bias, float* __restrict__ C, int mode) {
  __shared__ short As[128 * 64];
  __shared__ short Bs[128 * 64];
  int bx = blockIdx.x;
  int bm = bx >> 2, bn = bx & 3;
  int m0 = bm << 7, n0 = bn << 7;
  int tid = threadIdx.x;
  int lane = tid & 63, wv = tid >> 6;
  int wm = wv >> 1, wn = wv & 1;

  const f32x4 zz = {0.f, 0.f, 0.f, 0.f};
  f32x4 acc[4][4];
#pragma unroll
  for (int i = 0; i < 4; ++i)
#pragma unroll
    for (int j = 0; j < 4; ++j) acc[i][j] = zz;

  int srow = tid >> 3;
  int sk = (tid & 7) << 3;
  for (int ks = 0; ks < 8; ++ks) {
    int kb = ks << 6;
#pragma unroll
    for (int i = 0; i < 4; ++i) {
      int r = (i << 5) + srow;
      const unsigned short* ga = Ahi + (size_t)(m0 + r) * 512 + kb + sk;
      const unsigned short* gb = Bhi + (size_t)(n0 + r) * 512 + kb + sk;
      char* la = (char*)As + (i << 12) + (wv << 10);
      char* lb = (char*)Bs + (i << 12) + (wv << 10);
      __builtin_amdgcn_global_load_lds((const __attribute__((address_space(1))) void*)ga,
                                       (__attribute__((address_space(3))) void*)la, 16, 0, 0);
      __builtin_amdgcn_global_load_lds((const __attribute__((address_space(1))) void*)gb,
                                       (__attribute__((address_space(3))) void*)lb, 16, 0, 0);
    }
    __syncthreads();
#pragma unroll
    for (int kk = 0; kk < 2; ++kk) {
      bf16x8 af[4], bfr[4];
      int krd = (kk << 5) + ((lane >> 4) << 3);
#pragma unroll
      for (int mi = 0; mi < 4; ++mi)
        af[mi] = *(const bf16x8*)&As[((wm << 6) + (mi << 4) + (lane & 15)) * 64 + krd];
#pragma unroll
      for (int ni = 0; ni < 4; ++ni)
        bfr[ni] = *(const bf16x8*)&Bs[((wn << 6) + (ni << 4) + (lane & 15)) * 64 + krd];
#pragma unroll
      for (int mi = 0; mi < 4; ++mi)
#pragma unroll
        for (int ni = 0; ni < 4; ++ni)
          acc[mi][ni] = __builtin_amdgcn_mfma_f32_16x16x32_bf16(af[mi], bfr[ni], acc[mi][ni], 0, 0, 0);
    }
    __syncthreads();
  }

#pragma unroll
  for (int mi = 0; mi < 4; ++mi) {
    int mrow0 = m0 + (wm << 6) + (mi << 4) + ((lane >> 4) << 2);
    int bq_ = mrow0 >> 12;
    int t0 = mrow0 & 4095;
#pragma unroll
    for (int ni = 0; ni < 4; ++ni) {
      int col = n0 + (wn << 6) + (ni << 4) + (lane & 15);
      float bv = bias[col];
      f32x4 v = acc[mi][ni];
      v.x += bv; v.y += bv; v.z += bv; v.w += bv;
      if (mode == 1) {
        size_t base = (size_t)(bq_ * 8 + (col >> 6)) * 4096;
        int d = col & 63;
        C[(base + t0 + 0) * 64 + d] = v.x;
        C[(base + t0 + 1) * 64 + d] = v.y;
        C[(base + t0 + 2) * 64 + d] = v.z;
        C[(base + t0 + 3) * 64 + d] = v.w;
      } else {
        C[(size_t)(mrow0 + 0) * 512 + col] = v.x;
        C[(size_t)(mrow0 + 1) * 512 + col] = v.y;
        C[(size_t)(mrow0 + 2) * 512 + col] = v.z;
        C[(size_t)(mrow0 + 3) * 512 + col] = v.w;
      }
    }
  }
}

// ---------------- FFT: 6-stage radix-4 DIF (natural in -> digit-reversed out) ----------------
__device__ void dif_fft(float* re, float* im, const float2* __restrict__ TW, int tid) {
  int m = 1024, lm = 10;
#pragma unroll
  for (int s = 0; s < 6; ++s) {
    int stw = 1 << (2 * s);
    for (int bb = tid; bb < 1024; bb += 256) {
      int j = bb & (m - 1);
      int g = bb >> lm;
      int i0 = (g << (lm + 2)) + j;
      int p0 = IDX(i0), p1 = IDX(i0 + m), p2 = IDX(i0 + 2 * m), p3 = IDX(i0 + 3 * m);
      float are = re[p0], aim = im[p0];
      float cre = re[p1], cim = im[p1];
      float ere = re[p2], eim = im[p2];
      float gre = re[p3], gim = im[p3];
      float Are = are + ere, Aim = aim + eim;
      float Bre = are - ere, Bim = aim - eim;
      float Cre = cre + gre, Cim = cim + gim;
      float dre = cre - gre, dim_ = cim - gim;
      float Dre = dim_, Dim = -dre;  // -i*(c-g)
      re[p0] = Are + Cre; im[p0] = Aim + Cim;
      float2 w1 = TW[j * stw], w2 = TW[2 * j * stw], w3 = TW[3 * j * stw];
      float xr = Bre + Dre, xi = Bim + Dim;
      re[p1] = xr * w1.x - xi * w1.y; im[p1] = xr * w1.y + xi * w1.x;
      xr = Are - Cre; xi = Aim - Cim;
      re[p2] = xr * w2.x - xi * w2.y; im[p2] = xr * w2.y + xi * w2.x;
      xr = Bre - Dre; xi = Bim - Dim;
      re[p3] = xr * w3.x - xi * w3.y; im[p3] = xr * w3.y + xi * w3.x;
    }
    __syncthreads();
    m >>= 2; lm -= 2;
  }
}

// Packed FFT of z = q + i*k per (b,h,d); one wg handles (b,h) x 2 d's, accumulating
// Qf*conj(Kf) in registers, writes partial (indexed by LDS position p, coalesced).
// 1024 wgs = 32 (b,h) x 32 parts; NO atomics.
__global__ __launch_bounds__(256, 4)
void fft_corr(const float* __restrict__ QT, const float* __restrict__ KT,
              const float2* __restrict__ TW, float* __restrict__ PpartRe,
              float* __restrict__ PpartIm) {
  __shared__ float re[LDSN];
  __shared__ float im[LDSN];
  int wg = blockIdx.x;
  int bh = wg >> 5;
  int d0 = (wg & 31) << 1;
  int tid = threadIdx.x;
  const float* qb = QT + (size_t)bh * 64 * 4096;
  const float* kb = KT + (size_t)bh * 64 * 4096;
  float accR[16], accI[16];
#pragma unroll
  for (int i = 0; i < 16; ++i) { accR[i] = 0.f; accI[i] = 0.f; }
  for (int dd = 0; dd < 2; ++dd) {
    __syncthreads();  // prior extraction reads of re/im done
    const float* q = qb + (size_t)(d0 + dd) * 4096;
    const float* k = kb + (size_t)(d0 + dd) * 4096;
    for (int e = tid; e < 4096; e += 256) {
      re[IDX(e)] = q[e];
      im[IDX(e)] = k[e];
    }
    __syncthreads();
    dif_fft(re, im, TW, tid);
    // position p holds Z[f], f = rev4(p); pair with f' = (N-f)%N at position rev4(f')
#pragma unroll
    for (int i = 0; i < 16; ++i) {
      int p = tid + (i << 8);
      int f = rev4_12(p);
      int fn = (4096 - f) & 4095;
      int pn = rev4_12(fn);
      float zr = re[IDX(p)], zi = im[IDX(p)];
      float wr = re[IDX(pn)], wi = im[IDX(pn)];
      float qre = 0.5f * (zr + wr), qim = 0.5f * (zi - wi);
      float kre = 0.5f * (zi + wi), kim = 0.5f * (wr - zr);
      accR[i] += qre * kre + qim * kim;   // Re(Qf*conj(Kf))
      accI[i] += qim * kre - qre * kim;   // Im(Qf*conj(Kf))
    }
  }
  float* pR = PpartRe + (size_t)wg * 4096;
  float* pI = PpartIm + (size_t)wg * 4096;
#pragma unroll
  for (int i = 0; i < 16; ++i) {
    int p = tid + (i << 8);
    pR[p] = accR[i];
    pI[p] = accI[i];
  }
}

// Reduce 32 partials per (b,h) -> Psum. Grid 512 = 32 bh x 16 chunks of 256 p.
__global__ void reduce_p(const float* __restrict__ PpartRe, const float* __restrict__ PpartIm,
                         float* __restrict__ PsumRe, float* __restrict__ PsumIm) {
  int wg = blockIdx.x;
  int bh = wg >> 4, p = ((wg & 15) << 8) + threadIdx.x;
  const float* bR = PpartRe + (size_t)bh * 32 * 4096 + p;
  const float* bI = PpartIm + (size_t)bh * 32 * 4096 + p;
  float sr = 0.f, si = 0.f;
#pragma unroll
  for (int part = 0; part < 32; ++part) {
    sr += bR[(size_t)part * 4096];
    si += bI[(size_t)part * 4096];
  }
  PsumRe[bh * 4096 + p] = sr;
  PsumIm[bh * 4096 + p] = si;
}

// Inverse FFT via conj + forward DIF; corr(tau=rev4(p)) = re[p]/(4096*64).
// Top-8 via per-pass wave shuffle reduce (2 barriers/pass), then softmax.
__global__ __launch_bounds__(256, 2)
void ifft_topk(const float* __restrict__ PsumRe, const float* __restrict__ PsumIm,
               const float2* __restrict__ TW, float* __restrict__ attnW, int* __restrict__ delays) {
  __shared__ float re[LDSN];
  __shared__ float im[LDSN];
  __shared__ float wval[4];
  __shared__ int widx[4], wpos[4];
  int bh = blockIdx.x, tid = threadIdx.x;
  int lane = tid & 63, wv = tid >> 6;
  for (int e = tid; e < 4096; e += 256) {
    int f = rev4_12(e);
    re[IDX(f)] = PsumRe[bh * 4096 + e];
    im[IDX(f)] = -PsumIm[bh * 4096 + e];  // conj
  }
  __syncthreads();
  dif_fft(re, im, TW, tid);
  const float SC = 1.0f / 262144.0f;  // 1/(L*Dh)
  float topv[8]; int topi[8];
  for (int pass = 0; pass < 8; ++pass) {
    float bv = -3.4e38f; int bi = 1 << 30; int bp = 0;
#pragma unroll
    for (int i = 0; i < 16; ++i) {
      int p = tid + (i << 8);
      float v = re[IDX(p)];
      int tau = rev4_12(p);
      if (v > bv || (v == bv && tau < bi)) { bv = v; bi = tau; bp = p; }
    }
#pragma unroll
    for (int off = 32; off > 0; off >>= 1) {
      float ov = __shfl_down(bv, off);
      int oi = __shfl_down(bi, off);
      int opp = __shfl_down(bp, off);
      if (ov > bv || (ov == bv && oi < bi)) { bv = ov; bi = oi; bp = opp; }
    }
    if (lane == 0) { wval[wv] = bv; widx[wv] = bi; wpos[wv] = bp; }
    __syncthreads();
    if (tid == 0) {
#pragma unroll
      for (int w2 = 1; w2 < 4; ++w2) {
        if (wval[w2] > bv || (wval[w2] == bv && widx[w2] < bi)) {
          bv = wval[w2]; bi = widx[w2]; bp = wpos[w2];
        }
      }
      topv[pass] = bv * SC;
      topi[pass] = bi;
      re[IDX(bp)] = -3.4e38f;
    }
    __syncthreads();
  }
  if (tid == 0) {
    float mx = topv[0];  // pass 0 = global max
    float ex[8], s = 0.f;
    for (int k = 0; k < 8; ++k) { ex[k] = expf(topv[k] - mx); s += ex[k]; }
    float inv = 1.0f / s;
    for (int k = 0; k < 8; ++k) {
      attnW[bh * 8 + k] = ex[k] * inv;
      delays[bh * 8 + k] = topi[k];
    }
  }
}

// out[b,h,t,:] = sum_k attn_k * V[b,h,(t-d_k)%L,:]; write bf16 into final-GEMM A layout.
__global__ void gather_av(const float* __restrict__ V, const float* __restrict__ attnW,
                          const int* __restrict__ delays, unsigned short* __restrict__ Ahi) {
  int blk = blockIdx.x;
  int bh = blk >> 8, tb = blk & 255;
  int tid = threadIdx.x;
  int tt = tid >> 4, dq = tid & 15;
  int t = (tb << 4) + tt;
  const float4* Vb = (const float4*)(V + (size_t)bh * 4096 * 64);
  float4 acc = make_float4(0.f, 0.f, 0.f, 0.f);
#pragma unroll
  for (int kk = 0; kk < 8; ++kk) {
    float w = attnW[bh * 8 + kk];
    int dl = delays[bh * 8 + kk];
    int row = (t - dl) & 4095;
    float4 x = Vb[row * 16 + dq];
    acc.x += w * x.x; acc.y += w * x.y; acc.z += w * x.z; acc.w += w * x.w;
  }
  int b = bh >> 3, h = bh & 7;
  size_t o = ((size_t)((b << 12) + t)) * 512 + (h << 6) + (dq << 2);
  ushort4 hv;
  hv.x = f2bf(acc.x); hv.y = f2bf(acc.y); hv.z = f2bf(acc.z); hv.w = f2bf(acc.w);
  *(ushort4*)(Ahi + o) = hv;
}

// ---------------- orchestration ----------------
extern "C" void kernel_launch(void* const* d_in, const int* in_sizes, int n_in,
                              void* d_out, int out_size, void* d_ws, size_t ws_size,
                              hipStream_t stream) {
  (void)in_sizes; (void)n_in; (void)out_size; (void)ws_size;
  const float* x_q = (const float*)d_in[0];
  const float* x_kv = (const float*)d_in[1];
  const float* Wq = (const float*)d_in[2];
  const float* bq = (const float*)d_in[3];
  const float* Wk = (const float*)d_in[4];
  const float* bk = (const float*)d_in[5];
  const float* Wv = (const float*)d_in[6];
  const float* bv = (const float*)d_in[7];
  const float* Wo = (const float*)d_in[8];
  const float* bo = (const float*)d_in[9];
  float* out = (float*)d_out;
  char* ws = (char*)d_ws;

  // workspace layout (~137.1 MiB; all "33.5 MB" arrays are exactly 32 MiB)
  // 0-16    AqHi          -> Vbuf (0-32, after qk_gemm)
  // 16-32   AqLo          -> (Vbuf tail)
  // 36-52   AkvHi         -> PpartRe (after v_gemm) -> Aattn (after reduce_p)
  // 52-68   AkvLo         -> PpartIm
  // 68-72   WTb (8 x 512x512 bf16)
  // 72-104  QT            -> PsumRe/PsumIm (after fft_corr)
  // 104-136 KT
  // 137+    attnW, delays, TW
  unsigned short* AqHi  = (unsigned short*)(ws + 0 * MiB);
  unsigned short* AqLo  = (unsigned short*)(ws + 16 * MiB);
  float*          Vbuf  = (float*)(ws + 0 * MiB);
  unsigned short* AkvHi = (unsigned short*)(ws + 36 * MiB);
  unsigned short* AkvLo = (unsigned short*)(ws + 52 * MiB);
  float* PpartRe = (float*)(ws + 36 * MiB);
  float* PpartIm = (float*)(ws + 52 * MiB);
  unsigned short* Aattn = (unsigned short*)(ws + 36 * MiB);
  unsigned short* WTb   = (unsigned short*)(ws + 68 * MiB);
  float* QT    = (float*)(ws + 72 * MiB);
  float* KT    = (float*)(ws + 104 * MiB);
  float* PsumRe = (float*)(ws + 72 * MiB);
  float* PsumIm = (float*)(ws + 73 * MiB);
  float* attnW = (float*)(ws + 137 * MiB);
  int*   delays = (int*)(ws + 137 * MiB + 4096);
  float2* TW   = (float2*)(ws + 137 * MiB + 8192);

  int n4 = (16384 * 512) / 4;
  conv_split<<<dim3(n4 / 256), dim3(256), 0, stream>>>(x_q, AqHi, AqLo, n4);
  conv_split<<<dim3(n4 / 256), dim3(256), 0, stream>>>(x_kv, AkvHi, AkvLo, n4);
  conv_wt4<<<dim3(256), dim3(256), 0, stream>>>(Wq, Wk, Wv, Wo, WTb);
  make_tw<<<dim3(12), dim3(256), 0, stream>>>(TW);

  // Q and K projections fused (1024 wgs); V after (writes over dead Aq region).
  qk_gemm<<<dim3(1024), dim3(256), 0, stream>>>(AqHi, AqLo, AkvHi, AkvLo, WTb, bq, bk, QT, KT);
  gemm_bf16<<<dim3(512), dim3(256), 0, stream>>>(AkvHi, WTb + 4 * 262144, bv, Vbuf, 1);

  fft_corr<<<dim3(1024), dim3(256), 0, stream>>>(QT, KT, TW, PpartRe, PpartIm);
  reduce_p<<<dim3(512), dim3(256), 0, stream>>>(PpartRe, PpartIm, PsumRe, PsumIm);
  ifft_topk<<<dim3(32), dim3(256), 0, stream>>>(PsumRe, PsumIm, TW, attnW, delays);
  gather_av<<<dim3(8192), dim3(256), 0, stream>>>(Vbuf, attnW, delays, Aattn);

  // out = gathered @ Wo + bo (plain bf16)
  gemm_bf16<<<dim3(512), dim3(256), 0, stream>>>(Aattn, WTb + 6 * 262144, bo, out, 2);
}

// Round 5
// 247.283 us; speedup vs baseline: 4.1500x; 1.0480x over previous
//
#include <hip/hip_runtime.h>
#include <hip/hip_bf16.h>

// AutoCorrelation layer: QKV proj (bf16x3 MFMA GEMM) -> packed FFT cross-corr
// (partials + reduce + ifft, NO global atomics) -> top-8 + softmax -> delay-gather
// of V -> output proj.  B=4, L=4096, D_MODEL=512, NHEAD=8, DH=64, TOPK=8.

#define MiB (1024ull * 1024ull)

typedef __attribute__((ext_vector_type(8))) short bf16x8;
typedef __attribute__((ext_vector_type(4))) float f32x4;
static_assert(sizeof(bf16x8) == 16, "bf16x8 must be 16B");

__device__ __forceinline__ unsigned short f2bf(float f) {
  unsigned u = __float_as_uint(f);
  unsigned r = (u + 0x7FFFu + ((u >> 16) & 1u)) >> 16;  // RN-even
  return (unsigned short)r;
}
__device__ __forceinline__ float bf2f(unsigned short h) {
  return __uint_as_float(((unsigned)h) << 16);
}
// base-4 digit reversal of a 12-bit index (involution)
__device__ __forceinline__ int rev4_12(int x) {
  unsigned r = __brev((unsigned)x) >> 20;
  return (int)(((r & 0xAAAu) >> 1) | ((r & 0x555u) << 1));
}
// LDS pad: +1 float per 32 to break power-of-2 bank patterns
#define IDX(e) ((e) + ((e) >> 5))
#define LDSN (4095 + (4095 >> 5) + 1)

// XCD-aware bijective swizzle (nwg % 8 == 0): XCD x owns contiguous logical chunk.
__device__ __forceinline__ int xcd_swz(int bid, int cpx) {
  return (bid & 7) * cpx + (bid >> 3);
}

// ---------------- conversion kernels ----------------

// x_q and x_kv (f32) -> hi/lo bf16 splits, one fused launch (grid 2*n4/256).
__global__ void conv_split2(const float* __restrict__ xq, const float* __restrict__ xkv,
                            unsigned short* __restrict__ qhi, unsigned short* __restrict__ qlo,
                            unsigned short* __restrict__ khi, unsigned short* __restrict__ klo,
                            int n4) {
  int i = blockIdx.x * 256 + threadIdx.x;
  const float* x = (i < n4) ? xq : xkv;
  unsigned short* hi = (i < n4) ? qhi : khi;
  unsigned short* lo = (i < n4) ? qlo : klo;
  int ii = (i < n4) ? i : i - n4;
  float4 v = ((const float4*)x)[ii];
  ushort4 h, l;
  float f;
  f = v.x; h.x = f2bf(f); l.x = f2bf(f - bf2f(h.x));
  f = v.y; h.y = f2bf(f); l.y = f2bf(f - bf2f(h.y));
  f = v.z; h.z = f2bf(f); l.z = f2bf(f - bf2f(h.z));
  f = v.w; h.w = f2bf(f); l.w = f2bf(f - bf2f(h.w));
  ((ushort4*)hi)[ii] = h;
  ((ushort4*)lo)[ii] = l;
}

// All four W (512x512 f32 [k][n]) -> transposed hi/lo bf16 Wt[n][k], via LDS tile
// transpose (coalesced reads AND writes). Grid: 4 mats x 64 tiles of 64x64.
__global__ void conv_wt4(const float* __restrict__ W0, const float* __restrict__ W1,
                         const float* __restrict__ W2, const float* __restrict__ W3,
                         unsigned short* __restrict__ WT) {
  __shared__ float t[64][65];
  int bx = blockIdx.x;
  int w = bx >> 6, tile = bx & 63;
  int k0 = (tile >> 3) << 6, n0 = (tile & 7) << 6;
  const float* W = (w == 0) ? W0 : (w == 1) ? W1 : (w == 2) ? W2 : W3;
  unsigned short* hi = WT + (size_t)(2 * w) * 262144;
  unsigned short* lo = hi + 262144;
  int tid = threadIdx.x;
#pragma unroll
  for (int j = 0; j < 4; ++j) {
    int i = tid + (j << 8);
    int rr = i >> 4, c4 = (i & 15) << 2;
    float4 v = *(const float4*)&W[(size_t)(k0 + rr) * 512 + n0 + c4];
    t[rr][c4 + 0] = v.x; t[rr][c4 + 1] = v.y;
    t[rr][c4 + 2] = v.z; t[rr][c4 + 3] = v.w;
  }
  __syncthreads();
#pragma unroll
  for (int j = 0; j < 4; ++j) {
    int i = tid + (j << 8);
    int nn = i >> 4, k4 = (i & 15) << 2;
    ushort4 h, l;
    float f;
    f = t[k4 + 0][nn]; h.x = f2bf(f); l.x = f2bf(f - bf2f(h.x));
    f = t[k4 + 1][nn]; h.y = f2bf(f); l.y = f2bf(f - bf2f(h.y));
    f = t[k4 + 2][nn]; h.z = f2bf(f); l.z = f2bf(f - bf2f(h.z));
    f = t[k4 + 3][nn]; h.w = f2bf(f); l.w = f2bf(f - bf2f(h.w));
    size_t o = (size_t)(n0 + nn) * 512 + k0 + k4;
    *(ushort4*)(hi + o) = h;
    *(ushort4*)(lo + o) = l;
  }
}

// twiddle table T[r] = exp(-2*pi*i*r/4096), r=0..3071 (double-precision generated)
__global__ void make_tw(float2* __restrict__ T) {
  int r = blockIdx.x * 256 + threadIdx.x;
  if (r < 3072) {
    double a = -2.0 * 3.14159265358979323846 * (double)r / 4096.0;
    T[r] = make_float2((float)cos(a), (float)sin(a));
  }
}

// ---------------- fused Q+K GEMM (bf16x3, mode 0), 1024 wgs ----------------
// C(16384x512) = A @ W + bias with A=[Ahi|Ahi|Alo], B=[Bhi|Blo|Bhi] along K (3 segs).
// 128x128 tile, BK=64, 4 waves (2x2), mfma 16x16x32. C layout: C[(b*512+n)*4096+t].
// XCD swizzle: each XCD owns a contiguous bm-range -> A-panels fetched once.
__global__ __launch_bounds__(256, 2)
void qk_gemm(const unsigned short* __restrict__ AqHi, const unsigned short* __restrict__ AqLo,
             const unsigned short* __restrict__ AkvHi, const unsigned short* __restrict__ AkvLo,
             const unsigned short* __restrict__ WT,
             const float* __restrict__ bq, const float* __restrict__ bk,
             float* __restrict__ QT, float* __restrict__ KT) {
  __shared__ short As[128 * 64];
  __shared__ short Bs[128 * 64];
  int bx = xcd_swz(blockIdx.x, 128);  // 1024 wgs
  int op = bx >> 9;  // 0 = Q, 1 = K
  bx &= 511;
  const unsigned short* Ahi = op ? AkvHi : AqHi;
  const unsigned short* Alo = op ? AkvLo : AqLo;
  const unsigned short* Bhi = WT + (op ? 2 * 262144 : 0);
  const unsigned short* Blo = Bhi + 262144;
  const float* bias = op ? bk : bq;
  float* C = op ? KT : QT;

  int bm = bx >> 2, bn = bx & 3;
  int m0 = bm << 7, n0 = bn << 7;
  int tid = threadIdx.x;
  int lane = tid & 63, wv = tid >> 6;
  int wm = wv >> 1, wn = wv & 1;

  const f32x4 zz = {0.f, 0.f, 0.f, 0.f};
  f32x4 acc[4][4];
#pragma unroll
  for (int i = 0; i < 4; ++i)
#pragma unroll
    for (int j = 0; j < 4; ++j) acc[i][j] = zz;

  int srow = tid >> 3;
  int sk = (tid & 7) << 3;
  for (int ks = 0; ks < 24; ++ks) {
    int seg = ks >> 3;
    int kb = (ks & 7) << 6;
    const unsigned short* Aseg = (seg == 2) ? Alo : Ahi;
    const unsigned short* Bseg = (seg == 1) ? Blo : Bhi;
#pragma unroll
    for (int i = 0; i < 4; ++i) {
      int r = (i << 5) + srow;
      const unsigned short* ga = Aseg + (size_t)(m0 + r) * 512 + kb + sk;
      const unsigned short* gb = Bseg + (size_t)(n0 + r) * 512 + kb + sk;
      char* la = (char*)As + (i << 12) + (wv << 10);
      char* lb = (char*)Bs + (i << 12) + (wv << 10);
      __builtin_amdgcn_global_load_lds((const __attribute__((address_space(1))) void*)ga,
                                       (__attribute__((address_space(3))) void*)la, 16, 0, 0);
      __builtin_amdgcn_global_load_lds((const __attribute__((address_space(1))) void*)gb,
                                       (__attribute__((address_space(3))) void*)lb, 16, 0, 0);
    }
    __syncthreads();
#pragma unroll
    for (int kk = 0; kk < 2; ++kk) {
      bf16x8 af[4], bfr[4];
      int krd = (kk << 5) + ((lane >> 4) << 3);
#pragma unroll
      for (int mi = 0; mi < 4; ++mi)
        af[mi] = *(const bf16x8*)&As[((wm << 6) + (mi << 4) + (lane & 15)) * 64 + krd];
#pragma unroll
      for (int ni = 0; ni < 4; ++ni)
        bfr[ni] = *(const bf16x8*)&Bs[((wn << 6) + (ni << 4) + (lane & 15)) * 64 + krd];
#pragma unroll
      for (int mi = 0; mi < 4; ++mi)
#pragma unroll
        for (int ni = 0; ni < 4; ++ni)
          acc[mi][ni] = __builtin_amdgcn_mfma_f32_16x16x32_bf16(af[mi], bfr[ni], acc[mi][ni], 0, 0, 0);
    }
    __syncthreads();
  }

#pragma unroll
  for (int mi = 0; mi < 4; ++mi) {
    int mrow0 = m0 + (wm << 6) + (mi << 4) + ((lane >> 4) << 2);
    int bq_ = mrow0 >> 12;
    int t0 = mrow0 & 4095;
#pragma unroll
    for (int ni = 0; ni < 4; ++ni) {
      int col = n0 + (wn << 6) + (ni << 4) + (lane & 15);
      float bv = bias[col];
      f32x4 v = acc[mi][ni];
      v.x += bv; v.y += bv; v.z += bv; v.w += bv;
      *(f32x4*)&C[((size_t)(bq_ * 512 + col)) * 4096 + t0] = v;
    }
  }
}

// ---------------- generic GEMM for V (mode 1) and OUT (mode 2), nseg=1, 512 wgs ----------------
__global__ __launch_bounds__(256, 2)
void gemm_bf16(const unsigned short* __restrict__ Ahi,
               const unsigned short* __restrict__ Bhi,
               const float* __restrict__ bias, float* __restrict__ C, int mode) {
  __shared__ short As[128 * 64];
  __shared__ short Bs[128 * 64];
  int bx = xcd_swz(blockIdx.x, 64);  // 512 wgs
  int bm = bx >> 2, bn = bx & 3;
  int m0 = bm << 7, n0 = bn << 7;
  int tid = threadIdx.x;
  int lane = tid & 63, wv = tid >> 6;
  int wm = wv >> 1, wn = wv & 1;

  const f32x4 zz = {0.f, 0.f, 0.f, 0.f};
  f32x4 acc[4][4];
#pragma unroll
  for (int i = 0; i < 4; ++i)
#pragma unroll
    for (int j = 0; j < 4; ++j) acc[i][j] = zz;

  int srow = tid >> 3;
  int sk = (tid & 7) << 3;
  for (int ks = 0; ks < 8; ++ks) {
    int kb = ks << 6;
#pragma unroll
    for (int i = 0; i < 4; ++i) {
      int r = (i << 5) + srow;
      const unsigned short* ga = Ahi + (size_t)(m0 + r) * 512 + kb + sk;
      const unsigned short* gb = Bhi + (size_t)(n0 + r) * 512 + kb + sk;
      char* la = (char*)As + (i << 12) + (wv << 10);
      char* lb = (char*)Bs + (i << 12) + (wv << 10);
      __builtin_amdgcn_global_load_lds((const __attribute__((address_space(1))) void*)ga,
                                       (__attribute__((address_space(3))) void*)la, 16, 0, 0);
      __builtin_amdgcn_global_load_lds((const __attribute__((address_space(1))) void*)gb,
                                       (__attribute__((address_space(3))) void*)lb, 16, 0, 0);
    }
    __syncthreads();
#pragma unroll
    for (int kk = 0; kk < 2; ++kk) {
      bf16x8 af[4], bfr[4];
      int krd = (kk << 5) + ((lane >> 4) << 3);
#pragma unroll
      for (int mi = 0; mi < 4; ++mi)
        af[mi] = *(const bf16x8*)&As[((wm << 6) + (mi << 4) + (lane & 15)) * 64 + krd];
#pragma unroll
      for (int ni = 0; ni < 4; ++ni)
        bfr[ni] = *(const bf16x8*)&Bs[((wn << 6) + (ni << 4) + (lane & 15)) * 64 + krd];
#pragma unroll
      for (int mi = 0; mi < 4; ++mi)
#pragma unroll
        for (int ni = 0; ni < 4; ++ni)
          acc[mi][ni] = __builtin_amdgcn_mfma_f32_16x16x32_bf16(af[mi], bfr[ni], acc[mi][ni], 0, 0, 0);
    }
    __syncthreads();
  }

#pragma unroll
  for (int mi = 0; mi < 4; ++mi) {
    int mrow0 = m0 + (wm << 6) + (mi << 4) + ((lane >> 4) << 2);
    int bq_ = mrow0 >> 12;
    int t0 = mrow0 & 4095;
#pragma unroll
    for (int ni = 0; ni < 4; ++ni) {
      int col = n0 + (wn << 6) + (ni << 4) + (lane & 15);
      float bv = bias[col];
      f32x4 v = acc[mi][ni];
      v.x += bv; v.y += bv; v.z += bv; v.w += bv;
      if (mode == 1) {
        size_t base = (size_t)(bq_ * 8 + (col >> 6)) * 4096;
        int d = col & 63;
        C[(base + t0 + 0) * 64 + d] = v.x;
        C[(base + t0 + 1) * 64 + d] = v.y;
        C[(base + t0 + 2) * 64 + d] = v.z;
        C[(base + t0 + 3) * 64 + d] = v.w;
      } else {
        C[(size_t)(mrow0 + 0) * 512 + col] = v.x;
        C[(size_t)(mrow0 + 1) * 512 + col] = v.y;
        C[(size_t)(mrow0 + 2) * 512 + col] = v.z;
        C[(size_t)(mrow0 + 3) * 512 + col] = v.w;
      }
    }
  }
}

// ---------------- FFT: 6-stage radix-4 DIF (natural in -> digit-reversed out) ----------------
__device__ void dif_fft(float* re, float* im, const float2* __restrict__ TW, int tid) {
  int m = 1024, lm = 10;
#pragma unroll
  for (int s = 0; s < 6; ++s) {
    int stw = 1 << (2 * s);
    for (int bb = tid; bb < 1024; bb += 256) {
      int j = bb & (m - 1);
      int g = bb >> lm;
      int i0 = (g << (lm + 2)) + j;
      int p0 = IDX(i0), p1 = IDX(i0 + m), p2 = IDX(i0 + 2 * m), p3 = IDX(i0 + 3 * m);
      float are = re[p0], aim = im[p0];
      float cre = re[p1], cim = im[p1];
      float ere = re[p2], eim = im[p2];
      float gre = re[p3], gim = im[p3];
      float Are = are + ere, Aim = aim + eim;
      float Bre = are - ere, Bim = aim - eim;
      float Cre = cre + gre, Cim = cim + gim;
      float dre = cre - gre, dim_ = cim - gim;
      float Dre = dim_, Dim = -dre;  // -i*(c-g)
      re[p0] = Are + Cre; im[p0] = Aim + Cim;
      float2 w1 = TW[j * stw], w2 = TW[2 * j * stw], w3 = TW[3 * j * stw];
      float xr = Bre + Dre, xi = Bim + Dim;
      re[p1] = xr * w1.x - xi * w1.y; im[p1] = xr * w1.y + xi * w1.x;
      xr = Are - Cre; xi = Aim - Cim;
      re[p2] = xr * w2.x - xi * w2.y; im[p2] = xr * w2.y + xi * w2.x;
      xr = Bre - Dre; xi = Bim - Dim;
      re[p3] = xr * w3.x - xi * w3.y; im[p3] = xr * w3.y + xi * w3.x;
    }
    __syncthreads();
    m >>= 2; lm -= 2;
  }
}

// Packed FFT of z = q + i*k per (b,h,d); one wg handles (b,h) x 2 d's, accumulating
// Qf*conj(Kf) in registers, writes partial (indexed by LDS position p, coalesced).
// 1024 wgs = 32 (b,h) x 32 parts; NO atomics.
__global__ __launch_bounds__(256, 4)
void fft_corr(const float* __restrict__ QT, const float* __restrict__ KT,
              const float2* __restrict__ TW, float* __restrict__ PpartRe,
              float* __restrict__ PpartIm) {
  __shared__ float re[LDSN];
  __shared__ float im[LDSN];
  int wg = blockIdx.x;
  int bh = wg >> 5;
  int d0 = (wg & 31) << 1;
  int tid = threadIdx.x;
  const float* qb = QT + (size_t)bh * 64 * 4096;
  const float* kb = KT + (size_t)bh * 64 * 4096;
  float accR[16], accI[16];
#pragma unroll
  for (int i = 0; i < 16; ++i) { accR[i] = 0.f; accI[i] = 0.f; }
  for (int dd = 0; dd < 2; ++dd) {
    __syncthreads();  // prior extraction reads of re/im done
    const float* q = qb + (size_t)(d0 + dd) * 4096;
    const float* k = kb + (size_t)(d0 + dd) * 4096;
    for (int e = tid; e < 4096; e += 256) {
      re[IDX(e)] = q[e];
      im[IDX(e)] = k[e];
    }
    __syncthreads();
    dif_fft(re, im, TW, tid);
    // position p holds Z[f], f = rev4(p); pair with f' = (N-f)%N at position rev4(f')
#pragma unroll
    for (int i = 0; i < 16; ++i) {
      int p = tid + (i << 8);
      int f = rev4_12(p);
      int fn = (4096 - f) & 4095;
      int pn = rev4_12(fn);
      float zr = re[IDX(p)], zi = im[IDX(p)];
      float wr = re[IDX(pn)], wi = im[IDX(pn)];
      float qre = 0.5f * (zr + wr), qim = 0.5f * (zi - wi);
      float kre = 0.5f * (zi + wi), kim = 0.5f * (wr - zr);
      accR[i] += qre * kre + qim * kim;   // Re(Qf*conj(Kf))
      accI[i] += qim * kre - qre * kim;   // Im(Qf*conj(Kf))
    }
  }
  float* pR = PpartRe + (size_t)wg * 4096;
  float* pI = PpartIm + (size_t)wg * 4096;
#pragma unroll
  for (int i = 0; i < 16; ++i) {
    int p = tid + (i << 8);
    pR[p] = accR[i];
    pI[p] = accI[i];
  }
}

// Reduce 32 partials per (b,h) -> Psum. Grid 512 = 32 bh x 16 chunks of 256 p.
__global__ void reduce_p(const float* __restrict__ PpartRe, const float* __restrict__ PpartIm,
                         float* __restrict__ PsumRe, float* __restrict__ PsumIm) {
  int wg = blockIdx.x;
  int bh = wg >> 4, p = ((wg & 15) << 8) + threadIdx.x;
  const float* bR = PpartRe + (size_t)bh * 32 * 4096 + p;
  const float* bI = PpartIm + (size_t)bh * 32 * 4096 + p;
  float sr = 0.f, si = 0.f;
#pragma unroll
  for (int part = 0; part < 32; ++part) {
    sr += bR[(size_t)part * 4096];
    si += bI[(size_t)part * 4096];
  }
  PsumRe[bh * 4096 + p] = sr;
  PsumIm[bh * 4096 + p] = si;
}

// Inverse FFT via conj + forward DIF; corr(tau=rev4(p)) = re[p]/(4096*64).
// Top-8 via per-pass wave shuffle reduce (2 barriers/pass), then softmax.
__global__ __launch_bounds__(256, 2)
void ifft_topk(const float* __restrict__ PsumRe, const float* __restrict__ PsumIm,
               const float2* __restrict__ TW, float* __restrict__ attnW, int* __restrict__ delays) {
  __shared__ float re[LDSN];
  __shared__ float im[LDSN];
  __shared__ float wval[4];
  __shared__ int widx[4], wpos[4];
  int bh = blockIdx.x, tid = threadIdx.x;
  int lane = tid & 63, wv = tid >> 6;
  for (int e = tid; e < 4096; e += 256) {
    int f = rev4_12(e);
    re[IDX(f)] = PsumRe[bh * 4096 + e];
    im[IDX(f)] = -PsumIm[bh * 4096 + e];  // conj
  }
  __syncthreads();
  dif_fft(re, im, TW, tid);
  const float SC = 1.0f / 262144.0f;  // 1/(L*Dh)
  float topv[8]; int topi[8];
  for (int pass = 0; pass < 8; ++pass) {
    float bv = -3.4e38f; int bi = 1 << 30; int bp = 0;
#pragma unroll
    for (int i = 0; i < 16; ++i) {
      int p = tid + (i << 8);
      float v = re[IDX(p)];
      int tau = rev4_12(p);
      if (v > bv || (v == bv && tau < bi)) { bv = v; bi = tau; bp = p; }
    }
#pragma unroll
    for (int off = 32; off > 0; off >>= 1) {
      float ov = __shfl_down(bv, off);
      int oi = __shfl_down(bi, off);
      int opp = __shfl_down(bp, off);
      if (ov > bv || (ov == bv && oi < bi)) { bv = ov; bi = oi; bp = opp; }
    }
    if (lane == 0) { wval[wv] = bv; widx[wv] = bi; wpos[wv] = bp; }
    __syncthreads();
    if (tid == 0) {
#pragma unroll
      for (int w2 = 1; w2 < 4; ++w2) {
        if (wval[w2] > bv || (wval[w2] == bv && widx[w2] < bi)) {
          bv = wval[w2]; bi = widx[w2]; bp = wpos[w2];
        }
      }
      topv[pass] = bv * SC;
      topi[pass] = bi;
      re[IDX(bp)] = -3.4e38f;
    }
    __syncthreads();
  }
  if (tid == 0) {
    float mx = topv[0];  // pass 0 = global max
    float ex[8], s = 0.f;
    for (int k = 0; k < 8; ++k) { ex[k] = expf(topv[k] - mx); s += ex[k]; }
    float inv = 1.0f / s;
    for (int k = 0; k < 8; ++k) {
      attnW[bh * 8 + k] = ex[k] * inv;
      delays[bh * 8 + k] = topi[k];
    }
  }
}

// out[b,h,t,:] = sum_k attn_k * V[b,h,(t-d_k)%L,:]; write bf16 into final-GEMM A layout.
__global__ void gather_av(const float* __restrict__ V, const float* __restrict__ attnW,
                          const int* __restrict__ delays, unsigned short* __restrict__ Ahi) {
  int blk = blockIdx.x;
  int bh = blk >> 8, tb = blk & 255;
  int tid = threadIdx.x;
  int tt = tid >> 4, dq = tid & 15;
  int t = (tb << 4) + tt;
  const float4* Vb = (const float4*)(V + (size_t)bh * 4096 * 64);
  float4 acc = make_float4(0.f, 0.f, 0.f, 0.f);
#pragma unroll
  for (int kk = 0; kk < 8; ++kk) {
    float w = attnW[bh * 8 + kk];
    int dl = delays[bh * 8 + kk];
    int row = (t - dl) & 4095;
    float4 x = Vb[row * 16 + dq];
    acc.x += w * x.x; acc.y += w * x.y; acc.z += w * x.z; acc.w += w * x.w;
  }
  int b = bh >> 3, h = bh & 7;
  size_t o = ((size_t)((b << 12) + t)) * 512 + (h << 6) + (dq << 2);
  ushort4 hv;
  hv.x = f2bf(acc.x); hv.y = f2bf(acc.y); hv.z = f2bf(acc.z); hv.w = f2bf(acc.w);
  *(ushort4*)(Ahi + o) = hv;
}

// ---------------- orchestration ----------------
extern "C" void kernel_launch(void* const* d_in, const int* in_sizes, int n_in,
                              void* d_out, int out_size, void* d_ws, size_t ws_size,
                              hipStream_t stream) {
  (void)in_sizes; (void)n_in; (void)out_size; (void)ws_size;
  const float* x_q = (const float*)d_in[0];
  const float* x_kv = (const float*)d_in[1];
  const float* Wq = (const float*)d_in[2];
  const float* bq = (const float*)d_in[3];
  const float* Wk = (const float*)d_in[4];
  const float* bk = (const float*)d_in[5];
  const float* Wv = (const float*)d_in[6];
  const float* bv = (const float*)d_in[7];
  const float* Wo = (const float*)d_in[8];
  const float* bo = (const float*)d_in[9];
  float* out = (float*)d_out;
  char* ws = (char*)d_ws;

  // workspace layout (~137.1 MiB)
  // 0-16    AqHi          -> Vbuf (0-32, after qk_gemm)
  // 16-32   AqLo          -> (Vbuf tail)
  // 36-52   AkvHi         -> PpartRe (after v_gemm) -> Aattn (after reduce_p)
  // 52-68   AkvLo         -> PpartIm
  // 68-72   WTb (8 x 512x512 bf16)
  // 72-104  QT            -> PsumRe/PsumIm (after fft_corr)
  // 104-136 KT
  // 137+    attnW, delays, TW
  unsigned short* AqHi  = (unsigned short*)(ws + 0 * MiB);
  unsigned short* AqLo  = (unsigned short*)(ws + 16 * MiB);
  float*          Vbuf  = (float*)(ws + 0 * MiB);
  unsigned short* AkvHi = (unsigned short*)(ws + 36 * MiB);
  unsigned short* AkvLo = (unsigned short*)(ws + 52 * MiB);
  float* PpartRe = (float*)(ws + 36 * MiB);
  float* PpartIm = (float*)(ws + 52 * MiB);
  unsigned short* Aattn = (unsigned short*)(ws + 36 * MiB);
  unsigned short* WTb   = (unsigned short*)(ws + 68 * MiB);
  float* QT    = (float*)(ws + 72 * MiB);
  float* KT    = (float*)(ws + 104 * MiB);
  float* PsumRe = (float*)(ws + 72 * MiB);
  float* PsumIm = (float*)(ws + 73 * MiB);
  float* attnW = (float*)(ws + 137 * MiB);
  int*   delays = (int*)(ws + 137 * MiB + 4096);
  float2* TW   = (float2*)(ws + 137 * MiB + 8192);

  int n4 = (16384 * 512) / 4;
  conv_split2<<<dim3(2 * n4 / 256), dim3(256), 0, stream>>>(x_q, x_kv, AqHi, AqLo, AkvHi, AkvLo, n4);
  conv_wt4<<<dim3(256), dim3(256), 0, stream>>>(Wq, Wk, Wv, Wo, WTb);
  make_tw<<<dim3(12), dim3(256), 0, stream>>>(TW);

  // Q and K projections fused (1024 wgs); V after (writes over dead Aq region).
  qk_gemm<<<dim3(1024), dim3(256), 0, stream>>>(AqHi, AqLo, AkvHi, AkvLo, WTb, bq, bk, QT, KT);
  gemm_bf16<<<dim3(512), dim3(256), 0, stream>>>(AkvHi, WTb + 4 * 262144, bv, Vbuf, 1);

  fft_corr<<<dim3(1024), dim3(256), 0, stream>>>(QT, KT, TW, PpartRe, PpartIm);
  reduce_p<<<dim3(512), dim3(256), 0, stream>>>(PpartRe, PpartIm, PsumRe, PsumIm);
  ifft_topk<<<dim3(32), dim3(256), 0, stream>>>(PsumRe, PsumIm, TW, attnW, delays);
  gather_av<<<dim3(8192), dim3(256), 0, stream>>>(Vbuf, attnW, delays, Aattn);

  // out = gathered @ Wo + bo (plain bf16)
  gemm_bf16<<<dim3(512), dim3(256), 0, stream>>>(Aattn, WTb + 6 * 262144, bo, out, 2);
}

// Round 6
// 233.520 us; speedup vs baseline: 4.3945x; 1.0589x over previous
//
#include <hip/hip_runtime.h>
#include <hip/hip_bf16.h>

// AutoCorrelation layer: QKV proj (bf16x3 MFMA GEMM) -> packed FFT cross-corr
// (partials + reduce + ifft, NO global atomics) -> top-8 + softmax -> delay-gather
// of V -> output proj.  B=4, L=4096, D_MODEL=512, NHEAD=8, DH=64, TOPK=8.

#define MiB (1024ull * 1024ull)

typedef __attribute__((ext_vector_type(8))) short bf16x8;
typedef __attribute__((ext_vector_type(4))) float f32x4;
static_assert(sizeof(bf16x8) == 16, "bf16x8 must be 16B");

__device__ __forceinline__ unsigned short f2bf(float f) {
  unsigned u = __float_as_uint(f);
  unsigned r = (u + 0x7FFFu + ((u >> 16) & 1u)) >> 16;  // RN-even
  return (unsigned short)r;
}
__device__ __forceinline__ float bf2f(unsigned short h) {
  return __uint_as_float(((unsigned)h) << 16);
}
// base-4 digit reversal of a 12-bit index (involution)
__device__ __forceinline__ int rev4_12(int x) {
  unsigned r = __brev((unsigned)x) >> 20;
  return (int)(((r & 0xAAAu) >> 1) | ((r & 0x555u) << 1));
}
// LDS pad: +1 float per 32 to break power-of-2 bank patterns
#define IDX(e) ((e) + ((e) >> 5))
#define LDSN (4095 + (4095 >> 5) + 1)

// XCD-aware bijective swizzle (nwg % 8 == 0): XCD x owns contiguous logical chunk.
__device__ __forceinline__ int xcd_swz(int bid, int cpx) {
  return (bid & 7) * cpx + (bid >> 3);
}

// ---------------- conversion kernels ----------------

// x_q and x_kv (f32) -> hi/lo bf16 splits, one fused launch (grid 2*n4/256).
__global__ void conv_split2(const float* __restrict__ xq, const float* __restrict__ xkv,
                            unsigned short* __restrict__ qhi, unsigned short* __restrict__ qlo,
                            unsigned short* __restrict__ khi, unsigned short* __restrict__ klo,
                            int n4) {
  int i = blockIdx.x * 256 + threadIdx.x;
  const float* x = (i < n4) ? xq : xkv;
  unsigned short* hi = (i < n4) ? qhi : khi;
  unsigned short* lo = (i < n4) ? qlo : klo;
  int ii = (i < n4) ? i : i - n4;
  float4 v = ((const float4*)x)[ii];
  ushort4 h, l;
  float f;
  f = v.x; h.x = f2bf(f); l.x = f2bf(f - bf2f(h.x));
  f = v.y; h.y = f2bf(f); l.y = f2bf(f - bf2f(h.y));
  f = v.z; h.z = f2bf(f); l.z = f2bf(f - bf2f(h.z));
  f = v.w; h.w = f2bf(f); l.w = f2bf(f - bf2f(h.w));
  ((ushort4*)hi)[ii] = h;
  ((ushort4*)lo)[ii] = l;
}

// All four W (512x512 f32 [k][n]) -> transposed hi/lo bf16 Wt[n][k], via LDS tile
// transpose (coalesced reads AND writes). Grid: 4 mats x 64 tiles of 64x64.
__global__ void conv_wt4(const float* __restrict__ W0, const float* __restrict__ W1,
                         const float* __restrict__ W2, const float* __restrict__ W3,
                         unsigned short* __restrict__ WT) {
  __shared__ float t[64][65];
  int bx = blockIdx.x;
  int w = bx >> 6, tile = bx & 63;
  int k0 = (tile >> 3) << 6, n0 = (tile & 7) << 6;
  const float* W = (w == 0) ? W0 : (w == 1) ? W1 : (w == 2) ? W2 : W3;
  unsigned short* hi = WT + (size_t)(2 * w) * 262144;
  unsigned short* lo = hi + 262144;
  int tid = threadIdx.x;
#pragma unroll
  for (int j = 0; j < 4; ++j) {
    int i = tid + (j << 8);
    int rr = i >> 4, c4 = (i & 15) << 2;
    float4 v = *(const float4*)&W[(size_t)(k0 + rr) * 512 + n0 + c4];
    t[rr][c4 + 0] = v.x; t[rr][c4 + 1] = v.y;
    t[rr][c4 + 2] = v.z; t[rr][c4 + 3] = v.w;
  }
  __syncthreads();
#pragma unroll
  for (int j = 0; j < 4; ++j) {
    int i = tid + (j << 8);
    int nn = i >> 4, k4 = (i & 15) << 2;
    ushort4 h, l;
    float f;
    f = t[k4 + 0][nn]; h.x = f2bf(f); l.x = f2bf(f - bf2f(h.x));
    f = t[k4 + 1][nn]; h.y = f2bf(f); l.y = f2bf(f - bf2f(h.y));
    f = t[k4 + 2][nn]; h.z = f2bf(f); l.z = f2bf(f - bf2f(h.z));
    f = t[k4 + 3][nn]; h.w = f2bf(f); l.w = f2bf(f - bf2f(h.w));
    size_t o = (size_t)(n0 + nn) * 512 + k0 + k4;
    *(ushort4*)(hi + o) = h;
    *(ushort4*)(lo + o) = l;
  }
}

// twiddle table T[r] = exp(-2*pi*i*r/4096), r=0..3071 (double-precision generated)
__global__ void make_tw(float2* __restrict__ T) {
  int r = blockIdx.x * 256 + threadIdx.x;
  if (r < 3072) {
    double a = -2.0 * 3.14159265358979323846 * (double)r / 4096.0;
    T[r] = make_float2((float)cos(a), (float)sin(a));
  }
}

// ---------------- fused Q+K GEMM (bf16x3, mode 0), 1024 wgs ----------------
// C(16384x512) = A @ W + bias with A=[Ahi|Ahi|Alo], B=[Bhi|Blo|Bhi] along K (3 segs).
// 128x128 tile, BK=64, 4 waves (2x2), mfma 16x16x32. C layout: C[(b*512+n)*4096+t].
// XCD swizzle: each XCD owns a contiguous bm-range -> A-panels fetched once.
__global__ __launch_bounds__(256, 2)
void qk_gemm(const unsigned short* __restrict__ AqHi, const unsigned short* __restrict__ AqLo,
             const unsigned short* __restrict__ AkvHi, const unsigned short* __restrict__ AkvLo,
             const unsigned short* __restrict__ WT,
             const float* __restrict__ bq, const float* __restrict__ bk,
             float* __restrict__ QT, float* __restrict__ KT) {
  __shared__ short As[128 * 64];
  __shared__ short Bs[128 * 64];
  int bx = xcd_swz(blockIdx.x, 128);  // 1024 wgs
  int op = bx >> 9;  // 0 = Q, 1 = K
  bx &= 511;
  const unsigned short* Ahi = op ? AkvHi : AqHi;
  const unsigned short* Alo = op ? AkvLo : AqLo;
  const unsigned short* Bhi = WT + (op ? 2 * 262144 : 0);
  const unsigned short* Blo = Bhi + 262144;
  const float* bias = op ? bk : bq;
  float* C = op ? KT : QT;

  int bm = bx >> 2, bn = bx & 3;
  int m0 = bm << 7, n0 = bn << 7;
  int tid = threadIdx.x;
  int lane = tid & 63, wv = tid >> 6;
  int wm = wv >> 1, wn = wv & 1;

  const f32x4 zz = {0.f, 0.f, 0.f, 0.f};
  f32x4 acc[4][4];
#pragma unroll
  for (int i = 0; i < 4; ++i)
#pragma unroll
    for (int j = 0; j < 4; ++j) acc[i][j] = zz;

  int srow = tid >> 3;
  int sk = (tid & 7) << 3;
  for (int ks = 0; ks < 24; ++ks) {
    int seg = ks >> 3;
    int kb = (ks & 7) << 6;
    const unsigned short* Aseg = (seg == 2) ? Alo : Ahi;
    const unsigned short* Bseg = (seg == 1) ? Blo : Bhi;
#pragma unroll
    for (int i = 0; i < 4; ++i) {
      int r = (i << 5) + srow;
      const unsigned short* ga = Aseg + (size_t)(m0 + r) * 512 + kb + sk;
      const unsigned short* gb = Bseg + (size_t)(n0 + r) * 512 + kb + sk;
      char* la = (char*)As + (i << 12) + (wv << 10);
      char* lb = (char*)Bs + (i << 12) + (wv << 10);
      __builtin_amdgcn_global_load_lds((const __attribute__((address_space(1))) void*)ga,
                                       (__attribute__((address_space(3))) void*)la, 16, 0, 0);
      __builtin_amdgcn_global_load_lds((const __attribute__((address_space(1))) void*)gb,
                                       (__attribute__((address_space(3))) void*)lb, 16, 0, 0);
    }
    __syncthreads();
#pragma unroll
    for (int kk = 0; kk < 2; ++kk) {
      bf16x8 af[4], bfr[4];
      int krd = (kk << 5) + ((lane >> 4) << 3);
#pragma unroll
      for (int mi = 0; mi < 4; ++mi)
        af[mi] = *(const bf16x8*)&As[((wm << 6) + (mi << 4) + (lane & 15)) * 64 + krd];
#pragma unroll
      for (int ni = 0; ni < 4; ++ni)
        bfr[ni] = *(const bf16x8*)&Bs[((wn << 6) + (ni << 4) + (lane & 15)) * 64 + krd];
#pragma unroll
      for (int mi = 0; mi < 4; ++mi)
#pragma unroll
        for (int ni = 0; ni < 4; ++ni)
          acc[mi][ni] = __builtin_amdgcn_mfma_f32_16x16x32_bf16(af[mi], bfr[ni], acc[mi][ni], 0, 0, 0);
    }
    __syncthreads();
  }

#pragma unroll
  for (int mi = 0; mi < 4; ++mi) {
    int mrow0 = m0 + (wm << 6) + (mi << 4) + ((lane >> 4) << 2);
    int bq_ = mrow0 >> 12;
    int t0 = mrow0 & 4095;
#pragma unroll
    for (int ni = 0; ni < 4; ++ni) {
      int col = n0 + (wn << 6) + (ni << 4) + (lane & 15);
      float bv = bias[col];
      f32x4 v = acc[mi][ni];
      v.x += bv; v.y += bv; v.z += bv; v.w += bv;
      *(f32x4*)&C[((size_t)(bq_ * 512 + col)) * 4096 + t0] = v;
    }
  }
}

// ---------------- generic GEMM for V (mode 1) and OUT (mode 2), nseg=1, 512 wgs ----------------
__global__ __launch_bounds__(256, 2)
void gemm_bf16(const unsigned short* __restrict__ Ahi,
               const unsigned short* __restrict__ Bhi,
               const float* __restrict__ bias, float* __restrict__ C, int mode) {
  __shared__ short As[128 * 64];
  __shared__ short Bs[128 * 64];
  int bx = xcd_swz(blockIdx.x, 64);  // 512 wgs
  int bm = bx >> 2, bn = bx & 3;
  int m0 = bm << 7, n0 = bn << 7;
  int tid = threadIdx.x;
  int lane = tid & 63, wv = tid >> 6;
  int wm = wv >> 1, wn = wv & 1;

  const f32x4 zz = {0.f, 0.f, 0.f, 0.f};
  f32x4 acc[4][4];
#pragma unroll
  for (int i = 0; i < 4; ++i)
#pragma unroll
    for (int j = 0; j < 4; ++j) acc[i][j] = zz;

  int srow = tid >> 3;
  int sk = (tid & 7) << 3;
  for (int ks = 0; ks < 8; ++ks) {
    int kb = ks << 6;
#pragma unroll
    for (int i = 0; i < 4; ++i) {
      int r = (i << 5) + srow;
      const unsigned short* ga = Ahi + (size_t)(m0 + r) * 512 + kb + sk;
      const unsigned short* gb = Bhi + (size_t)(n0 + r) * 512 + kb + sk;
      char* la = (char*)As + (i << 12) + (wv << 10);
      char* lb = (char*)Bs + (i << 12) + (wv << 10);
      __builtin_amdgcn_global_load_lds((const __attribute__((address_space(1))) void*)ga,
                                       (__attribute__((address_space(3))) void*)la, 16, 0, 0);
      __builtin_amdgcn_global_load_lds((const __attribute__((address_space(1))) void*)gb,
                                       (__attribute__((address_space(3))) void*)lb, 16, 0, 0);
    }
    __syncthreads();
#pragma unroll
    for (int kk = 0; kk < 2; ++kk) {
      bf16x8 af[4], bfr[4];
      int krd = (kk << 5) + ((lane >> 4) << 3);
#pragma unroll
      for (int mi = 0; mi < 4; ++mi)
        af[mi] = *(const bf16x8*)&As[((wm << 6) + (mi << 4) + (lane & 15)) * 64 + krd];
#pragma unroll
      for (int ni = 0; ni < 4; ++ni)
        bfr[ni] = *(const bf16x8*)&Bs[((wn << 6) + (ni << 4) + (lane & 15)) * 64 + krd];
#pragma unroll
      for (int mi = 0; mi < 4; ++mi)
#pragma unroll
        for (int ni = 0; ni < 4; ++ni)
          acc[mi][ni] = __builtin_amdgcn_mfma_f32_16x16x32_bf16(af[mi], bfr[ni], acc[mi][ni], 0, 0, 0);
    }
    __syncthreads();
  }

#pragma unroll
  for (int mi = 0; mi < 4; ++mi) {
    int mrow0 = m0 + (wm << 6) + (mi << 4) + ((lane >> 4) << 2);
    int bq_ = mrow0 >> 12;
    int t0 = mrow0 & 4095;
#pragma unroll
    for (int ni = 0; ni < 4; ++ni) {
      int col = n0 + (wn << 6) + (ni << 4) + (lane & 15);
      float bv = bias[col];
      f32x4 v = acc[mi][ni];
      v.x += bv; v.y += bv; v.z += bv; v.w += bv;
      if (mode == 1) {
        size_t base = (size_t)(bq_ * 8 + (col >> 6)) * 4096;
        int d = col & 63;
        C[(base + t0 + 0) * 64 + d] = v.x;
        C[(base + t0 + 1) * 64 + d] = v.y;
        C[(base + t0 + 2) * 64 + d] = v.z;
        C[(base + t0 + 3) * 64 + d] = v.w;
      } else {
        C[(size_t)(mrow0 + 0) * 512 + col] = v.x;
        C[(size_t)(mrow0 + 1) * 512 + col] = v.y;
        C[(size_t)(mrow0 + 2) * 512 + col] = v.z;
        C[(size_t)(mrow0 + 3) * 512 + col] = v.w;
      }
    }
  }
}

// ---------------- FFT: 6-stage radix-4 DIF, 512 threads (2 butterflies/thr/stage) ----
__device__ __forceinline__ void dif_fft(float* re, float* im, const float2* __restrict__ TW, int tid) {
  int m = 1024, lm = 10;
#pragma unroll
  for (int s = 0; s < 6; ++s) {
    int stw = 1 << (2 * s);
#pragma unroll
    for (int it = 0; it < 2; ++it) {
      int bb = tid + (it << 9);
      int j = bb & (m - 1);
      int g = bb >> lm;
      int i0 = (g << (lm + 2)) + j;
      int p0 = IDX(i0), p1 = IDX(i0 + m), p2 = IDX(i0 + 2 * m), p3 = IDX(i0 + 3 * m);
      float are = re[p0], aim = im[p0];
      float cre = re[p1], cim = im[p1];
      float ere = re[p2], eim = im[p2];
      float gre = re[p3], gim = im[p3];
      float Are = are + ere, Aim = aim + eim;
      float Bre = are - ere, Bim = aim - eim;
      float Cre = cre + gre, Cim = cim + gim;
      float dre = cre - gre, dim_ = cim - gim;
      float Dre = dim_, Dim = -dre;  // -i*(c-g)
      re[p0] = Are + Cre; im[p0] = Aim + Cim;
      float2 w1 = TW[j * stw], w2 = TW[2 * j * stw], w3 = TW[3 * j * stw];
      float xr = Bre + Dre, xi = Bim + Dim;
      re[p1] = xr * w1.x - xi * w1.y; im[p1] = xr * w1.y + xi * w1.x;
      xr = Are - Cre; xi = Aim - Cim;
      re[p2] = xr * w2.x - xi * w2.y; im[p2] = xr * w2.y + xi * w2.x;
      xr = Bre - Dre; xi = Bim - Dim;
      re[p3] = xr * w3.x - xi * w3.y; im[p3] = xr * w3.y + xi * w3.x;
    }
    __syncthreads();
    m >>= 2; lm -= 2;
  }
}

// Packed FFT of z = q + i*k per (b,h,d); one wg (512 thr) handles (b,h) x 2 d's,
// accumulating Qf*conj(Kf) in registers, writes partial (by LDS position p, coalesced).
// 1024 wgs = 32 (b,h) x 32 parts; NO atomics.
__global__ __launch_bounds__(512, 4)
void fft_corr(const float* __restrict__ QT, const float* __restrict__ KT,
              const float2* __restrict__ TW, float* __restrict__ PpartRe,
              float* __restrict__ PpartIm) {
  __shared__ float re[LDSN];
  __shared__ float im[LDSN];
  int wg = blockIdx.x;
  int bh = wg >> 5;
  int d0 = (wg & 31) << 1;
  int tid = threadIdx.x;
  const float* qb = QT + (size_t)bh * 64 * 4096;
  const float* kb = KT + (size_t)bh * 64 * 4096;
  float accR[8], accI[8];
#pragma unroll
  for (int i = 0; i < 8; ++i) { accR[i] = 0.f; accI[i] = 0.f; }
  for (int dd = 0; dd < 2; ++dd) {
    __syncthreads();  // prior extraction reads of re/im done
    const float4* q4 = (const float4*)(qb + (size_t)(d0 + dd) * 4096);
    const float4* k4 = (const float4*)(kb + (size_t)(d0 + dd) * 4096);
#pragma unroll
    for (int i = 0; i < 2; ++i) {
      int e4 = tid + (i << 9);
      float4 qv = q4[e4], kv = k4[e4];
      int e = e4 << 2;
      re[IDX(e + 0)] = qv.x; im[IDX(e + 0)] = kv.x;
      re[IDX(e + 1)] = qv.y; im[IDX(e + 1)] = kv.y;
      re[IDX(e + 2)] = qv.z; im[IDX(e + 2)] = kv.z;
      re[IDX(e + 3)] = qv.w; im[IDX(e + 3)] = kv.w;
    }
    __syncthreads();
    dif_fft(re, im, TW, tid);
    // position p holds Z[f], f = rev4(p); pair with f' = (N-f)%N at position rev4(f')
#pragma unroll
    for (int j = 0; j < 8; ++j) {
      int p = tid + (j << 9);
      int f = rev4_12(p);
      int fn = (4096 - f) & 4095;
      int pn = rev4_12(fn);
      float zr = re[IDX(p)], zi = im[IDX(p)];
      float wr = re[IDX(pn)], wi = im[IDX(pn)];
      float qre = 0.5f * (zr + wr), qim = 0.5f * (zi - wi);
      float kre = 0.5f * (zi + wi), kim = 0.5f * (wr - zr);
      accR[j] += qre * kre + qim * kim;   // Re(Qf*conj(Kf))
      accI[j] += qim * kre - qre * kim;   // Im(Qf*conj(Kf))
    }
  }
  float* pR = PpartRe + (size_t)wg * 4096;
  float* pI = PpartIm + (size_t)wg * 4096;
#pragma unroll
  for (int j = 0; j < 8; ++j) {
    int p = tid + (j << 9);
    pR[p] = accR[j];
    pI[p] = accI[j];
  }
}

// Reduce 32 partials per (b,h) -> Psum, float4. Grid 128 = 32 bh x 4 chunks of 1024 p.
__global__ void reduce_p(const float* __restrict__ PpartRe, const float* __restrict__ PpartIm,
                         float* __restrict__ PsumRe, float* __restrict__ PsumIm) {
  int wg = blockIdx.x;
  int bh = wg >> 2;
  int p4 = ((wg & 3) << 8) + threadIdx.x;  // float4 index 0..1023
  const float4* bR = (const float4*)(PpartRe + (size_t)bh * 32 * 4096);
  const float4* bI = (const float4*)(PpartIm + (size_t)bh * 32 * 4096);
  float4 sr = make_float4(0.f, 0.f, 0.f, 0.f);
  float4 si = make_float4(0.f, 0.f, 0.f, 0.f);
#pragma unroll
  for (int part = 0; part < 32; ++part) {
    float4 a = bR[part * 1024 + p4];
    float4 b = bI[part * 1024 + p4];
    sr.x += a.x; sr.y += a.y; sr.z += a.z; sr.w += a.w;
    si.x += b.x; si.y += b.y; si.z += b.z; si.w += b.w;
  }
  ((float4*)(PsumRe + (size_t)bh * 4096))[p4] = sr;
  ((float4*)(PsumIm + (size_t)bh * 4096))[p4] = si;
}

// Inverse FFT via conj + forward DIF (512 thr); corr(tau=rev4(p)) = re[p]/(4096*64).
// Top-8 via per-pass wave shuffle reduce, then softmax.
__global__ __launch_bounds__(512, 4)
void ifft_topk(const float* __restrict__ PsumRe, const float* __restrict__ PsumIm,
               const float2* __restrict__ TW, float* __restrict__ attnW, int* __restrict__ delays) {
  __shared__ float re[LDSN];
  __shared__ float im[LDSN];
  __shared__ float wval[8];
  __shared__ int widx[8], wpos[8];
  int bh = blockIdx.x, tid = threadIdx.x;
  int lane = tid & 63, wv = tid >> 6;
  const float4* pr4 = (const float4*)(PsumRe + (size_t)bh * 4096);
  const float4* pi4 = (const float4*)(PsumIm + (size_t)bh * 4096);
#pragma unroll
  for (int i = 0; i < 2; ++i) {
    int e4 = tid + (i << 9);
    float4 a = pr4[e4], b = pi4[e4];
    int fb = rev4_12(e4 << 2);  // rev4 of (e4*4 + j) = fb | (j<<10)
    re[IDX(fb + 0 * 1024)] = a.x; im[IDX(fb + 0 * 1024)] = -b.x;
    re[IDX(fb + 1 * 1024)] = a.y; im[IDX(fb + 1 * 1024)] = -b.y;
    re[IDX(fb + 2 * 1024)] = a.z; im[IDX(fb + 2 * 1024)] = -b.z;
    re[IDX(fb + 3 * 1024)] = a.w; im[IDX(fb + 3 * 1024)] = -b.w;
  }
  __syncthreads();
  dif_fft(re, im, TW, tid);
  const float SC = 1.0f / 262144.0f;  // 1/(L*Dh)
  float topv[8]; int topi[8];
#pragma unroll
  for (int pass = 0; pass < 8; ++pass) {
    float bv = -3.4e38f; int bi = 1 << 30; int bp = 0;
#pragma unroll
    for (int i = 0; i < 8; ++i) {
      int p = tid + (i << 9);
      float v = re[IDX(p)];
      int tau = rev4_12(p);
      if (v > bv || (v == bv && tau < bi)) { bv = v; bi = tau; bp = p; }
    }
#pragma unroll
    for (int off = 32; off > 0; off >>= 1) {
      float ov = __shfl_down(bv, off);
      int oi = __shfl_down(bi, off);
      int opp = __shfl_down(bp, off);
      if (ov > bv || (ov == bv && oi < bi)) { bv = ov; bi = oi; bp = opp; }
    }
    if (lane == 0) { wval[wv] = bv; widx[wv] = bi; wpos[wv] = bp; }
    __syncthreads();
    if (tid == 0) {
#pragma unroll
      for (int w2 = 1; w2 < 8; ++w2) {
        if (wval[w2] > bv || (wval[w2] == bv && widx[w2] < bi)) {
          bv = wval[w2]; bi = widx[w2]; bp = wpos[w2];
        }
      }
      topv[pass] = bv * SC;
      topi[pass] = bi;
      re[IDX(bp)] = -3.4e38f;
    }
    __syncthreads();
  }
  if (tid == 0) {
    float mx = topv[0];  // pass 0 = global max
    float ex[8], s = 0.f;
    for (int k = 0; k < 8; ++k) { ex[k] = expf(topv[k] - mx); s += ex[k]; }
    float inv = 1.0f / s;
    for (int k = 0; k < 8; ++k) {
      attnW[bh * 8 + k] = ex[k] * inv;
      delays[bh * 8 + k] = topi[k];
    }
  }
}

// out[b,h,t,:] = sum_k attn_k * V[b,h,(t-d_k)%L,:]; write bf16 into final-GEMM A layout.
__global__ void gather_av(const float* __restrict__ V, const float* __restrict__ attnW,
                          const int* __restrict__ delays, unsigned short* __restrict__ Ahi) {
  int blk = blockIdx.x;
  int bh = blk >> 8, tb = blk & 255;
  int tid = threadIdx.x;
  int tt = tid >> 4, dq = tid & 15;
  int t = (tb << 4) + tt;
  const float4* Vb = (const float4*)(V + (size_t)bh * 4096 * 64);
  float4 acc = make_float4(0.f, 0.f, 0.f, 0.f);
#pragma unroll
  for (int kk = 0; kk < 8; ++kk) {
    float w = attnW[bh * 8 + kk];
    int dl = delays[bh * 8 + kk];
    int row = (t - dl) & 4095;
    float4 x = Vb[row * 16 + dq];
    acc.x += w * x.x; acc.y += w * x.y; acc.z += w * x.z; acc.w += w * x.w;
  }
  int b = bh >> 3, h = bh & 7;
  size_t o = ((size_t)((b << 12) + t)) * 512 + (h << 6) + (dq << 2);
  ushort4 hv;
  hv.x = f2bf(acc.x); hv.y = f2bf(acc.y); hv.z = f2bf(acc.z); hv.w = f2bf(acc.w);
  *(ushort4*)(Ahi + o) = hv;
}

// ---------------- orchestration ----------------
extern "C" void kernel_launch(void* const* d_in, const int* in_sizes, int n_in,
                              void* d_out, int out_size, void* d_ws, size_t ws_size,
                              hipStream_t stream) {
  (void)in_sizes; (void)n_in; (void)out_size; (void)ws_size;
  const float* x_q = (const float*)d_in[0];
  const float* x_kv = (const float*)d_in[1];
  const float* Wq = (const float*)d_in[2];
  const float* bq = (const float*)d_in[3];
  const float* Wk = (const float*)d_in[4];
  const float* bk = (const float*)d_in[5];
  const float* Wv = (const float*)d_in[6];
  const float* bv = (const float*)d_in[7];
  const float* Wo = (const float*)d_in[8];
  const float* bo = (const float*)d_in[9];
  float* out = (float*)d_out;
  char* ws = (char*)d_ws;

  // workspace layout (~137.1 MiB)
  // 0-16    AqHi          -> Vbuf (0-32, after qk_gemm)
  // 16-32   AqLo          -> (Vbuf tail)
  // 36-52   AkvHi         -> PpartRe (after v_gemm) -> Aattn (after reduce_p)
  // 52-68   AkvLo         -> PpartIm
  // 68-72   WTb (8 x 512x512 bf16)
  // 72-104  QT            -> PsumRe/PsumIm (after fft_corr)
  // 104-136 KT
  // 137+    attnW, delays, TW
  unsigned short* AqHi  = (unsigned short*)(ws + 0 * MiB);
  unsigned short* AqLo  = (unsigned short*)(ws + 16 * MiB);
  float*          Vbuf  = (float*)(ws + 0 * MiB);
  unsigned short* AkvHi = (unsigned short*)(ws + 36 * MiB);
  unsigned short* AkvLo = (unsigned short*)(ws + 52 * MiB);
  float* PpartRe = (float*)(ws + 36 * MiB);
  float* PpartIm = (float*)(ws + 52 * MiB);
  unsigned short* Aattn = (unsigned short*)(ws + 36 * MiB);
  unsigned short* WTb   = (unsigned short*)(ws + 68 * MiB);
  float* QT    = (float*)(ws + 72 * MiB);
  float* KT    = (float*)(ws + 104 * MiB);
  float* PsumRe = (float*)(ws + 72 * MiB);
  float* PsumIm = (float*)(ws + 73 * MiB);
  float* attnW = (float*)(ws + 137 * MiB);
  int*   delays = (int*)(ws + 137 * MiB + 4096);
  float2* TW   = (float2*)(ws + 137 * MiB + 8192);

  int n4 = (16384 * 512) / 4;
  conv_split2<<<dim3(2 * n4 / 256), dim3(256), 0, stream>>>(x_q, x_kv, AqHi, AqLo, AkvHi, AkvLo, n4);
  conv_wt4<<<dim3(256), dim3(256), 0, stream>>>(Wq, Wk, Wv, Wo, WTb);
  make_tw<<<dim3(12), dim3(256), 0, stream>>>(TW);

  // Q and K projections fused (1024 wgs); V after (writes over dead Aq region).
  qk_gemm<<<dim3(1024), dim3(256), 0, stream>>>(AqHi, AqLo, AkvHi, AkvLo, WTb, bq, bk, QT, KT);
  gemm_bf16<<<dim3(512), dim3(256), 0, stream>>>(AkvHi, WTb + 4 * 262144, bv, Vbuf, 1);

  fft_corr<<<dim3(1024), dim3(512), 0, stream>>>(QT, KT, TW, PpartRe, PpartIm);
  reduce_p<<<dim3(128), dim3(256), 0, stream>>>(PpartRe, PpartIm, PsumRe, PsumIm);
  ifft_topk<<<dim3(32), dim3(512), 0, stream>>>(PsumRe, PsumIm, TW, attnW, delays);
  gather_av<<<dim3(8192), dim3(256), 0, stream>>>(Vbuf, attnW, delays, Aattn);

  // out = gathered @ Wo + bo (plain bf16)
  gemm_bf16<<<dim3(512), dim3(256), 0, stream>>>(Aattn, WTb + 6 * 262144, bo, out, 2);
}

// Round 7
// 222.718 us; speedup vs baseline: 4.6077x; 1.0485x over previous
//
#include <hip/hip_runtime.h>
#include <hip/hip_bf16.h>

// AutoCorrelation layer: QKV proj (bf16x3 MFMA GEMM; Q+K on a 256^2 8-phase
// counted-vmcnt schedule) -> packed FFT cross-corr (partials + reduce + ifft,
// NO global atomics) -> top-8 + softmax -> delay-gather of V -> output proj.
// B=4, L=4096, D_MODEL=512, NHEAD=8, DH=64, TOPK=8.

#define MiB (1024ull * 1024ull)

typedef __attribute__((ext_vector_type(8))) short bf16x8;
typedef __attribute__((ext_vector_type(4))) float f32x4;
static_assert(sizeof(bf16x8) == 16, "bf16x8 must be 16B");

__device__ __forceinline__ unsigned short f2bf(float f) {
  unsigned u = __float_as_uint(f);
  unsigned r = (u + 0x7FFFu + ((u >> 16) & 1u)) >> 16;  // RN-even
  return (unsigned short)r;
}
__device__ __forceinline__ float bf2f(unsigned short h) {
  return __uint_as_float(((unsigned)h) << 16);
}
// base-4 digit reversal of a 12-bit index (involution)
__device__ __forceinline__ int rev4_12(int x) {
  unsigned r = __brev((unsigned)x) >> 20;
  return (int)(((r & 0xAAAu) >> 1) | ((r & 0x555u) << 1));
}
// LDS pad: +1 float per 32 to break power-of-2 bank patterns
#define IDX(e) ((e) + ((e) >> 5))
#define LDSN (4095 + (4095 >> 5) + 1)

// XCD-aware bijective swizzle (nwg % 8 == 0): XCD x owns contiguous logical chunk.
__device__ __forceinline__ int xcd_swz(int bid, int cpx) {
  return (bid & 7) * cpx + (bid >> 3);
}

#define BARRIER() do { asm volatile("" ::: "memory"); __builtin_amdgcn_s_barrier(); asm volatile("" ::: "memory"); } while (0)
#define WAITV6() asm volatile("s_waitcnt vmcnt(6)" ::: "memory")

// ---------------- conversion kernels ----------------

__global__ void conv_split2(const float* __restrict__ xq, const float* __restrict__ xkv,
                            unsigned short* __restrict__ qhi, unsigned short* __restrict__ qlo,
                            unsigned short* __restrict__ khi, unsigned short* __restrict__ klo,
                            int n4) {
  int i = blockIdx.x * 256 + threadIdx.x;
  const float* x = (i < n4) ? xq : xkv;
  unsigned short* hi = (i < n4) ? qhi : khi;
  unsigned short* lo = (i < n4) ? qlo : klo;
  int ii = (i < n4) ? i : i - n4;
  float4 v = ((const float4*)x)[ii];
  ushort4 h, l;
  float f;
  f = v.x; h.x = f2bf(f); l.x = f2bf(f - bf2f(h.x));
  f = v.y; h.y = f2bf(f); l.y = f2bf(f - bf2f(h.y));
  f = v.z; h.z = f2bf(f); l.z = f2bf(f - bf2f(h.z));
  f = v.w; h.w = f2bf(f); l.w = f2bf(f - bf2f(h.w));
  ((ushort4*)hi)[ii] = h;
  ((ushort4*)lo)[ii] = l;
}

// All four W (512x512 f32 [k][n]) -> transposed hi/lo bf16 Wt[n][k], via LDS tile
// transpose. Grid: 4 mats x 64 tiles of 64x64.
__global__ void conv_wt4(const float* __restrict__ W0, const float* __restrict__ W1,
                         const float* __restrict__ W2, const float* __restrict__ W3,
                         unsigned short* __restrict__ WT) {
  __shared__ float t[64][65];
  int bx = blockIdx.x;
  int w = bx >> 6, tile = bx & 63;
  int k0 = (tile >> 3) << 6, n0 = (tile & 7) << 6;
  const float* W = (w == 0) ? W0 : (w == 1) ? W1 : (w == 2) ? W2 : W3;
  unsigned short* hi = WT + (size_t)(2 * w) * 262144;
  unsigned short* lo = hi + 262144;
  int tid = threadIdx.x;
#pragma unroll
  for (int j = 0; j < 4; ++j) {
    int i = tid + (j << 8);
    int rr = i >> 4, c4 = (i & 15) << 2;
    float4 v = *(const float4*)&W[(size_t)(k0 + rr) * 512 + n0 + c4];
    t[rr][c4 + 0] = v.x; t[rr][c4 + 1] = v.y;
    t[rr][c4 + 2] = v.z; t[rr][c4 + 3] = v.w;
  }
  __syncthreads();
#pragma unroll
  for (int j = 0; j < 4; ++j) {
    int i = tid + (j << 8);
    int nn = i >> 4, k4 = (i & 15) << 2;
    ushort4 h, l;
    float f;
    f = t[k4 + 0][nn]; h.x = f2bf(f); l.x = f2bf(f - bf2f(h.x));
    f = t[k4 + 1][nn]; h.y = f2bf(f); l.y = f2bf(f - bf2f(h.y));
    f = t[k4 + 2][nn]; h.z = f2bf(f); l.z = f2bf(f - bf2f(h.z));
    f = t[k4 + 3][nn]; h.w = f2bf(f); l.w = f2bf(f - bf2f(h.w));
    size_t o = (size_t)(n0 + nn) * 512 + k0 + k4;
    *(ushort4*)(hi + o) = h;
    *(ushort4*)(lo + o) = l;
  }
}

// twiddle table T[r] = exp(-2*pi*i*r/4096), r=0..3071 (double-precision generated)
__global__ void make_tw(float2* __restrict__ T) {
  int r = blockIdx.x * 256 + threadIdx.x;
  if (r < 3072) {
    double a = -2.0 * 3.14159265358979323846 * (double)r / 4096.0;
    T[r] = make_float2((float)cos(a), (float)sin(a));
  }
}

// ---------------- fused Q+K GEMM: 256^2 tile, 8-wave, 4-phase/K-tile, counted vmcnt ----
// C(16384x512) = A @ W + bias, 3 K-segments (Ahi*Bhi, Ahi*Blo, Alo*Bhi), K'=1536.
// Grid 256 wgs x 512 thr = 1 block/CU. BM=BN=256, BK=64; waves 2(M)x4(N), each 128x64 out.
// LDS 128 KiB: 2 bufs x {A 256x64, B 256x64} bf16. XOR-swizzle col16 ^= row&7 on
// both write (pre-swizzled global src, linear gload_lds dest) and ds_read.
// Stage schedule per tile t (cur buf o): ph0 -> A-h1,h3 of t+1 (other buf);
// ph1 -> B rows 0..127 of t+2 (o); ph2 -> B rows 128..255 of t+2 (o);
// ph3 -> A-h0,h2 of t+2 (o); vmcnt(6) once per tile. Raw s_barrier only.
__global__ __launch_bounds__(512, 2)
void qk_gemm8(const unsigned short* __restrict__ AqHi, const unsigned short* __restrict__ AqLo,
              const unsigned short* __restrict__ AkvHi, const unsigned short* __restrict__ AkvLo,
              const unsigned short* __restrict__ WT,
              const float* __restrict__ bq, const float* __restrict__ bk,
              float* __restrict__ QT, float* __restrict__ KT) {
  __shared__ __align__(16) char lds[131072];
  int tid = threadIdx.x;
  int lane = tid & 63, wv = tid >> 6;
  int wm = wv >> 2, wn = wv & 3;

  int sw = xcd_swz(blockIdx.x, 32);  // 256 wgs
  int op = sw >> 7;                  // 0 = Q, 1 = K
  int r = sw & 127;
  int m0 = (r >> 1) << 8;            // 64 M-tiles
  int n0 = (r & 1) << 8;             // 2 N-tiles

  const unsigned short* Ahi = op ? AkvHi : AqHi;
  const unsigned short* Alo = op ? AkvLo : AqLo;
  const unsigned short* Bhi = WT + (op ? 2 * 262144 : 0);
  const unsigned short* Blo = Bhi + 262144;
  const float* bias = op ? bk : bq;
  float* C = op ? KT : QT;

  // per-thread swizzled read offsets (bytes within a 16-row fragment row-block)
  int aoff0 = ((lane & 15) << 7) + ((((lane >> 4) + 0) ^ (lane & 7)) << 4);  // ks=0
  int aoff1 = ((lane & 15) << 7) + ((((lane >> 4) + 4) ^ (lane & 7)) << 4);  // ks=1
  // per-thread stage source pieces
  int src_row = tid >> 3;                     // 0..63 row within 64-row chunk
  int src_col = (tid & 7) ^ (src_row & 7);    // inverse-swizzled 16B block

  f32x4 acc[8][4];
  const f32x4 zz = {0.f, 0.f, 0.f, 0.f};
#pragma unroll
  for (int i = 0; i < 8; ++i)
#pragma unroll
    for (int j = 0; j < 4; ++j) acc[i][j] = zz;

  // seg pointers per K-tile v (0..23): A: seg0,1=hi seg2=lo; B: seg0,2=hi seg1=lo
  auto APTR = [&](int v) {
    const unsigned short* p = (v >= 16) ? Alo : Ahi;
    return p + (size_t)m0 * 512 + ((v & 7) << 6);
  };
  auto BPTR = [&](int v) {
    const unsigned short* p = (v >= 8 && v < 16) ? Blo : Bhi;
    return p + (size_t)n0 * 512 + ((v & 7) << 6);
  };
  // stage one 8KB chunk (64 rows x 128B): gbase already includes tile row base + kb
  auto STAGE = [&](const unsigned short* gbase, int R0, int ldsOff) {
    const unsigned short* ga = gbase + (size_t)(R0 + src_row) * 512 + (src_col << 3);
    char* la = lds + ldsOff + (R0 << 7) + (wv << 10);  // wave-uniform base
    __builtin_amdgcn_global_load_lds((const __attribute__((address_space(1))) void*)ga,
                                     (__attribute__((address_space(3))) void*)la, 16, 0, 0);
  };
#define RDA(o, mi, ks) (*(const bf16x8*)(lds + (o) + (wm << 14) + ((mi) << 11) + aoff##ks))
#define RDB(o, ni, ks) (*(const bf16x8*)(lds + (o) + 32768 + (wn << 13) + ((ni) << 11) + aoff##ks))
#define MFMA_PAIR(mi0, A0, A1)                                                              \
  __builtin_amdgcn_s_setprio(1);                                                            \
  _Pragma("unroll") for (int ks = 0; ks < 2; ++ks) {                                        \
    _Pragma("unroll") for (int ni = 0; ni < 4; ++ni) {                                      \
      acc[mi0][ni] = __builtin_amdgcn_mfma_f32_16x16x32_bf16(A0[ks], b[ni][ks], acc[mi0][ni], 0, 0, 0);          \
      acc[mi0 + 1][ni] = __builtin_amdgcn_mfma_f32_16x16x32_bf16(A1[ks], b[ni][ks], acc[mi0 + 1][ni], 0, 0, 0);  \
    }                                                                                       \
  }                                                                                         \
  __builtin_amdgcn_s_setprio(0)

  // -------- prologue: tile0 full (8) + tile1's B all + A-h0,h2 (6) --------
  STAGE(BPTR(0), 0, 32768);   STAGE(BPTR(0), 64, 32768);
  STAGE(BPTR(0), 128, 32768); STAGE(BPTR(0), 192, 32768);
  STAGE(APTR(0), 0, 0);       STAGE(APTR(0), 64, 0);
  STAGE(APTR(0), 128, 0);     STAGE(APTR(0), 192, 0);
  STAGE(BPTR(1), 0, 65536 + 32768);   STAGE(BPTR(1), 64, 65536 + 32768);
  STAGE(BPTR(1), 128, 65536 + 32768); STAGE(BPTR(1), 192, 65536 + 32768);
  STAGE(APTR(1), 0, 65536);           STAGE(APTR(1), 128, 65536);
  WAITV6();
  BARRIER();

  for (int t = 0; t < 24; ++t) {
    int o = (t & 1) << 16;
    int on = o ^ 65536;
    int t1 = (t + 1 < 24) ? t + 1 : 23;
    int t2 = (t + 2 < 24) ? t + 2 : 23;
    const unsigned short* a1p = APTR(t1);
    const unsigned short* a2p = APTR(t2);
    const unsigned short* b2p = BPTR(t2);

    // ---- ph0: read B(all) + A mi0,1; stage A-h1,h3 of t+1 -> other buf ----
    bf16x8 b[4][2], aA[2][2];
#pragma unroll
    for (int ni = 0; ni < 4; ++ni) { b[ni][0] = RDB(o, ni, 0); b[ni][1] = RDB(o, ni, 1); }
    aA[0][0] = RDA(o, 0, 0); aA[0][1] = RDA(o, 0, 1);
    aA[1][0] = RDA(o, 1, 0); aA[1][1] = RDA(o, 1, 1);
    STAGE(a1p, 64, on); STAGE(a1p, 192, on);
    BARRIER();
    MFMA_PAIR(0, aA[0], aA[1]);
    BARRIER();

    // ---- ph1: read A mi2,3; stage B rows 0..127 of t+2 -> o ----
    aA[0][0] = RDA(o, 2, 0); aA[0][1] = RDA(o, 2, 1);
    aA[1][0] = RDA(o, 3, 0); aA[1][1] = RDA(o, 3, 1);
    STAGE(b2p, 0, o + 32768); STAGE(b2p, 64, o + 32768);
    BARRIER();
    MFMA_PAIR(2, aA[0], aA[1]);
    BARRIER();

    // ---- ph2: read A mi4,5; stage B rows 128..255 of t+2 -> o ----
    aA[0][0] = RDA(o, 4, 0); aA[0][1] = RDA(o, 4, 1);
    aA[1][0] = RDA(o, 5, 0); aA[1][1] = RDA(o, 5, 1);
    STAGE(b2p, 128, o + 32768); STAGE(b2p, 192, o + 32768);
    BARRIER();
    MFMA_PAIR(4, aA[0], aA[1]);
    BARRIER();

    // ---- ph3: read A mi6,7; stage A-h0,h2 of t+2 -> o; vmcnt(6) ----
    aA[0][0] = RDA(o, 6, 0); aA[0][1] = RDA(o, 6, 1);
    aA[1][0] = RDA(o, 7, 0); aA[1][1] = RDA(o, 7, 1);
    STAGE(a2p, 0, o); STAGE(a2p, 128, o);
    BARRIER();
    MFMA_PAIR(6, aA[0], aA[1]);
    WAITV6();
    BARRIER();
  }
#undef RDA
#undef RDB
#undef MFMA_PAIR

  // -------- epilogue: C[(b*512+n)*4096 + t] --------
#pragma unroll
  for (int mi = 0; mi < 8; ++mi) {
    int mrow0 = m0 + (wm << 7) + (mi << 4) + ((lane >> 4) << 2);
    int bq_ = mrow0 >> 12;
    int t0 = mrow0 & 4095;
#pragma unroll
    for (int ni = 0; ni < 4; ++ni) {
      int col = n0 + (wn << 6) + (ni << 4) + (lane & 15);
      float bv = bias[col];
      f32x4 v = acc[mi][ni];
      v.x += bv; v.y += bv; v.z += bv; v.w += bv;
      *(f32x4*)&C[((size_t)(bq_ * 512 + col)) * 4096 + t0] = v;
    }
  }
}

// ---------------- generic GEMM for V (mode 1) and OUT (mode 2), nseg=1, 512 wgs ----------------
__global__ __launch_bounds__(256, 2)
void gemm_bf16(const unsigned short* __restrict__ Ahi,
               const unsigned short* __restrict__ Bhi,
               const float* __restrict__ bias, float* __restrict__ C, int mode) {
  __shared__ short As[128 * 64];
  __shared__ short Bs[128 * 64];
  int bx = xcd_swz(blockIdx.x, 64);  // 512 wgs
  int bm = bx >> 2, bn = bx & 3;
  int m0 = bm << 7, n0 = bn << 7;
  int tid = threadIdx.x;
  int lane = tid & 63, wv = tid >> 6;
  int wm = wv >> 1, wn = wv & 1;

  const f32x4 zz = {0.f, 0.f, 0.f, 0.f};
  f32x4 acc[4][4];
#pragma unroll
  for (int i = 0; i < 4; ++i)
#pragma unroll
    for (int j = 0; j < 4; ++j) acc[i][j] = zz;

  int srow = tid >> 3;
  int sk = (tid & 7) << 3;
  for (int ks = 0; ks < 8; ++ks) {
    int kb = ks << 6;
#pragma unroll
    for (int i = 0; i < 4; ++i) {
      int r = (i << 5) + srow;
      const unsigned short* ga = Ahi + (size_t)(m0 + r) * 512 + kb + sk;
      const unsigned short* gb = Bhi + (size_t)(n0 + r) * 512 + kb + sk;
      char* la = (char*)As + (i << 12) + (wv << 10);
      char* lb = (char*)Bs + (i << 12) + (wv << 10);
      __builtin_amdgcn_global_load_lds((const __attribute__((address_space(1))) void*)ga,
                                       (__attribute__((address_space(3))) void*)la, 16, 0, 0);
      __builtin_amdgcn_global_load_lds((const __attribute__((address_space(1))) void*)gb,
                                       (__attribute__((address_space(3))) void*)lb, 16, 0, 0);
    }
    __syncthreads();
#pragma unroll
    for (int kk = 0; kk < 2; ++kk) {
      bf16x8 af[4], bfr[4];
      int krd = (kk << 5) + ((lane >> 4) << 3);
#pragma unroll
      for (int mi = 0; mi < 4; ++mi)
        af[mi] = *(const bf16x8*)&As[((wm << 6) + (mi << 4) + (lane & 15)) * 64 + krd];
#pragma unroll
      for (int ni = 0; ni < 4; ++ni)
        bfr[ni] = *(const bf16x8*)&Bs[((wn << 6) + (ni << 4) + (lane & 15)) * 64 + krd];
#pragma unroll
      for (int mi = 0; mi < 4; ++mi)
#pragma unroll
        for (int ni = 0; ni < 4; ++ni)
          acc[mi][ni] = __builtin_amdgcn_mfma_f32_16x16x32_bf16(af[mi], bfr[ni], acc[mi][ni], 0, 0, 0);
    }
    __syncthreads();
  }

#pragma unroll
  for (int mi = 0; mi < 4; ++mi) {
    int mrow0 = m0 + (wm << 6) + (mi << 4) + ((lane >> 4) << 2);
    int bq_ = mrow0 >> 12;
    int t0 = mrow0 & 4095;
#pragma unroll
    for (int ni = 0; ni < 4; ++ni) {
      int col = n0 + (wn << 6) + (ni << 4) + (lane & 15);
      float bv = bias[col];
      f32x4 v = acc[mi][ni];
      v.x += bv; v.y += bv; v.z += bv; v.w += bv;
      if (mode == 1) {
        size_t base = (size_t)(bq_ * 8 + (col >> 6)) * 4096;
        int d = col & 63;
        C[(base + t0 + 0) * 64 + d] = v.x;
        C[(base + t0 + 1) * 64 + d] = v.y;
        C[(base + t0 + 2) * 64 + d] = v.z;
        C[(base + t0 + 3) * 64 + d] = v.w;
      } else {
        C[(size_t)(mrow0 + 0) * 512 + col] = v.x;
        C[(size_t)(mrow0 + 1) * 512 + col] = v.y;
        C[(size_t)(mrow0 + 2) * 512 + col] = v.z;
        C[(size_t)(mrow0 + 3) * 512 + col] = v.w;
      }
    }
  }
}

// ---------------- FFT: 6-stage radix-4 DIF, 512 threads (2 butterflies/thr/stage) ----
__device__ __forceinline__ void dif_fft(float* re, float* im, const float2* __restrict__ TW, int tid) {
  int m = 1024, lm = 10;
#pragma unroll
  for (int s = 0; s < 6; ++s) {
    int stw = 1 << (2 * s);
#pragma unroll
    for (int it = 0; it < 2; ++it) {
      int bb = tid + (it << 9);
      int j = bb & (m - 1);
      int g = bb >> lm;
      int i0 = (g << (lm + 2)) + j;
      int p0 = IDX(i0), p1 = IDX(i0 + m), p2 = IDX(i0 + 2 * m), p3 = IDX(i0 + 3 * m);
      float are = re[p0], aim = im[p0];
      float cre = re[p1], cim = im[p1];
      float ere = re[p2], eim = im[p2];
      float gre = re[p3], gim = im[p3];
      float Are = are + ere, Aim = aim + eim;
      float Bre = are - ere, Bim = aim - eim;
      float Cre = cre + gre, Cim = cim + gim;
      float dre = cre - gre, dim_ = cim - gim;
      float Dre = dim_, Dim = -dre;  // -i*(c-g)
      re[p0] = Are + Cre; im[p0] = Aim + Cim;
      float2 w1 = TW[j * stw], w2 = TW[2 * j * stw], w3 = TW[3 * j * stw];
      float xr = Bre + Dre, xi = Bim + Dim;
      re[p1] = xr * w1.x - xi * w1.y; im[p1] = xr * w1.y + xi * w1.x;
      xr = Are - Cre; xi = Aim - Cim;
      re[p2] = xr * w2.x - xi * w2.y; im[p2] = xr * w2.y + xi * w2.x;
      xr = Bre - Dre; xi = Bim - Dim;
      re[p3] = xr * w3.x - xi * w3.y; im[p3] = xr * w3.y + xi * w3.x;
    }
    __syncthreads();
    m >>= 2; lm -= 2;
  }
}

// Packed FFT of z = q + i*k per (b,h,d); one wg (512 thr) handles (b,h) x 2 d's.
// 1024 wgs = 32 (b,h) x 32 parts; NO atomics.
__global__ __launch_bounds__(512, 4)
void fft_corr(const float* __restrict__ QT, const float* __restrict__ KT,
              const float2* __restrict__ TW, float* __restrict__ PpartRe,
              float* __restrict__ PpartIm) {
  __shared__ float re[LDSN];
  __shared__ float im[LDSN];
  int wg = blockIdx.x;
  int bh = wg >> 5;
  int d0 = (wg & 31) << 1;
  int tid = threadIdx.x;
  const float* qb = QT + (size_t)bh * 64 * 4096;
  const float* kb = KT + (size_t)bh * 64 * 4096;
  float accR[8], accI[8];
#pragma unroll
  for (int i = 0; i < 8; ++i) { accR[i] = 0.f; accI[i] = 0.f; }
  for (int dd = 0; dd < 2; ++dd) {
    __syncthreads();  // prior extraction reads of re/im done
    const float4* q4 = (const float4*)(qb + (size_t)(d0 + dd) * 4096);
    const float4* k4 = (const float4*)(kb + (size_t)(d0 + dd) * 4096);
#pragma unroll
    for (int i = 0; i < 2; ++i) {
      int e4 = tid + (i << 9);
      float4 qv = q4[e4], kv = k4[e4];
      int e = e4 << 2;
      re[IDX(e + 0)] = qv.x; im[IDX(e + 0)] = kv.x;
      re[IDX(e + 1)] = qv.y; im[IDX(e + 1)] = kv.y;
      re[IDX(e + 2)] = qv.z; im[IDX(e + 2)] = kv.z;
      re[IDX(e + 3)] = qv.w; im[IDX(e + 3)] = kv.w;
    }
    __syncthreads();
    dif_fft(re, im, TW, tid);
#pragma unroll
    for (int j = 0; j < 8; ++j) {
      int p = tid + (j << 9);
      int f = rev4_12(p);
      int fn = (4096 - f) & 4095;
      int pn = rev4_12(fn);
      float zr = re[IDX(p)], zi = im[IDX(p)];
      float wr = re[IDX(pn)], wi = im[IDX(pn)];
      float qre = 0.5f * (zr + wr), qim = 0.5f * (zi - wi);
      float kre = 0.5f * (zi + wi), kim = 0.5f * (wr - zr);
      accR[j] += qre * kre + qim * kim;   // Re(Qf*conj(Kf))
      accI[j] += qim * kre - qre * kim;   // Im(Qf*conj(Kf))
    }
  }
  float* pR = PpartRe + (size_t)wg * 4096;
  float* pI = PpartIm + (size_t)wg * 4096;
#pragma unroll
  for (int j = 0; j < 8; ++j) {
    int p = tid + (j << 9);
    pR[p] = accR[j];
    pI[p] = accI[j];
  }
}

// Reduce 32 partials per (b,h) -> Psum, float4. Grid 128 = 32 bh x 4 chunks of 1024 p.
__global__ void reduce_p(const float* __restrict__ PpartRe, const float* __restrict__ PpartIm,
                         float* __restrict__ PsumRe, float* __restrict__ PsumIm) {
  int wg = blockIdx.x;
  int bh = wg >> 2;
  int p4 = ((wg & 3) << 8) + threadIdx.x;  // float4 index 0..1023
  const float4* bR = (const float4*)(PpartRe + (size_t)bh * 32 * 4096);
  const float4* bI = (const float4*)(PpartIm + (size_t)bh * 32 * 4096);
  float4 sr = make_float4(0.f, 0.f, 0.f, 0.f);
  float4 si = make_float4(0.f, 0.f, 0.f, 0.f);
#pragma unroll
  for (int part = 0; part < 32; ++part) {
    float4 a = bR[part * 1024 + p4];
    float4 b = bI[part * 1024 + p4];
    sr.x += a.x; sr.y += a.y; sr.z += a.z; sr.w += a.w;
    si.x += b.x; si.y += b.y; si.z += b.z; si.w += b.w;
  }
  ((float4*)(PsumRe + (size_t)bh * 4096))[p4] = sr;
  ((float4*)(PsumIm + (size_t)bh * 4096))[p4] = si;
}

// Inverse FFT via conj + forward DIF (512 thr); corr(tau=rev4(p)) = re[p]/(4096*64).
__global__ __launch_bounds__(512, 4)
void ifft_topk(const float* __restrict__ PsumRe, const float* __restrict__ PsumIm,
               const float2* __restrict__ TW, float* __restrict__ attnW, int* __restrict__ delays) {
  __shared__ float re[LDSN];
  __shared__ float im[LDSN];
  __shared__ float wval[8];
  __shared__ int widx[8], wpos[8];
  int bh = blockIdx.x, tid = threadIdx.x;
  int lane = tid & 63, wv = tid >> 6;
  const float4* pr4 = (const float4*)(PsumRe + (size_t)bh * 4096);
  const float4* pi4 = (const float4*)(PsumIm + (size_t)bh * 4096);
#pragma unroll
  for (int i = 0; i < 2; ++i) {
    int e4 = tid + (i << 9);
    float4 a = pr4[e4], b = pi4[e4];
    int fb = rev4_12(e4 << 2);  // rev4 of (e4*4 + j) = fb | (j<<10)
    re[IDX(fb + 0 * 1024)] = a.x; im[IDX(fb + 0 * 1024)] = -b.x;
    re[IDX(fb + 1 * 1024)] = a.y; im[IDX(fb + 1 * 1024)] = -b.y;
    re[IDX(fb + 2 * 1024)] = a.z; im[IDX(fb + 2 * 1024)] = -b.z;
    re[IDX(fb + 3 * 1024)] = a.w; im[IDX(fb + 3 * 1024)] = -b.w;
  }
  __syncthreads();
  dif_fft(re, im, TW, tid);
  const float SC = 1.0f / 262144.0f;  // 1/(L*Dh)
  float topv[8]; int topi[8];
#pragma unroll
  for (int pass = 0; pass < 8; ++pass) {
    float bv = -3.4e38f; int bi = 1 << 30; int bp = 0;
#pragma unroll
    for (int i = 0; i < 8; ++i) {
      int p = tid + (i << 9);
      float v = re[IDX(p)];
      int tau = rev4_12(p);
      if (v > bv || (v == bv && tau < bi)) { bv = v; bi = tau; bp = p; }
    }
#pragma unroll
    for (int off = 32; off > 0; off >>= 1) {
      float ov = __shfl_down(bv, off);
      int oi = __shfl_down(bi, off);
      int opp = __shfl_down(bp, off);
      if (ov > bv || (ov == bv && oi < bi)) { bv = ov; bi = oi; bp = opp; }
    }
    if (lane == 0) { wval[wv] = bv; widx[wv] = bi; wpos[wv] = bp; }
    __syncthreads();
    if (tid == 0) {
#pragma unroll
      for (int w2 = 1; w2 < 8; ++w2) {
        if (wval[w2] > bv || (wval[w2] == bv && widx[w2] < bi)) {
          bv = wval[w2]; bi = widx[w2]; bp = wpos[w2];
        }
      }
      topv[pass] = bv * SC;
      topi[pass] = bi;
      re[IDX(bp)] = -3.4e38f;
    }
    __syncthreads();
  }
  if (tid == 0) {
    float mx = topv[0];  // pass 0 = global max
    float ex[8], s = 0.f;
    for (int k = 0; k < 8; ++k) { ex[k] = expf(topv[k] - mx); s += ex[k]; }
    float inv = 1.0f / s;
    for (int k = 0; k < 8; ++k) {
      attnW[bh * 8 + k] = ex[k] * inv;
      delays[bh * 8 + k] = topi[k];
    }
  }
}

// out[b,h,t,:] = sum_k attn_k * V[b,h,(t-d_k)%L,:]; write bf16 into final-GEMM A layout.
__global__ void gather_av(const float* __restrict__ V, const float* __restrict__ attnW,
                          const int* __restrict__ delays, unsigned short* __restrict__ Ahi) {
  int blk = blockIdx.x;
  int bh = blk >> 8, tb = blk & 255;
  int tid = threadIdx.x;
  int tt = tid >> 4, dq = tid & 15;
  int t = (tb << 4) + tt;
  const float4* Vb = (const float4*)(V + (size_t)bh * 4096 * 64);
  float4 acc = make_float4(0.f, 0.f, 0.f, 0.f);
#pragma unroll
  for (int kk = 0; kk < 8; ++kk) {
    float w = attnW[bh * 8 + kk];
    int dl = delays[bh * 8 + kk];
    int row = (t - dl) & 4095;
    float4 x = Vb[row * 16 + dq];
    acc.x += w * x.x; acc.y += w * x.y; acc.z += w * x.z; acc.w += w * x.w;
  }
  int b = bh >> 3, h = bh & 7;
  size_t o = ((size_t)((b << 12) + t)) * 512 + (h << 6) + (dq << 2);
  ushort4 hv;
  hv.x = f2bf(acc.x); hv.y = f2bf(acc.y); hv.z = f2bf(acc.z); hv.w = f2bf(acc.w);
  *(ushort4*)(Ahi + o) = hv;
}

// ---------------- orchestration ----------------
extern "C" void kernel_launch(void* const* d_in, const int* in_sizes, int n_in,
                              void* d_out, int out_size, void* d_ws, size_t ws_size,
                              hipStream_t stream) {
  (void)in_sizes; (void)n_in; (void)out_size; (void)ws_size;
  const float* x_q = (const float*)d_in[0];
  const float* x_kv = (const float*)d_in[1];
  const float* Wq = (const float*)d_in[2];
  const float* bq = (const float*)d_in[3];
  const float* Wk = (const float*)d_in[4];
  const float* bk = (const float*)d_in[5];
  const float* Wv = (const float*)d_in[6];
  const float* bv = (const float*)d_in[7];
  const float* Wo = (const float*)d_in[8];
  const float* bo = (const float*)d_in[9];
  float* out = (float*)d_out;
  char* ws = (char*)d_ws;

  // workspace layout (~137.1 MiB)
  unsigned short* AqHi  = (unsigned short*)(ws + 0 * MiB);
  unsigned short* AqLo  = (unsigned short*)(ws + 16 * MiB);
  float*          Vbuf  = (float*)(ws + 0 * MiB);
  unsigned short* AkvHi = (unsigned short*)(ws + 36 * MiB);
  unsigned short* AkvLo = (unsigned short*)(ws + 52 * MiB);
  float* PpartRe = (float*)(ws + 36 * MiB);
  float* PpartIm = (float*)(ws + 52 * MiB);
  unsigned short* Aattn = (unsigned short*)(ws + 36 * MiB);
  unsigned short* WTb   = (unsigned short*)(ws + 68 * MiB);
  float* QT    = (float*)(ws + 72 * MiB);
  float* KT    = (float*)(ws + 104 * MiB);
  float* PsumRe = (float*)(ws + 72 * MiB);
  float* PsumIm = (float*)(ws + 73 * MiB);
  float* attnW = (float*)(ws + 137 * MiB);
  int*   delays = (int*)(ws + 137 * MiB + 4096);
  float2* TW   = (float2*)(ws + 137 * MiB + 8192);

  int n4 = (16384 * 512) / 4;
  conv_split2<<<dim3(2 * n4 / 256), dim3(256), 0, stream>>>(x_q, x_kv, AqHi, AqLo, AkvHi, AkvLo, n4);
  conv_wt4<<<dim3(256), dim3(256), 0, stream>>>(Wq, Wk, Wv, Wo, WTb);
  make_tw<<<dim3(12), dim3(256), 0, stream>>>(TW);

  // Q and K projections fused, 256^2 8-phase (256 wgs x 512 thr = 1 block/CU).
  qk_gemm8<<<dim3(256), dim3(512), 0, stream>>>(AqHi, AqLo, AkvHi, AkvLo, WTb, bq, bk, QT, KT);
  gemm_bf16<<<dim3(512), dim3(256), 0, stream>>>(AkvHi, WTb + 4 * 262144, bv, Vbuf, 1);

  fft_corr<<<dim3(1024), dim3(512), 0, stream>>>(QT, KT, TW, PpartRe, PpartIm);
  reduce_p<<<dim3(128), dim3(256), 0, stream>>>(PpartRe, PpartIm, PsumRe, PsumIm);
  ifft_topk<<<dim3(32), dim3(512), 0, stream>>>(PsumRe, PsumIm, TW, attnW, delays);
  gather_av<<<dim3(8192), dim3(256), 0, stream>>>(Vbuf, attnW, delays, Aattn);

  // out = gathered @ Wo + bo (plain bf16)
  gemm_bf16<<<dim3(512), dim3(256), 0, stream>>>(Aattn, WTb + 6 * 262144, bo, out, 2);
}

// Round 8
// 208.920 us; speedup vs baseline: 4.9120x; 1.0660x over previous
//
#include <hip/hip_runtime.h>
#include <hip/hip_bf16.h>

// AutoCorrelation layer: QKV proj (bf16x3 MFMA GEMM; Q+K on a 256^2 8-phase
// counted-vmcnt schedule) -> packed FFT cross-corr (radix-16 in-register
// superstages; partials + reduce + ifft, NO global atomics) -> top-8 + softmax
// -> delay-gather of V -> output proj.  B=4, L=4096, D=512, H=8, Dh=64, K=8.

#define MiB (1024ull * 1024ull)

typedef __attribute__((ext_vector_type(8))) short bf16x8;
typedef __attribute__((ext_vector_type(4))) float f32x4;
static_assert(sizeof(bf16x8) == 16, "bf16x8 must be 16B");

__device__ __forceinline__ unsigned short f2bf(float f) {
  unsigned u = __float_as_uint(f);
  unsigned r = (u + 0x7FFFu + ((u >> 16) & 1u)) >> 16;  // RN-even
  return (unsigned short)r;
}
__device__ __forceinline__ float bf2f(unsigned short h) {
  return __uint_as_float(((unsigned)h) << 16);
}
// base-4 digit reversal of a 12-bit index (involution)
__device__ __forceinline__ int rev4_12(int x) {
  unsigned r = __brev((unsigned)x) >> 20;
  return (int)(((r & 0xAAAu) >> 1) | ((r & 0x555u) << 1));
}
// LDS pad: +1 float per 32 to break power-of-2 bank patterns
#define IDX(e) ((e) + ((e) >> 5))
#define LDSN (4095 + (4095 >> 5) + 1)

// XCD-aware bijective swizzle (nwg % 8 == 0): XCD x owns contiguous logical chunk.
__device__ __forceinline__ int xcd_swz(int bid, int cpx) {
  return (bid & 7) * cpx + (bid >> 3);
}

#define BARRIER() do { asm volatile("" ::: "memory"); __builtin_amdgcn_s_barrier(); asm volatile("" ::: "memory"); } while (0)
#define WAITV6() asm volatile("s_waitcnt vmcnt(6)" ::: "memory")

// ---------------- conversion kernels ----------------

__global__ void conv_split2(const float* __restrict__ xq, const float* __restrict__ xkv,
                            unsigned short* __restrict__ qhi, unsigned short* __restrict__ qlo,
                            unsigned short* __restrict__ khi, unsigned short* __restrict__ klo,
                            int n4) {
  int i = blockIdx.x * 256 + threadIdx.x;
  const float* x = (i < n4) ? xq : xkv;
  unsigned short* hi = (i < n4) ? qhi : khi;
  unsigned short* lo = (i < n4) ? qlo : klo;
  int ii = (i < n4) ? i : i - n4;
  float4 v = ((const float4*)x)[ii];
  ushort4 h, l;
  float f;
  f = v.x; h.x = f2bf(f); l.x = f2bf(f - bf2f(h.x));
  f = v.y; h.y = f2bf(f); l.y = f2bf(f - bf2f(h.y));
  f = v.z; h.z = f2bf(f); l.z = f2bf(f - bf2f(h.z));
  f = v.w; h.w = f2bf(f); l.w = f2bf(f - bf2f(h.w));
  ((ushort4*)hi)[ii] = h;
  ((ushort4*)lo)[ii] = l;
}

// All four W (512x512 f32 [k][n]) -> transposed hi/lo bf16 Wt[n][k], via LDS tile
// transpose. Grid: 4 mats x 64 tiles of 64x64.
__global__ void conv_wt4(const float* __restrict__ W0, const float* __restrict__ W1,
                         const float* __restrict__ W2, const float* __restrict__ W3,
                         unsigned short* __restrict__ WT) {
  __shared__ float t[64][65];
  int bx = blockIdx.x;
  int w = bx >> 6, tile = bx & 63;
  int k0 = (tile >> 3) << 6, n0 = (tile & 7) << 6;
  const float* W = (w == 0) ? W0 : (w == 1) ? W1 : (w == 2) ? W2 : W3;
  unsigned short* hi = WT + (size_t)(2 * w) * 262144;
  unsigned short* lo = hi + 262144;
  int tid = threadIdx.x;
#pragma unroll
  for (int j = 0; j < 4; ++j) {
    int i = tid + (j << 8);
    int rr = i >> 4, c4 = (i & 15) << 2;
    float4 v = *(const float4*)&W[(size_t)(k0 + rr) * 512 + n0 + c4];
    t[rr][c4 + 0] = v.x; t[rr][c4 + 1] = v.y;
    t[rr][c4 + 2] = v.z; t[rr][c4 + 3] = v.w;
  }
  __syncthreads();
#pragma unroll
  for (int j = 0; j < 4; ++j) {
    int i = tid + (j << 8);
    int nn = i >> 4, k4 = (i & 15) << 2;
    ushort4 h, l;
    float f;
    f = t[k4 + 0][nn]; h.x = f2bf(f); l.x = f2bf(f - bf2f(h.x));
    f = t[k4 + 1][nn]; h.y = f2bf(f); l.y = f2bf(f - bf2f(h.y));
    f = t[k4 + 2][nn]; h.z = f2bf(f); l.z = f2bf(f - bf2f(h.z));
    f = t[k4 + 3][nn]; h.w = f2bf(f); l.w = f2bf(f - bf2f(h.w));
    size_t o = (size_t)(n0 + nn) * 512 + k0 + k4;
    *(ushort4*)(hi + o) = h;
    *(ushort4*)(lo + o) = l;
  }
}

// twiddle table T[r] = exp(-2*pi*i*r/4096), r=0..3071 (double-precision generated)
__global__ void make_tw(float2* __restrict__ T) {
  int r = blockIdx.x * 256 + threadIdx.x;
  if (r < 3072) {
    double a = -2.0 * 3.14159265358979323846 * (double)r / 4096.0;
    T[r] = make_float2((float)cos(a), (float)sin(a));
  }
}

// ---------------- fused Q+K GEMM: 256^2 tile, 8-wave, 4-phase/K-tile, counted vmcnt ----
__global__ __launch_bounds__(512, 2)
void qk_gemm8(const unsigned short* __restrict__ AqHi, const unsigned short* __restrict__ AqLo,
              const unsigned short* __restrict__ AkvHi, const unsigned short* __restrict__ AkvLo,
              const unsigned short* __restrict__ WT,
              const float* __restrict__ bq, const float* __restrict__ bk,
              float* __restrict__ QT, float* __restrict__ KT) {
  __shared__ __align__(16) char lds[131072];
  int tid = threadIdx.x;
  int lane = tid & 63, wv = tid >> 6;
  int wm = wv >> 2, wn = wv & 3;

  int sw = xcd_swz(blockIdx.x, 32);  // 256 wgs
  int op = sw >> 7;                  // 0 = Q, 1 = K
  int r = sw & 127;
  int m0 = (r >> 1) << 8;            // 64 M-tiles
  int n0 = (r & 1) << 8;             // 2 N-tiles

  const unsigned short* Ahi = op ? AkvHi : AqHi;
  const unsigned short* Alo = op ? AkvLo : AqLo;
  const unsigned short* Bhi = WT + (op ? 2 * 262144 : 0);
  const unsigned short* Blo = Bhi + 262144;
  const float* bias = op ? bk : bq;
  float* C = op ? KT : QT;

  int aoff0 = ((lane & 15) << 7) + ((((lane >> 4) + 0) ^ (lane & 7)) << 4);  // ks=0
  int aoff1 = ((lane & 15) << 7) + ((((lane >> 4) + 4) ^ (lane & 7)) << 4);  // ks=1
  int src_row = tid >> 3;
  int src_col = (tid & 7) ^ (src_row & 7);

  f32x4 acc[8][4];
  const f32x4 zz = {0.f, 0.f, 0.f, 0.f};
#pragma unroll
  for (int i = 0; i < 8; ++i)
#pragma unroll
    for (int j = 0; j < 4; ++j) acc[i][j] = zz;

  auto APTR = [&](int v) {
    const unsigned short* p = (v >= 16) ? Alo : Ahi;
    return p + (size_t)m0 * 512 + ((v & 7) << 6);
  };
  auto BPTR = [&](int v) {
    const unsigned short* p = (v >= 8 && v < 16) ? Blo : Bhi;
    return p + (size_t)n0 * 512 + ((v & 7) << 6);
  };
  auto STAGE = [&](const unsigned short* gbase, int R0, int ldsOff) {
    const unsigned short* ga = gbase + (size_t)(R0 + src_row) * 512 + (src_col << 3);
    char* la = lds + ldsOff + (R0 << 7) + (wv << 10);
    __builtin_amdgcn_global_load_lds((const __attribute__((address_space(1))) void*)ga,
                                     (__attribute__((address_space(3))) void*)la, 16, 0, 0);
  };
#define RDA(o, mi, ks) (*(const bf16x8*)(lds + (o) + (wm << 14) + ((mi) << 11) + aoff##ks))
#define RDB(o, ni, ks) (*(const bf16x8*)(lds + (o) + 32768 + (wn << 13) + ((ni) << 11) + aoff##ks))
#define MFMA_PAIR(mi0, A0, A1)                                                              \
  __builtin_amdgcn_s_setprio(1);                                                            \
  _Pragma("unroll") for (int ks = 0; ks < 2; ++ks) {                                        \
    _Pragma("unroll") for (int ni = 0; ni < 4; ++ni) {                                      \
      acc[mi0][ni] = __builtin_amdgcn_mfma_f32_16x16x32_bf16(A0[ks], b[ni][ks], acc[mi0][ni], 0, 0, 0);          \
      acc[mi0 + 1][ni] = __builtin_amdgcn_mfma_f32_16x16x32_bf16(A1[ks], b[ni][ks], acc[mi0 + 1][ni], 0, 0, 0);  \
    }                                                                                       \
  }                                                                                         \
  __builtin_amdgcn_s_setprio(0)

  STAGE(BPTR(0), 0, 32768);   STAGE(BPTR(0), 64, 32768);
  STAGE(BPTR(0), 128, 32768); STAGE(BPTR(0), 192, 32768);
  STAGE(APTR(0), 0, 0);       STAGE(APTR(0), 64, 0);
  STAGE(APTR(0), 128, 0);     STAGE(APTR(0), 192, 0);
  STAGE(BPTR(1), 0, 65536 + 32768);   STAGE(BPTR(1), 64, 65536 + 32768);
  STAGE(BPTR(1), 128, 65536 + 32768); STAGE(BPTR(1), 192, 65536 + 32768);
  STAGE(APTR(1), 0, 65536);           STAGE(APTR(1), 128, 65536);
  WAITV6();
  BARRIER();

  for (int t = 0; t < 24; ++t) {
    int o = (t & 1) << 16;
    int on = o ^ 65536;
    int t1 = (t + 1 < 24) ? t + 1 : 23;
    int t2 = (t + 2 < 24) ? t + 2 : 23;
    const unsigned short* a1p = APTR(t1);
    const unsigned short* a2p = APTR(t2);
    const unsigned short* b2p = BPTR(t2);

    bf16x8 b[4][2], aA[2][2];
#pragma unroll
    for (int ni = 0; ni < 4; ++ni) { b[ni][0] = RDB(o, ni, 0); b[ni][1] = RDB(o, ni, 1); }
    aA[0][0] = RDA(o, 0, 0); aA[0][1] = RDA(o, 0, 1);
    aA[1][0] = RDA(o, 1, 0); aA[1][1] = RDA(o, 1, 1);
    STAGE(a1p, 64, on); STAGE(a1p, 192, on);
    BARRIER();
    MFMA_PAIR(0, aA[0], aA[1]);
    BARRIER();

    aA[0][0] = RDA(o, 2, 0); aA[0][1] = RDA(o, 2, 1);
    aA[1][0] = RDA(o, 3, 0); aA[1][1] = RDA(o, 3, 1);
    STAGE(b2p, 0, o + 32768); STAGE(b2p, 64, o + 32768);
    BARRIER();
    MFMA_PAIR(2, aA[0], aA[1]);
    BARRIER();

    aA[0][0] = RDA(o, 4, 0); aA[0][1] = RDA(o, 4, 1);
    aA[1][0] = RDA(o, 5, 0); aA[1][1] = RDA(o, 5, 1);
    STAGE(b2p, 128, o + 32768); STAGE(b2p, 192, o + 32768);
    BARRIER();
    MFMA_PAIR(4, aA[0], aA[1]);
    BARRIER();

    aA[0][0] = RDA(o, 6, 0); aA[0][1] = RDA(o, 6, 1);
    aA[1][0] = RDA(o, 7, 0); aA[1][1] = RDA(o, 7, 1);
    STAGE(a2p, 0, o); STAGE(a2p, 128, o);
    BARRIER();
    MFMA_PAIR(6, aA[0], aA[1]);
    WAITV6();
    BARRIER();
  }
#undef RDA
#undef RDB
#undef MFMA_PAIR

#pragma unroll
  for (int mi = 0; mi < 8; ++mi) {
    int mrow0 = m0 + (wm << 7) + (mi << 4) + ((lane >> 4) << 2);
    int bq_ = mrow0 >> 12;
    int t0 = mrow0 & 4095;
#pragma unroll
    for (int ni = 0; ni < 4; ++ni) {
      int col = n0 + (wn << 6) + (ni << 4) + (lane & 15);
      float bv = bias[col];
      f32x4 v = acc[mi][ni];
      v.x += bv; v.y += bv; v.z += bv; v.w += bv;
      *(f32x4*)&C[((size_t)(bq_ * 512 + col)) * 4096 + t0] = v;
    }
  }
}

// ---------------- generic GEMM for V (mode 1) and OUT (mode 2), nseg=1, 512 wgs ----------------
__global__ __launch_bounds__(256, 2)
void gemm_bf16(const unsigned short* __restrict__ Ahi,
               const unsigned short* __restrict__ Bhi,
               const float* __restrict__ bias, float* __restrict__ C, int mode) {
  __shared__ short As[128 * 64];
  __shared__ short Bs[128 * 64];
  int bx = xcd_swz(blockIdx.x, 64);  // 512 wgs
  int bm = bx >> 2, bn = bx & 3;
  int m0 = bm << 7, n0 = bn << 7;
  int tid = threadIdx.x;
  int lane = tid & 63, wv = tid >> 6;
  int wm = wv >> 1, wn = wv & 1;

  const f32x4 zz = {0.f, 0.f, 0.f, 0.f};
  f32x4 acc[4][4];
#pragma unroll
  for (int i = 0; i < 4; ++i)
#pragma unroll
    for (int j = 0; j < 4; ++j) acc[i][j] = zz;

  int srow = tid >> 3;
  int sk = (tid & 7) << 3;
  for (int ks = 0; ks < 8; ++ks) {
    int kb = ks << 6;
#pragma unroll
    for (int i = 0; i < 4; ++i) {
      int r = (i << 5) + srow;
      const unsigned short* ga = Ahi + (size_t)(m0 + r) * 512 + kb + sk;
      const unsigned short* gb = Bhi + (size_t)(n0 + r) * 512 + kb + sk;
      char* la = (char*)As + (i << 12) + (wv << 10);
      char* lb = (char*)Bs + (i << 12) + (wv << 10);
      __builtin_amdgcn_global_load_lds((const __attribute__((address_space(1))) void*)ga,
                                       (__attribute__((address_space(3))) void*)la, 16, 0, 0);
      __builtin_amdgcn_global_load_lds((const __attribute__((address_space(1))) void*)gb,
                                       (__attribute__((address_space(3))) void*)lb, 16, 0, 0);
    }
    __syncthreads();
#pragma unroll
    for (int kk = 0; kk < 2; ++kk) {
      bf16x8 af[4], bfr[4];
      int krd = (kk << 5) + ((lane >> 4) << 3);
#pragma unroll
      for (int mi = 0; mi < 4; ++mi)
        af[mi] = *(const bf16x8*)&As[((wm << 6) + (mi << 4) + (lane & 15)) * 64 + krd];
#pragma unroll
      for (int ni = 0; ni < 4; ++ni)
        bfr[ni] = *(const bf16x8*)&Bs[((wn << 6) + (ni << 4) + (lane & 15)) * 64 + krd];
#pragma unroll
      for (int mi = 0; mi < 4; ++mi)
#pragma unroll
        for (int ni = 0; ni < 4; ++ni)
          acc[mi][ni] = __builtin_amdgcn_mfma_f32_16x16x32_bf16(af[mi], bfr[ni], acc[mi][ni], 0, 0, 0);
    }
    __syncthreads();
  }

#pragma unroll
  for (int mi = 0; mi < 4; ++mi) {
    int mrow0 = m0 + (wm << 6) + (mi << 4) + ((lane >> 4) << 2);
    int bq_ = mrow0 >> 12;
    int t0 = mrow0 & 4095;
#pragma unroll
    for (int ni = 0; ni < 4; ++ni) {
      int col = n0 + (wn << 6) + (ni << 4) + (lane & 15);
      float bv = bias[col];
      f32x4 v = acc[mi][ni];
      v.x += bv; v.y += bv; v.z += bv; v.w += bv;
      if (mode == 1) {
        size_t base = (size_t)(bq_ * 8 + (col >> 6)) * 4096;
        int d = col & 63;
        C[(base + t0 + 0) * 64 + d] = v.x;
        C[(base + t0 + 1) * 64 + d] = v.y;
        C[(base + t0 + 2) * 64 + d] = v.z;
        C[(base + t0 + 3) * 64 + d] = v.w;
      } else {
        C[(size_t)(mrow0 + 0) * 512 + col] = v.x;
        C[(size_t)(mrow0 + 1) * 512 + col] = v.y;
        C[(size_t)(mrow0 + 2) * 512 + col] = v.z;
        C[(size_t)(mrow0 + 3) * 512 + col] = v.w;
      }
    }
  }
}

// ---------------- FFT: radix-16 superstages (stage pairs fused in registers) ----------
// Bit-identical to the 6-stage radix-4 DIF: superstage ss fuses stages 2ss, 2ss+1.
// 256 units of 16 points each; 3 LDS round-trips, 3 barriers.
__device__ __forceinline__ void r4(float& x0r, float& x0i, float& x1r, float& x1i,
                                   float& x2r, float& x2i, float& x3r, float& x3i,
                                   float2 w1, float2 w2, float2 w3) {
  float Ar = x0r + x2r, Ai = x0i + x2i;
  float Br = x0r - x2r, Bi = x0i - x2i;
  float Cr = x1r + x3r, Ci = x1i + x3i;
  float Dr = x1i - x3i, Di = x3r - x1r;  // -i*(x1-x3)
  x0r = Ar + Cr; x0i = Ai + Ci;
  float tr = Br + Dr, ti = Bi + Di;
  x1r = tr * w1.x - ti * w1.y; x1i = tr * w1.y + ti * w1.x;
  tr = Ar - Cr; ti = Ai - Ci;
  x2r = tr * w2.x - ti * w2.y; x2i = tr * w2.y + ti * w2.x;
  tr = Br - Dr; ti = Bi - Di;
  x3r = tr * w3.x - ti * w3.y; x3i = tr * w3.y + ti * w3.x;
}

__device__ __forceinline__ void fft16_superstages(float* re, float* im,
                                                  const float2* __restrict__ TW,
                                                  int u, bool active) {
#pragma unroll
  for (int ss = 0; ss < 3; ++ss) {
    const int lm = 10 - 4 * ss;      // 10, 6, 2
    const int m = 1 << lm;
    const int m4 = m >> 2;
    const int stw = 1 << (4 * ss);   // 1, 16, 256
    const int stw4 = stw << 2;
    if (active) {
      int jj = u & (m4 - 1);
      int g = u >> (lm - 2);
      int base = (g << (lm + 2)) + jj;
      float xr[4][4], xi[4][4];
#pragma unroll
      for (int a = 0; a < 4; ++a)
#pragma unroll
        for (int b = 0; b < 4; ++b) {
          int p = IDX(base + a * m + b * m4);
          xr[a][b] = re[p]; xi[a][b] = im[p];
        }
      // level 1: stage 2ss, radix-4 over a (per b), twiddle j = b*m4+jj
#pragma unroll
      for (int b = 0; b < 4; ++b) {
        int j1 = (b * m4 + jj) * stw;
        float2 w1 = TW[j1], w2 = TW[2 * j1], w3 = TW[3 * j1];
        r4(xr[0][b], xi[0][b], xr[1][b], xi[1][b], xr[2][b], xi[2][b], xr[3][b], xi[3][b], w1, w2, w3);
      }
      // level 2: stage 2ss+1, radix-4 over b (per a), twiddle j' = jj
      {
        int j2 = jj * stw4;
        float2 v1 = TW[j2], v2 = TW[2 * j2], v3 = TW[3 * j2];
#pragma unroll
        for (int a = 0; a < 4; ++a)
          r4(xr[a][0], xi[a][0], xr[a][1], xi[a][1], xr[a][2], xi[a][2], xr[a][3], xi[a][3], v1, v2, v3);
      }
#pragma unroll
      for (int a = 0; a < 4; ++a)
#pragma unroll
        for (int b = 0; b < 4; ++b) {
          int p = IDX(base + a * m + b * m4);
          re[p] = xr[a][b]; im[p] = xi[a][b];
        }
    }
    __syncthreads();
  }
}

// Packed FFT of z = q + i*k per (b,h,d); one wg (512 thr) runs its 2 d's
// CONCURRENTLY (256 units each, wave-uniform split). 1024 wgs; NO atomics.
__global__ __launch_bounds__(512, 2)
void fft_corr(const float* __restrict__ QT, const float* __restrict__ KT,
              const float2* __restrict__ TW, float* __restrict__ PpartRe,
              float* __restrict__ PpartIm) {
  __shared__ float re[2][LDSN];
  __shared__ float im[2][LDSN];
  int wg = blockIdx.x;
  int bh = wg >> 5;
  int d0 = (wg & 31) << 1;
  int tid = threadIdx.x;
  const float* qb = QT + (size_t)bh * 64 * 4096;
  const float* kb = KT + (size_t)bh * 64 * 4096;
#pragma unroll
  for (int ff = 0; ff < 2; ++ff) {
    const float4* q4 = (const float4*)(qb + (size_t)(d0 + ff) * 4096);
    const float4* k4 = (const float4*)(kb + (size_t)(d0 + ff) * 4096);
#pragma unroll
    for (int i = 0; i < 2; ++i) {
      int e4 = tid + (i << 9);
      float4 qv = q4[e4], kv = k4[e4];
      int e = e4 << 2;
      re[ff][IDX(e + 0)] = qv.x; im[ff][IDX(e + 0)] = kv.x;
      re[ff][IDX(e + 1)] = qv.y; im[ff][IDX(e + 1)] = kv.y;
      re[ff][IDX(e + 2)] = qv.z; im[ff][IDX(e + 2)] = kv.z;
      re[ff][IDX(e + 3)] = qv.w; im[ff][IDX(e + 3)] = kv.w;
    }
  }
  __syncthreads();
  // wave-uniform FFT split: waves 0-3 -> fft 0, waves 4-7 -> fft 1
  fft16_superstages(re[tid >> 8], im[tid >> 8], TW, tid & 255, true);
  // extraction: position p holds Z[f], f = rev4(p); pair f' = (N-f)%N at rev4(f')
  float accR[8], accI[8];
#pragma unroll
  for (int j = 0; j < 8; ++j) { accR[j] = 0.f; accI[j] = 0.f; }
#pragma unroll
  for (int ff = 0; ff < 2; ++ff) {
#pragma unroll
    for (int j = 0; j < 8; ++j) {
      int p = tid + (j << 9);
      int f = rev4_12(p);
      int fn = (4096 - f) & 4095;
      int pn = rev4_12(fn);
      float zr = re[ff][IDX(p)], zi = im[ff][IDX(p)];
      float wr = re[ff][IDX(pn)], wi = im[ff][IDX(pn)];
      float qre = 0.5f * (zr + wr), qim = 0.5f * (zi - wi);
      float kre = 0.5f * (zi + wi), kim = 0.5f * (wr - zr);
      accR[j] += qre * kre + qim * kim;   // Re(Qf*conj(Kf))
      accI[j] += qim * kre - qre * kim;   // Im(Qf*conj(Kf))
    }
  }
  float* pR = PpartRe + (size_t)wg * 4096;
  float* pI = PpartIm + (size_t)wg * 4096;
#pragma unroll
  for (int j = 0; j < 8; ++j) {
    int p = tid + (j << 9);
    pR[p] = accR[j];
    pI[p] = accI[j];
  }
}

// Reduce 32 partials per (b,h) -> Psum, float4. Grid 128 = 32 bh x 4 chunks of 1024 p.
__global__ void reduce_p(const float* __restrict__ PpartRe, const float* __restrict__ PpartIm,
                         float* __restrict__ PsumRe, float* __restrict__ PsumIm) {
  int wg = blockIdx.x;
  int bh = wg >> 2;
  int p4 = ((wg & 3) << 8) + threadIdx.x;  // float4 index 0..1023
  const float4* bR = (const float4*)(PpartRe + (size_t)bh * 32 * 4096);
  const float4* bI = (const float4*)(PpartIm + (size_t)bh * 32 * 4096);
  float4 sr = make_float4(0.f, 0.f, 0.f, 0.f);
  float4 si = make_float4(0.f, 0.f, 0.f, 0.f);
#pragma unroll
  for (int part = 0; part < 32; ++part) {
    float4 a = bR[part * 1024 + p4];
    float4 b = bI[part * 1024 + p4];
    sr.x += a.x; sr.y += a.y; sr.z += a.z; sr.w += a.w;
    si.x += b.x; si.y += b.y; si.z += b.z; si.w += b.w;
  }
  ((float4*)(PsumRe + (size_t)bh * 4096))[p4] = sr;
  ((float4*)(PsumIm + (size_t)bh * 4096))[p4] = si;
}

// Inverse FFT via conj + forward DIF (radix-16); corr(tau=rev4(p)) = re[p]/(4096*64).
__global__ __launch_bounds__(512, 1)
void ifft_topk(const float* __restrict__ PsumRe, const float* __restrict__ PsumIm,
               const float2* __restrict__ TW, float* __restrict__ attnW, int* __restrict__ delays) {
  __shared__ float re[LDSN];
  __shared__ float im[LDSN];
  __shared__ float wval[8];
  __shared__ int widx[8], wpos[8];
  int bh = blockIdx.x, tid = threadIdx.x;
  int lane = tid & 63, wv = tid >> 6;
  const float4* pr4 = (const float4*)(PsumRe + (size_t)bh * 4096);
  const float4* pi4 = (const float4*)(PsumIm + (size_t)bh * 4096);
#pragma unroll
  for (int i = 0; i < 2; ++i) {
    int e4 = tid + (i << 9);
    float4 a = pr4[e4], b = pi4[e4];
    int fb = rev4_12(e4 << 2);  // rev4 of (e4*4 + j) = fb | (j<<10)
    re[IDX(fb + 0 * 1024)] = a.x; im[IDX(fb + 0 * 1024)] = -b.x;
    re[IDX(fb + 1 * 1024)] = a.y; im[IDX(fb + 1 * 1024)] = -b.y;
    re[IDX(fb + 2 * 1024)] = a.z; im[IDX(fb + 2 * 1024)] = -b.z;
    re[IDX(fb + 3 * 1024)] = a.w; im[IDX(fb + 3 * 1024)] = -b.w;
  }
  __syncthreads();
  fft16_superstages(re, im, TW, tid & 255, tid < 256);
  const float SC = 1.0f / 262144.0f;  // 1/(L*Dh)
  float topv[8]; int topi[8];
#pragma unroll
  for (int pass = 0; pass < 8; ++pass) {
    float bv = -3.4e38f; int bi = 1 << 30; int bp = 0;
#pragma unroll
    for (int i = 0; i < 8; ++i) {
      int p = tid + (i << 9);
      float v = re[IDX(p)];
      int tau = rev4_12(p);
      if (v > bv || (v == bv && tau < bi)) { bv = v; bi = tau; bp = p; }
    }
#pragma unroll
    for (int off = 32; off > 0; off >>= 1) {
      float ov = __shfl_down(bv, off);
      int oi = __shfl_down(bi, off);
      int opp = __shfl_down(bp, off);
      if (ov > bv || (ov == bv && oi < bi)) { bv = ov; bi = oi; bp = opp; }
    }
    if (lane == 0) { wval[wv] = bv; widx[wv] = bi; wpos[wv] = bp; }
    __syncthreads();
    if (tid == 0) {
#pragma unroll
      for (int w2 = 1; w2 < 8; ++w2) {
        if (wval[w2] > bv || (wval[w2] == bv && widx[w2] < bi)) {
          bv = wval[w2]; bi = widx[w2]; bp = wpos[w2];
        }
      }
      topv[pass] = bv * SC;
      topi[pass] = bi;
      re[IDX(bp)] = -3.4e38f;
    }
    __syncthreads();
  }
  if (tid == 0) {
    float mx = topv[0];  // pass 0 = global max
    float ex[8], s = 0.f;
    for (int k = 0; k < 8; ++k) { ex[k] = expf(topv[k] - mx); s += ex[k]; }
    float inv = 1.0f / s;
    for (int k = 0; k < 8; ++k) {
      attnW[bh * 8 + k] = ex[k] * inv;
      delays[bh * 8 + k] = topi[k];
    }
  }
}

// out[b,h,t,:] = sum_k attn_k * V[b,h,(t-d_k)%L,:]; write bf16 into final-GEMM A layout.
__global__ void gather_av(const float* __restrict__ V, const float* __restrict__ attnW,
                          const int* __restrict__ delays, unsigned short* __restrict__ Ahi) {
  int blk = blockIdx.x;
  int bh = blk >> 8, tb = blk & 255;
  int tid = threadIdx.x;
  int tt = tid >> 4, dq = tid & 15;
  int t = (tb << 4) + tt;
  const float4* Vb = (const float4*)(V + (size_t)bh * 4096 * 64);
  float4 acc = make_float4(0.f, 0.f, 0.f, 0.f);
#pragma unroll
  for (int kk = 0; kk < 8; ++kk) {
    float w = attnW[bh * 8 + kk];
    int dl = delays[bh * 8 + kk];
    int row = (t - dl) & 4095;
    float4 x = Vb[row * 16 + dq];
    acc.x += w * x.x; acc.y += w * x.y; acc.z += w * x.z; acc.w += w * x.w;
  }
  int b = bh >> 3, h = bh & 7;
  size_t o = ((size_t)((b << 12) + t)) * 512 + (h << 6) + (dq << 2);
  ushort4 hv;
  hv.x = f2bf(acc.x); hv.y = f2bf(acc.y); hv.z = f2bf(acc.z); hv.w = f2bf(acc.w);
  *(ushort4*)(Ahi + o) = hv;
}

// ---------------- orchestration ----------------
extern "C" void kernel_launch(void* const* d_in, const int* in_sizes, int n_in,
                              void* d_out, int out_size, void* d_ws, size_t ws_size,
                              hipStream_t stream) {
  (void)in_sizes; (void)n_in; (void)out_size; (void)ws_size;
  const float* x_q = (const float*)d_in[0];
  const float* x_kv = (const float*)d_in[1];
  const float* Wq = (const float*)d_in[2];
  const float* bq = (const float*)d_in[3];
  const float* Wk = (const float*)d_in[4];
  const float* bk = (const float*)d_in[5];
  const float* Wv = (const float*)d_in[6];
  const float* bv = (const float*)d_in[7];
  const float* Wo = (const float*)d_in[8];
  const float* bo = (const float*)d_in[9];
  float* out = (float*)d_out;
  char* ws = (char*)d_ws;

  // workspace layout (~137.1 MiB)
  unsigned short* AqHi  = (unsigned short*)(ws + 0 * MiB);
  unsigned short* AqLo  = (unsigned short*)(ws + 16 * MiB);
  float*          Vbuf  = (float*)(ws + 0 * MiB);
  unsigned short* AkvHi = (unsigned short*)(ws + 36 * MiB);
  unsigned short* AkvLo = (unsigned short*)(ws + 52 * MiB);
  float* PpartRe = (float*)(ws + 36 * MiB);
  float* PpartIm = (float*)(ws + 52 * MiB);
  unsigned short* Aattn = (unsigned short*)(ws + 36 * MiB);
  unsigned short* WTb   = (unsigned short*)(ws + 68 * MiB);
  float* QT    = (float*)(ws + 72 * MiB);
  float* KT    = (float*)(ws + 104 * MiB);
  float* PsumRe = (float*)(ws + 72 * MiB);
  float* PsumIm = (float*)(ws + 73 * MiB);
  float* attnW = (float*)(ws + 137 * MiB);
  int*   delays = (int*)(ws + 137 * MiB + 4096);
  float2* TW   = (float2*)(ws + 137 * MiB + 8192);

  int n4 = (16384 * 512) / 4;
  conv_split2<<<dim3(2 * n4 / 256), dim3(256), 0, stream>>>(x_q, x_kv, AqHi, AqLo, AkvHi, AkvLo, n4);
  conv_wt4<<<dim3(256), dim3(256), 0, stream>>>(Wq, Wk, Wv, Wo, WTb);
  make_tw<<<dim3(12), dim3(256), 0, stream>>>(TW);

  // Q and K projections fused, 256^2 8-phase (256 wgs x 512 thr = 1 block/CU).
  qk_gemm8<<<dim3(256), dim3(512), 0, stream>>>(AqHi, AqLo, AkvHi, AkvLo, WTb, bq, bk, QT, KT);
  gemm_bf16<<<dim3(512), dim3(256), 0, stream>>>(AkvHi, WTb + 4 * 262144, bv, Vbuf, 1);

  fft_corr<<<dim3(1024), dim3(512), 0, stream>>>(QT, KT, TW, PpartRe, PpartIm);
  reduce_p<<<dim3(128), dim3(256), 0, stream>>>(PpartRe, PpartIm, PsumRe, PsumIm);
  ifft_topk<<<dim3(32), dim3(512), 0, stream>>>(PsumRe, PsumIm, TW, attnW, delays);
  gather_av<<<dim3(8192), dim3(256), 0, stream>>>(Vbuf, attnW, delays, Aattn);

  // out = gathered @ Wo + bo (plain bf16)
  gemm_bf16<<<dim3(512), dim3(256), 0, stream>>>(Aattn, WTb + 6 * 262144, bo, out, 2);
}

// Round 9
// 191.842 us; speedup vs baseline: 5.3493x; 1.0890x over previous
//
#include <hip/hip_runtime.h>
#include <hip/hip_bf16.h>

// AutoCorrelation layer: QKV proj (bf16x3 MFMA GEMM; Q+K on a 256^2 8-phase
// counted-vmcnt schedule) -> packed FFT cross-corr (radix-16 in-register
// superstages; partials + reduce + ifft, NO global atomics) -> top-8 + softmax
// -> delay-gather of V (bf16) -> output proj.  B=4, L=4096, D=512, H=8, Dh=64.

#define MiB (1024ull * 1024ull)

typedef __attribute__((ext_vector_type(8))) short bf16x8;
typedef __attribute__((ext_vector_type(4))) float f32x4;
static_assert(sizeof(bf16x8) == 16, "bf16x8 must be 16B");

__device__ __forceinline__ unsigned short f2bf(float f) {
  unsigned u = __float_as_uint(f);
  unsigned r = (u + 0x7FFFu + ((u >> 16) & 1u)) >> 16;  // RN-even
  return (unsigned short)r;
}
__device__ __forceinline__ float bf2f(unsigned short h) {
  return __uint_as_float(((unsigned)h) << 16);
}
// base-4 digit reversal of a 12-bit index (involution)
__device__ __forceinline__ int rev4_12(int x) {
  unsigned r = __brev((unsigned)x) >> 20;
  return (int)(((r & 0xAAAu) >> 1) | ((r & 0x555u) << 1));
}
// LDS pad: +1 float per 32 to break power-of-2 bank patterns
#define IDX(e) ((e) + ((e) >> 5))
#define LDSN (4095 + (4095 >> 5) + 1)

// XCD-aware bijective swizzle (nwg % 8 == 0): XCD x owns contiguous logical chunk.
__device__ __forceinline__ int xcd_swz(int bid, int cpx) {
  return (bid & 7) * cpx + (bid >> 3);
}

#define BARRIER() do { asm volatile("" ::: "memory"); __builtin_amdgcn_s_barrier(); asm volatile("" ::: "memory"); } while (0)
#define WAITV6() asm volatile("s_waitcnt vmcnt(6)" ::: "memory")

// ---------------- fused prep: x hi/lo splits + W transposes + twiddle table ----------
// blocks [0,16384): conv_split2; [16384,16640): conv_wt4; [16640,16652): make_tw.
__global__ void prep_all(const float* __restrict__ xq, const float* __restrict__ xkv,
                         unsigned short* __restrict__ qhi, unsigned short* __restrict__ qlo,
                         unsigned short* __restrict__ khi, unsigned short* __restrict__ klo,
                         const float* __restrict__ W0, const float* __restrict__ W1,
                         const float* __restrict__ W2, const float* __restrict__ W3,
                         unsigned short* __restrict__ WT, float2* __restrict__ TWt, int n4) {
  __shared__ float t[64][65];
  int blk = blockIdx.x;
  int tid = threadIdx.x;
  if (blk < 16384) {
    int i = blk * 256 + tid;
    const float* x = (i < n4) ? xq : xkv;
    unsigned short* hi = (i < n4) ? qhi : khi;
    unsigned short* lo = (i < n4) ? qlo : klo;
    int ii = (i < n4) ? i : i - n4;
    float4 v = ((const float4*)x)[ii];
    ushort4 h, l;
    float f;
    f = v.x; h.x = f2bf(f); l.x = f2bf(f - bf2f(h.x));
    f = v.y; h.y = f2bf(f); l.y = f2bf(f - bf2f(h.y));
    f = v.z; h.z = f2bf(f); l.z = f2bf(f - bf2f(h.z));
    f = v.w; h.w = f2bf(f); l.w = f2bf(f - bf2f(h.w));
    ((ushort4*)hi)[ii] = h;
    ((ushort4*)lo)[ii] = l;
  } else if (blk < 16640) {
    int bx = blk - 16384;
    int w = bx >> 6, tile = bx & 63;
    int k0 = (tile >> 3) << 6, n0 = (tile & 7) << 6;
    const float* W = (w == 0) ? W0 : (w == 1) ? W1 : (w == 2) ? W2 : W3;
    unsigned short* hi = WT + (size_t)(2 * w) * 262144;
    unsigned short* lo = hi + 262144;
#pragma unroll
    for (int j = 0; j < 4; ++j) {
      int i = tid + (j << 8);
      int rr = i >> 4, c4 = (i & 15) << 2;
      float4 v = *(const float4*)&W[(size_t)(k0 + rr) * 512 + n0 + c4];
      t[rr][c4 + 0] = v.x; t[rr][c4 + 1] = v.y;
      t[rr][c4 + 2] = v.z; t[rr][c4 + 3] = v.w;
    }
    __syncthreads();
#pragma unroll
    for (int j = 0; j < 4; ++j) {
      int i = tid + (j << 8);
      int nn = i >> 4, k4 = (i & 15) << 2;
      ushort4 h, l;
      float f;
      f = t[k4 + 0][nn]; h.x = f2bf(f); l.x = f2bf(f - bf2f(h.x));
      f = t[k4 + 1][nn]; h.y = f2bf(f); l.y = f2bf(f - bf2f(h.y));
      f = t[k4 + 2][nn]; h.z = f2bf(f); l.z = f2bf(f - bf2f(h.z));
      f = t[k4 + 3][nn]; h.w = f2bf(f); l.w = f2bf(f - bf2f(h.w));
      size_t o = (size_t)(n0 + nn) * 512 + k0 + k4;
      *(ushort4*)(hi + o) = h;
      *(ushort4*)(lo + o) = l;
    }
  } else {
    int r = (blk - 16640) * 256 + tid;
    if (r < 3072) {
      double a = -2.0 * 3.14159265358979323846 * (double)r / 4096.0;
      TWt[r] = make_float2((float)cos(a), (float)sin(a));
    }
  }
}

// ---------------- fused Q+K GEMM: 256^2 tile, 8-wave, 4-phase/K-tile, counted vmcnt ----
__global__ __launch_bounds__(512, 2)
void qk_gemm8(const unsigned short* __restrict__ AqHi, const unsigned short* __restrict__ AqLo,
              const unsigned short* __restrict__ AkvHi, const unsigned short* __restrict__ AkvLo,
              const unsigned short* __restrict__ WT,
              const float* __restrict__ bq, const float* __restrict__ bk,
              float* __restrict__ QT, float* __restrict__ KT) {
  __shared__ __align__(16) char lds[131072];
  int tid = threadIdx.x;
  int lane = tid & 63, wv = tid >> 6;
  int wm = wv >> 2, wn = wv & 3;

  int sw = xcd_swz(blockIdx.x, 32);  // 256 wgs
  int op = sw >> 7;                  // 0 = Q, 1 = K
  int r = sw & 127;
  int m0 = (r >> 1) << 8;            // 64 M-tiles
  int n0 = (r & 1) << 8;             // 2 N-tiles

  const unsigned short* Ahi = op ? AkvHi : AqHi;
  const unsigned short* Alo = op ? AkvLo : AqLo;
  const unsigned short* Bhi = WT + (op ? 2 * 262144 : 0);
  const unsigned short* Blo = Bhi + 262144;
  const float* bias = op ? bk : bq;
  float* C = op ? KT : QT;

  int aoff0 = ((lane & 15) << 7) + ((((lane >> 4) + 0) ^ (lane & 7)) << 4);  // ks=0
  int aoff1 = ((lane & 15) << 7) + ((((lane >> 4) + 4) ^ (lane & 7)) << 4);  // ks=1
  int src_row = tid >> 3;
  int src_col = (tid & 7) ^ (src_row & 7);

  f32x4 acc[8][4];
  const f32x4 zz = {0.f, 0.f, 0.f, 0.f};
#pragma unroll
  for (int i = 0; i < 8; ++i)
#pragma unroll
    for (int j = 0; j < 4; ++j) acc[i][j] = zz;

  auto APTR = [&](int v) {
    const unsigned short* p = (v >= 16) ? Alo : Ahi;
    return p + (size_t)m0 * 512 + ((v & 7) << 6);
  };
  auto BPTR = [&](int v) {
    const unsigned short* p = (v >= 8 && v < 16) ? Blo : Bhi;
    return p + (size_t)n0 * 512 + ((v & 7) << 6);
  };
  auto STAGE = [&](const unsigned short* gbase, int R0, int ldsOff) {
    const unsigned short* ga = gbase + (size_t)(R0 + src_row) * 512 + (src_col << 3);
    char* la = lds + ldsOff + (R0 << 7) + (wv << 10);
    __builtin_amdgcn_global_load_lds((const __attribute__((address_space(1))) void*)ga,
                                     (__attribute__((address_space(3))) void*)la, 16, 0, 0);
  };
#define RDA(o, mi, ks) (*(const bf16x8*)(lds + (o) + (wm << 14) + ((mi) << 11) + aoff##ks))
#define RDB(o, ni, ks) (*(const bf16x8*)(lds + (o) + 32768 + (wn << 13) + ((ni) << 11) + aoff##ks))
#define MFMA_PAIR(mi0, A0, A1)                                                              \
  __builtin_amdgcn_s_setprio(1);                                                            \
  _Pragma("unroll") for (int ks = 0; ks < 2; ++ks) {                                        \
    _Pragma("unroll") for (int ni = 0; ni < 4; ++ni) {                                      \
      acc[mi0][ni] = __builtin_amdgcn_mfma_f32_16x16x32_bf16(A0[ks], b[ni][ks], acc[mi0][ni], 0, 0, 0);          \
      acc[mi0 + 1][ni] = __builtin_amdgcn_mfma_f32_16x16x32_bf16(A1[ks], b[ni][ks], acc[mi0 + 1][ni], 0, 0, 0);  \
    }                                                                                       \
  }                                                                                         \
  __builtin_amdgcn_s_setprio(0)

  STAGE(BPTR(0), 0, 32768);   STAGE(BPTR(0), 64, 32768);
  STAGE(BPTR(0), 128, 32768); STAGE(BPTR(0), 192, 32768);
  STAGE(APTR(0), 0, 0);       STAGE(APTR(0), 64, 0);
  STAGE(APTR(0), 128, 0);     STAGE(APTR(0), 192, 0);
  STAGE(BPTR(1), 0, 65536 + 32768);   STAGE(BPTR(1), 64, 65536 + 32768);
  STAGE(BPTR(1), 128, 65536 + 32768); STAGE(BPTR(1), 192, 65536 + 32768);
  STAGE(APTR(1), 0, 65536);           STAGE(APTR(1), 128, 65536);
  WAITV6();
  BARRIER();

  for (int t = 0; t < 24; ++t) {
    int o = (t & 1) << 16;
    int on = o ^ 65536;
    int t1 = (t + 1 < 24) ? t + 1 : 23;
    int t2 = (t + 2 < 24) ? t + 2 : 23;
    const unsigned short* a1p = APTR(t1);
    const unsigned short* a2p = APTR(t2);
    const unsigned short* b2p = BPTR(t2);

    bf16x8 b[4][2], aA[2][2];
#pragma unroll
    for (int ni = 0; ni < 4; ++ni) { b[ni][0] = RDB(o, ni, 0); b[ni][1] = RDB(o, ni, 1); }
    aA[0][0] = RDA(o, 0, 0); aA[0][1] = RDA(o, 0, 1);
    aA[1][0] = RDA(o, 1, 0); aA[1][1] = RDA(o, 1, 1);
    STAGE(a1p, 64, on); STAGE(a1p, 192, on);
    BARRIER();
    MFMA_PAIR(0, aA[0], aA[1]);
    BARRIER();

    aA[0][0] = RDA(o, 2, 0); aA[0][1] = RDA(o, 2, 1);
    aA[1][0] = RDA(o, 3, 0); aA[1][1] = RDA(o, 3, 1);
    STAGE(b2p, 0, o + 32768); STAGE(b2p, 64, o + 32768);
    BARRIER();
    MFMA_PAIR(2, aA[0], aA[1]);
    BARRIER();

    aA[0][0] = RDA(o, 4, 0); aA[0][1] = RDA(o, 4, 1);
    aA[1][0] = RDA(o, 5, 0); aA[1][1] = RDA(o, 5, 1);
    STAGE(b2p, 128, o + 32768); STAGE(b2p, 192, o + 32768);
    BARRIER();
    MFMA_PAIR(4, aA[0], aA[1]);
    BARRIER();

    aA[0][0] = RDA(o, 6, 0); aA[0][1] = RDA(o, 6, 1);
    aA[1][0] = RDA(o, 7, 0); aA[1][1] = RDA(o, 7, 1);
    STAGE(a2p, 0, o); STAGE(a2p, 128, o);
    BARRIER();
    MFMA_PAIR(6, aA[0], aA[1]);
    WAITV6();
    BARRIER();
  }
#undef RDA
#undef RDB
#undef MFMA_PAIR

#pragma unroll
  for (int mi = 0; mi < 8; ++mi) {
    int mrow0 = m0 + (wm << 7) + (mi << 4) + ((lane >> 4) << 2);
    int bq_ = mrow0 >> 12;
    int t0 = mrow0 & 4095;
#pragma unroll
    for (int ni = 0; ni < 4; ++ni) {
      int col = n0 + (wn << 6) + (ni << 4) + (lane & 15);
      float bv = bias[col];
      f32x4 v = acc[mi][ni];
      v.x += bv; v.y += bv; v.z += bv; v.w += bv;
      *(f32x4*)&C[((size_t)(bq_ * 512 + col)) * 4096 + t0] = v;
    }
  }
}

// ---------------- generic GEMM: V (mode 1, bf16 out) and OUT (mode 2, f32 out) ----------
__global__ __launch_bounds__(256, 2)
void gemm_bf16(const unsigned short* __restrict__ Ahi,
               const unsigned short* __restrict__ Bhi,
               const float* __restrict__ bias, float* __restrict__ Cf,
               unsigned short* __restrict__ Ch, int mode) {
  __shared__ short As[128 * 64];
  __shared__ short Bs[128 * 64];
  int bx = xcd_swz(blockIdx.x, 64);  // 512 wgs
  int bm = bx >> 2, bn = bx & 3;
  int m0 = bm << 7, n0 = bn << 7;
  int tid = threadIdx.x;
  int lane = tid & 63, wv = tid >> 6;
  int wm = wv >> 1, wn = wv & 1;

  const f32x4 zz = {0.f, 0.f, 0.f, 0.f};
  f32x4 acc[4][4];
#pragma unroll
  for (int i = 0; i < 4; ++i)
#pragma unroll
    for (int j = 0; j < 4; ++j) acc[i][j] = zz;

  int srow = tid >> 3;
  int sk = (tid & 7) << 3;
  for (int ks = 0; ks < 8; ++ks) {
    int kb = ks << 6;
#pragma unroll
    for (int i = 0; i < 4; ++i) {
      int r = (i << 5) + srow;
      const unsigned short* ga = Ahi + (size_t)(m0 + r) * 512 + kb + sk;
      const unsigned short* gb = Bhi + (size_t)(n0 + r) * 512 + kb + sk;
      char* la = (char*)As + (i << 12) + (wv << 10);
      char* lb = (char*)Bs + (i << 12) + (wv << 10);
      __builtin_amdgcn_global_load_lds((const __attribute__((address_space(1))) void*)ga,
                                       (__attribute__((address_space(3))) void*)la, 16, 0, 0);
      __builtin_amdgcn_global_load_lds((const __attribute__((address_space(1))) void*)gb,
                                       (__attribute__((address_space(3))) void*)lb, 16, 0, 0);
    }
    __syncthreads();
#pragma unroll
    for (int kk = 0; kk < 2; ++kk) {
      bf16x8 af[4], bfr[4];
      int krd = (kk << 5) + ((lane >> 4) << 3);
#pragma unroll
      for (int mi = 0; mi < 4; ++mi)
        af[mi] = *(const bf16x8*)&As[((wm << 6) + (mi << 4) + (lane & 15)) * 64 + krd];
#pragma unroll
      for (int ni = 0; ni < 4; ++ni)
        bfr[ni] = *(const bf16x8*)&Bs[((wn << 6) + (ni << 4) + (lane & 15)) * 64 + krd];
#pragma unroll
      for (int mi = 0; mi < 4; ++mi)
#pragma unroll
        for (int ni = 0; ni < 4; ++ni)
          acc[mi][ni] = __builtin_amdgcn_mfma_f32_16x16x32_bf16(af[mi], bfr[ni], acc[mi][ni], 0, 0, 0);
    }
    __syncthreads();
  }

#pragma unroll
  for (int mi = 0; mi < 4; ++mi) {
    int mrow0 = m0 + (wm << 6) + (mi << 4) + ((lane >> 4) << 2);
    int bq_ = mrow0 >> 12;
    int t0 = mrow0 & 4095;
#pragma unroll
    for (int ni = 0; ni < 4; ++ni) {
      int col = n0 + (wn << 6) + (ni << 4) + (lane & 15);
      float bv = bias[col];
      f32x4 v = acc[mi][ni];
      v.x += bv; v.y += bv; v.z += bv; v.w += bv;
      if (mode == 1) {
        // V layout (bf16): Ch[((b*8+h)*4096+t)*64 + d]
        size_t base = (size_t)(bq_ * 8 + (col >> 6)) * 4096;
        int d = col & 63;
        Ch[(base + t0 + 0) * 64 + d] = f2bf(v.x);
        Ch[(base + t0 + 1) * 64 + d] = f2bf(v.y);
        Ch[(base + t0 + 2) * 64 + d] = f2bf(v.z);
        Ch[(base + t0 + 3) * 64 + d] = f2bf(v.w);
      } else {
        Cf[(size_t)(mrow0 + 0) * 512 + col] = v.x;
        Cf[(size_t)(mrow0 + 1) * 512 + col] = v.y;
        Cf[(size_t)(mrow0 + 2) * 512 + col] = v.z;
        Cf[(size_t)(mrow0 + 3) * 512 + col] = v.w;
      }
    }
  }
}

// ---------------- FFT: radix-16 superstages (stage pairs fused in registers) ----------
__device__ __forceinline__ void r4(float& x0r, float& x0i, float& x1r, float& x1i,
                                   float& x2r, float& x2i, float& x3r, float& x3i,
                                   float2 w1, float2 w2, float2 w3) {
  float Ar = x0r + x2r, Ai = x0i + x2i;
  float Br = x0r - x2r, Bi = x0i - x2i;
  float Cr = x1r + x3r, Ci = x1i + x3i;
  float Dr = x1i - x3i, Di = x3r - x1r;  // -i*(x1-x3)
  x0r = Ar + Cr; x0i = Ai + Ci;
  float tr = Br + Dr, ti = Bi + Di;
  x1r = tr * w1.x - ti * w1.y; x1i = tr * w1.y + ti * w1.x;
  tr = Ar - Cr; ti = Ai - Ci;
  x2r = tr * w2.x - ti * w2.y; x2i = tr * w2.y + ti * w2.x;
  tr = Br - Dr; ti = Bi - Di;
  x3r = tr * w3.x - ti * w3.y; x3i = tr * w3.y + ti * w3.x;
}

__device__ __forceinline__ void fft16_superstages(float* re, float* im,
                                                  const float2* __restrict__ TW,
                                                  int u, bool active) {
#pragma unroll
  for (int ss = 0; ss < 3; ++ss) {
    const int lm = 10 - 4 * ss;      // 10, 6, 2
    const int m = 1 << lm;
    const int m4 = m >> 2;
    const int stw = 1 << (4 * ss);   // 1, 16, 256
    const int stw4 = stw << 2;
    if (active) {
      int jj = u & (m4 - 1);
      int g = u >> (lm - 2);
      int base = (g << (lm + 2)) + jj;
      float xr[4][4], xi[4][4];
#pragma unroll
      for (int a = 0; a < 4; ++a)
#pragma unroll
        for (int b = 0; b < 4; ++b) {
          int p = IDX(base + a * m + b * m4);
          xr[a][b] = re[p]; xi[a][b] = im[p];
        }
#pragma unroll
      for (int b = 0; b < 4; ++b) {
        int j1 = (b * m4 + jj) * stw;
        float2 w1 = TW[j1], w2 = TW[2 * j1], w3 = TW[3 * j1];
        r4(xr[0][b], xi[0][b], xr[1][b], xi[1][b], xr[2][b], xi[2][b], xr[3][b], xi[3][b], w1, w2, w3);
      }
      {
        int j2 = jj * stw4;
        float2 v1 = TW[j2], v2 = TW[2 * j2], v3 = TW[3 * j2];
#pragma unroll
        for (int a = 0; a < 4; ++a)
          r4(xr[a][0], xi[a][0], xr[a][1], xi[a][1], xr[a][2], xi[a][2], xr[a][3], xi[a][3], v1, v2, v3);
      }
#pragma unroll
      for (int a = 0; a < 4; ++a)
#pragma unroll
        for (int b = 0; b < 4; ++b) {
          int p = IDX(base + a * m + b * m4);
          re[p] = xr[a][b]; im[p] = xi[a][b];
        }
    }
    __syncthreads();
  }
}

// Packed FFT of z = q + i*k per (b,h,d); one wg (512 thr) handles 4 d's as
// 2 rounds of 2 CONCURRENT FFTs (256 units each, wave-uniform split).
// 512 wgs = 32 bh x 16 parts; NO atomics.
__global__ __launch_bounds__(512, 2)
void fft_corr(const float* __restrict__ QT, const float* __restrict__ KT,
              const float2* __restrict__ TW, float* __restrict__ PpartRe,
              float* __restrict__ PpartIm) {
  __shared__ float re[2][LDSN];
  __shared__ float im[2][LDSN];
  int wg = blockIdx.x;
  int bh = wg >> 4;
  int d0 = (wg & 15) << 2;
  int tid = threadIdx.x;
  const float* qb = QT + (size_t)bh * 64 * 4096;
  const float* kb = KT + (size_t)bh * 64 * 4096;
  float accR[8], accI[8];
#pragma unroll
  for (int j = 0; j < 8; ++j) { accR[j] = 0.f; accI[j] = 0.f; }
  for (int rr = 0; rr < 2; ++rr) {
    if (rr) __syncthreads();  // prior extraction reads done
#pragma unroll
    for (int ff = 0; ff < 2; ++ff) {
      const float4* q4 = (const float4*)(qb + (size_t)(d0 + 2 * rr + ff) * 4096);
      const float4* k4 = (const float4*)(kb + (size_t)(d0 + 2 * rr + ff) * 4096);
#pragma unroll
      for (int i = 0; i < 2; ++i) {
        int e4 = tid + (i << 9);
        float4 qv = q4[e4], kv = k4[e4];
        int e = e4 << 2;
        re[ff][IDX(e + 0)] = qv.x; im[ff][IDX(e + 0)] = kv.x;
        re[ff][IDX(e + 1)] = qv.y; im[ff][IDX(e + 1)] = kv.y;
        re[ff][IDX(e + 2)] = qv.z; im[ff][IDX(e + 2)] = kv.z;
        re[ff][IDX(e + 3)] = qv.w; im[ff][IDX(e + 3)] = kv.w;
      }
    }
    __syncthreads();
    // wave-uniform FFT split: waves 0-3 -> fft 0, waves 4-7 -> fft 1
    fft16_superstages(re[tid >> 8], im[tid >> 8], TW, tid & 255, true);
#pragma unroll
    for (int ff = 0; ff < 2; ++ff) {
#pragma unroll
      for (int j = 0; j < 8; ++j) {
        int p = tid + (j << 9);
        int f = rev4_12(p);
        int fn = (4096 - f) & 4095;
        int pn = rev4_12(fn);
        float zr = re[ff][IDX(p)], zi = im[ff][IDX(p)];
        float wr = re[ff][IDX(pn)], wi = im[ff][IDX(pn)];
        float qre = 0.5f * (zr + wr), qim = 0.5f * (zi - wi);
        float kre = 0.5f * (zi + wi), kim = 0.5f * (wr - zr);
        accR[j] += qre * kre + qim * kim;   // Re(Qf*conj(Kf))
        accI[j] += qim * kre - qre * kim;   // Im(Qf*conj(Kf))
      }
    }
  }
  float* pR = PpartRe + (size_t)wg * 4096;
  float* pI = PpartIm + (size_t)wg * 4096;
#pragma unroll
  for (int j = 0; j < 8; ++j) {
    int p = tid + (j << 9);
    pR[p] = accR[j];
    pI[p] = accI[j];
  }
}

// Reduce 16 partials per (b,h) -> Psum, float4. Grid 128 = 32 bh x 4 chunks of 1024 p.
__global__ void reduce_p(const float* __restrict__ PpartRe, const float* __restrict__ PpartIm,
                         float* __restrict__ PsumRe, float* __restrict__ PsumIm) {
  int wg = blockIdx.x;
  int bh = wg >> 2;
  int p4 = ((wg & 3) << 8) + threadIdx.x;  // float4 index 0..1023
  const float4* bR = (const float4*)(PpartRe + (size_t)bh * 16 * 4096);
  const float4* bI = (const float4*)(PpartIm + (size_t)bh * 16 * 4096);
  float4 sr = make_float4(0.f, 0.f, 0.f, 0.f);
  float4 si = make_float4(0.f, 0.f, 0.f, 0.f);
#pragma unroll
  for (int part = 0; part < 16; ++part) {
    float4 a = bR[part * 1024 + p4];
    float4 b = bI[part * 1024 + p4];
    sr.x += a.x; sr.y += a.y; sr.z += a.z; sr.w += a.w;
    si.x += b.x; si.y += b.y; si.z += b.z; si.w += b.w;
  }
  ((float4*)(PsumRe + (size_t)bh * 4096))[p4] = sr;
  ((float4*)(PsumIm + (size_t)bh * 4096))[p4] = si;
}

// Inverse FFT via conj + forward DIF (radix-16); corr(tau=rev4(p)) = re[p]/(4096*64).
__global__ __launch_bounds__(512, 1)
void ifft_topk(const float* __restrict__ PsumRe, const float* __restrict__ PsumIm,
               const float2* __restrict__ TW, float* __restrict__ attnW, int* __restrict__ delays) {
  __shared__ float re[LDSN];
  __shared__ float im[LDSN];
  __shared__ float wval[8];
  __shared__ int widx[8], wpos[8];
  int bh = blockIdx.x, tid = threadIdx.x;
  int lane = tid & 63, wv = tid >> 6;
  const float4* pr4 = (const float4*)(PsumRe + (size_t)bh * 4096);
  const float4* pi4 = (const float4*)(PsumIm + (size_t)bh * 4096);
#pragma unroll
  for (int i = 0; i < 2; ++i) {
    int e4 = tid + (i << 9);
    float4 a = pr4[e4], b = pi4[e4];
    int fb = rev4_12(e4 << 2);  // rev4 of (e4*4 + j) = fb | (j<<10)
    re[IDX(fb + 0 * 1024)] = a.x; im[IDX(fb + 0 * 1024)] = -b.x;
    re[IDX(fb + 1 * 1024)] = a.y; im[IDX(fb + 1 * 1024)] = -b.y;
    re[IDX(fb + 2 * 1024)] = a.z; im[IDX(fb + 2 * 1024)] = -b.z;
    re[IDX(fb + 3 * 1024)] = a.w; im[IDX(fb + 3 * 1024)] = -b.w;
  }
  __syncthreads();
  fft16_superstages(re, im, TW, tid & 255, tid < 256);
  const float SC = 1.0f / 262144.0f;  // 1/(L*Dh)
  float topv[8]; int topi[8];
#pragma unroll
  for (int pass = 0; pass < 8; ++pass) {
    float bv = -3.4e38f; int bi = 1 << 30; int bp = 0;
#pragma unroll
    for (int i = 0; i < 8; ++i) {
      int p = tid + (i << 9);
      float v = re[IDX(p)];
      int tau = rev4_12(p);
      if (v > bv || (v == bv && tau < bi)) { bv = v; bi = tau; bp = p; }
    }
#pragma unroll
    for (int off = 32; off > 0; off >>= 1) {
      float ov = __shfl_down(bv, off);
      int oi = __shfl_down(bi, off);
      int opp = __shfl_down(bp, off);
      if (ov > bv || (ov == bv && oi < bi)) { bv = ov; bi = oi; bp = opp; }
    }
    if (lane == 0) { wval[wv] = bv; widx[wv] = bi; wpos[wv] = bp; }
    __syncthreads();
    if (tid == 0) {
#pragma unroll
      for (int w2 = 1; w2 < 8; ++w2) {
        if (wval[w2] > bv || (wval[w2] == bv && widx[w2] < bi)) {
          bv = wval[w2]; bi = widx[w2]; bp = wpos[w2];
        }
      }
      topv[pass] = bv * SC;
      topi[pass] = bi;
      re[IDX(bp)] = -3.4e38f;
    }
    __syncthreads();
  }
  if (tid == 0) {
    float mx = topv[0];  // pass 0 = global max
    float ex[8], s = 0.f;
    for (int k = 0; k < 8; ++k) { ex[k] = expf(topv[k] - mx); s += ex[k]; }
    float inv = 1.0f / s;
    for (int k = 0; k < 8; ++k) {
      attnW[bh * 8 + k] = ex[k] * inv;
      delays[bh * 8 + k] = topi[k];
    }
  }
}

// out[b,h,t,:] = sum_k attn_k * V[b,h,(t-d_k)%L,:] (V bf16); write bf16 A for OUT gemm.
// Grid 4096 = 32 bh x 128 t-chunks of 32; thread handles 8 d's (16B loads/stores).
__global__ void gather_av(const unsigned short* __restrict__ Vh, const float* __restrict__ attnW,
                          const int* __restrict__ delays, unsigned short* __restrict__ Ahi) {
  int blk = blockIdx.x;
  int bh = blk >> 7, tb = blk & 127;
  int tid = threadIdx.x;
  int tt = tid >> 3, d8 = tid & 7;
  int t = (tb << 5) + tt;
  const unsigned short* Vb = Vh + (size_t)bh * 4096 * 64 + (d8 << 3);
  float w[8]; int dl[8];
#pragma unroll
  for (int kk = 0; kk < 8; ++kk) { w[kk] = attnW[bh * 8 + kk]; dl[kk] = delays[bh * 8 + kk]; }
  float a0 = 0.f, a1 = 0.f, a2 = 0.f, a3 = 0.f, a4 = 0.f, a5 = 0.f, a6 = 0.f, a7 = 0.f;
#pragma unroll
  for (int kk = 0; kk < 8; ++kk) {
    int row = (t - dl[kk]) & 4095;
    uint4 raw = *(const uint4*)(Vb + row * 64);
    float wk = w[kk];
    a0 += wk * bf2f((unsigned short)(raw.x & 0xFFFF));
    a1 += wk * bf2f((unsigned short)(raw.x >> 16));
    a2 += wk * bf2f((unsigned short)(raw.y & 0xFFFF));
    a3 += wk * bf2f((unsigned short)(raw.y >> 16));
    a4 += wk * bf2f((unsigned short)(raw.z & 0xFFFF));
    a5 += wk * bf2f((unsigned short)(raw.z >> 16));
    a6 += wk * bf2f((unsigned short)(raw.w & 0xFFFF));
    a7 += wk * bf2f((unsigned short)(raw.w >> 16));
  }
  int b = bh >> 3, h = bh & 7;
  size_t o = ((size_t)((b << 12) + t)) * 512 + (h << 6) + (d8 << 3);
  uint4 out;
  out.x = (unsigned)f2bf(a0) | ((unsigned)f2bf(a1) << 16);
  out.y = (unsigned)f2bf(a2) | ((unsigned)f2bf(a3) << 16);
  out.z = (unsigned)f2bf(a4) | ((unsigned)f2bf(a5) << 16);
  out.w = (unsigned)f2bf(a6) | ((unsigned)f2bf(a7) << 16);
  *(uint4*)(Ahi + o) = out;
}

// ---------------- orchestration ----------------
extern "C" void kernel_launch(void* const* d_in, const int* in_sizes, int n_in,
                              void* d_out, int out_size, void* d_ws, size_t ws_size,
                              hipStream_t stream) {
  (void)in_sizes; (void)n_in; (void)out_size; (void)ws_size;
  const float* x_q = (const float*)d_in[0];
  const float* x_kv = (const float*)d_in[1];
  const float* Wq = (const float*)d_in[2];
  const float* bq = (const float*)d_in[3];
  const float* Wk = (const float*)d_in[4];
  const float* bk = (const float*)d_in[5];
  const float* Wv = (const float*)d_in[6];
  const float* bv = (const float*)d_in[7];
  const float* Wo = (const float*)d_in[8];
  const float* bo = (const float*)d_in[9];
  float* out = (float*)d_out;
  char* ws = (char*)d_ws;

  // workspace layout (~137.1 MiB)
  // 0-16    AqHi          -> Vbuf16 (bf16, after qk_gemm8)
  // 16-32   AqLo
  // 36-52   AkvHi         -> PpartRe (8 MB, after v_gemm) -> Aattn (after reduce_p)
  // 52-68   AkvLo         -> PpartIm (8 MB)
  // 68-72   WTb (8 x 512x512 bf16)
  // 72-104  QT            -> PsumRe/PsumIm (after fft_corr)
  // 104-136 KT
  // 137+    attnW, delays, TW
  unsigned short* AqHi  = (unsigned short*)(ws + 0 * MiB);
  unsigned short* AqLo  = (unsigned short*)(ws + 16 * MiB);
  unsigned short* Vbuf16 = (unsigned short*)(ws + 0 * MiB);
  unsigned short* AkvHi = (unsigned short*)(ws + 36 * MiB);
  unsigned short* AkvLo = (unsigned short*)(ws + 52 * MiB);
  float* PpartRe = (float*)(ws + 36 * MiB);
  float* PpartIm = (float*)(ws + 52 * MiB);
  unsigned short* Aattn = (unsigned short*)(ws + 36 * MiB);
  unsigned short* WTb   = (unsigned short*)(ws + 68 * MiB);
  float* QT    = (float*)(ws + 72 * MiB);
  float* KT    = (float*)(ws + 104 * MiB);
  float* PsumRe = (float*)(ws + 72 * MiB);
  float* PsumIm = (float*)(ws + 73 * MiB);
  float* attnW = (float*)(ws + 137 * MiB);
  int*   delays = (int*)(ws + 137 * MiB + 4096);
  float2* TW   = (float2*)(ws + 137 * MiB + 8192);

  int n4 = (16384 * 512) / 4;
  prep_all<<<dim3(16652), dim3(256), 0, stream>>>(x_q, x_kv, AqHi, AqLo, AkvHi, AkvLo,
                                                  Wq, Wk, Wv, Wo, WTb, TW, n4);

  // Q and K projections fused, 256^2 8-phase (256 wgs x 512 thr = 1 block/CU).
  qk_gemm8<<<dim3(256), dim3(512), 0, stream>>>(AqHi, AqLo, AkvHi, AkvLo, WTb, bq, bk, QT, KT);
  gemm_bf16<<<dim3(512), dim3(256), 0, stream>>>(AkvHi, WTb + 4 * 262144, bv, nullptr, Vbuf16, 1);

  fft_corr<<<dim3(512), dim3(512), 0, stream>>>(QT, KT, TW, PpartRe, PpartIm);
  reduce_p<<<dim3(128), dim3(256), 0, stream>>>(PpartRe, PpartIm, PsumRe, PsumIm);
  ifft_topk<<<dim3(32), dim3(512), 0, stream>>>(PsumRe, PsumIm, TW, attnW, delays);
  gather_av<<<dim3(4096), dim3(256), 0, stream>>>(Vbuf16, attnW, delays, Aattn);

  // out = gathered @ Wo + bo (plain bf16 -> f32 out)
  gemm_bf16<<<dim3(512), dim3(256), 0, stream>>>(Aattn, WTb + 6 * 262144, bo, out, nullptr, 2);
}

// Round 10
// 184.852 us; speedup vs baseline: 5.5516x; 1.0378x over previous
//
#include <hip/hip_runtime.h>
#include <hip/hip_bf16.h>

// AutoCorrelation layer: QKV proj (bf16x3 MFMA GEMM; Q+K on a 256^2 8-phase
// counted-vmcnt schedule; V/OUT on dbuf-prefetch 128^2) -> packed FFT cross-corr
// (radix-16 in-register superstages; partials + reduce + ifft, NO atomics) ->
// single-pass bitonic top-8 + softmax -> delay-gather of V (bf16) -> output proj.
// B=4, L=4096, D=512, H=8, Dh=64.

#define MiB (1024ull * 1024ull)

typedef __attribute__((ext_vector_type(8))) short bf16x8;
typedef __attribute__((ext_vector_type(4))) float f32x4;
static_assert(sizeof(bf16x8) == 16, "bf16x8 must be 16B");

__device__ __forceinline__ unsigned short f2bf(float f) {
  unsigned u = __float_as_uint(f);
  unsigned r = (u + 0x7FFFu + ((u >> 16) & 1u)) >> 16;  // RN-even
  return (unsigned short)r;
}
__device__ __forceinline__ float bf2f(unsigned short h) {
  return __uint_as_float(((unsigned)h) << 16);
}
// base-4 digit reversal of a 12-bit index (involution)
__device__ __forceinline__ int rev4_12(int x) {
  unsigned r = __brev((unsigned)x) >> 20;
  return (int)(((r & 0xAAAu) >> 1) | ((r & 0x555u) << 1));
}
// LDS pad: +1 float per 32 to break power-of-2 bank patterns
#define IDX(e) ((e) + ((e) >> 5))
#define LDSN (4095 + (4095 >> 5) + 1)

// XCD-aware bijective swizzle (nwg % 8 == 0): XCD x owns contiguous logical chunk.
__device__ __forceinline__ int xcd_swz(int bid, int cpx) {
  return (bid & 7) * cpx + (bid >> 3);
}

#define BARRIER() do { asm volatile("" ::: "memory"); __builtin_amdgcn_s_barrier(); asm volatile("" ::: "memory"); } while (0)
#define WAITV6() asm volatile("s_waitcnt vmcnt(6)" ::: "memory")

// ---------------- fused prep: x hi/lo splits + W transposes + twiddle table ----------
__global__ void prep_all(const float* __restrict__ xq, const float* __restrict__ xkv,
                         unsigned short* __restrict__ qhi, unsigned short* __restrict__ qlo,
                         unsigned short* __restrict__ khi, unsigned short* __restrict__ klo,
                         const float* __restrict__ W0, const float* __restrict__ W1,
                         const float* __restrict__ W2, const float* __restrict__ W3,
                         unsigned short* __restrict__ WT, float2* __restrict__ TWt, int n4) {
  __shared__ float t[64][65];
  int blk = blockIdx.x;
  int tid = threadIdx.x;
  if (blk < 16384) {
    int i = blk * 256 + tid;
    const float* x = (i < n4) ? xq : xkv;
    unsigned short* hi = (i < n4) ? qhi : khi;
    unsigned short* lo = (i < n4) ? qlo : klo;
    int ii = (i < n4) ? i : i - n4;
    float4 v = ((const float4*)x)[ii];
    ushort4 h, l;
    float f;
    f = v.x; h.x = f2bf(f); l.x = f2bf(f - bf2f(h.x));
    f = v.y; h.y = f2bf(f); l.y = f2bf(f - bf2f(h.y));
    f = v.z; h.z = f2bf(f); l.z = f2bf(f - bf2f(h.z));
    f = v.w; h.w = f2bf(f); l.w = f2bf(f - bf2f(h.w));
    ((ushort4*)hi)[ii] = h;
    ((ushort4*)lo)[ii] = l;
  } else if (blk < 16640) {
    int bx = blk - 16384;
    int w = bx >> 6, tile = bx & 63;
    int k0 = (tile >> 3) << 6, n0 = (tile & 7) << 6;
    const float* W = (w == 0) ? W0 : (w == 1) ? W1 : (w == 2) ? W2 : W3;
    unsigned short* hi = WT + (size_t)(2 * w) * 262144;
    unsigned short* lo = hi + 262144;
#pragma unroll
    for (int j = 0; j < 4; ++j) {
      int i = tid + (j << 8);
      int rr = i >> 4, c4 = (i & 15) << 2;
      float4 v = *(const float4*)&W[(size_t)(k0 + rr) * 512 + n0 + c4];
      t[rr][c4 + 0] = v.x; t[rr][c4 + 1] = v.y;
      t[rr][c4 + 2] = v.z; t[rr][c4 + 3] = v.w;
    }
    __syncthreads();
#pragma unroll
    for (int j = 0; j < 4; ++j) {
      int i = tid + (j << 8);
      int nn = i >> 4, k4 = (i & 15) << 2;
      ushort4 h, l;
      float f;
      f = t[k4 + 0][nn]; h.x = f2bf(f); l.x = f2bf(f - bf2f(h.x));
      f = t[k4 + 1][nn]; h.y = f2bf(f); l.y = f2bf(f - bf2f(h.y));
      f = t[k4 + 2][nn]; h.z = f2bf(f); l.z = f2bf(f - bf2f(h.z));
      f = t[k4 + 3][nn]; h.w = f2bf(f); l.w = f2bf(f - bf2f(h.w));
      size_t o = (size_t)(n0 + nn) * 512 + k0 + k4;
      *(ushort4*)(hi + o) = h;
      *(ushort4*)(lo + o) = l;
    }
  } else {
    int r = (blk - 16640) * 256 + tid;
    if (r < 3072) {
      double a = -2.0 * 3.14159265358979323846 * (double)r / 4096.0;
      TWt[r] = make_float2((float)cos(a), (float)sin(a));
    }
  }
}

// ---------------- fused Q+K GEMM: 256^2 tile, 8-wave, 4-phase/K-tile, counted vmcnt ----
__global__ __launch_bounds__(512, 2)
void qk_gemm8(const unsigned short* __restrict__ AqHi, const unsigned short* __restrict__ AqLo,
              const unsigned short* __restrict__ AkvHi, const unsigned short* __restrict__ AkvLo,
              const unsigned short* __restrict__ WT,
              const float* __restrict__ bq, const float* __restrict__ bk,
              float* __restrict__ QT, float* __restrict__ KT) {
  __shared__ __align__(16) char lds[131072];
  int tid = threadIdx.x;
  int lane = tid & 63, wv = tid >> 6;
  int wm = wv >> 2, wn = wv & 3;

  int sw = xcd_swz(blockIdx.x, 32);  // 256 wgs
  int op = sw >> 7;                  // 0 = Q, 1 = K
  int r = sw & 127;
  int m0 = (r >> 1) << 8;            // 64 M-tiles
  int n0 = (r & 1) << 8;             // 2 N-tiles

  const unsigned short* Ahi = op ? AkvHi : AqHi;
  const unsigned short* Alo = op ? AkvLo : AqLo;
  const unsigned short* Bhi = WT + (op ? 2 * 262144 : 0);
  const unsigned short* Blo = Bhi + 262144;
  const float* bias = op ? bk : bq;
  float* C = op ? KT : QT;

  int aoff0 = ((lane & 15) << 7) + ((((lane >> 4) + 0) ^ (lane & 7)) << 4);  // ks=0
  int aoff1 = ((lane & 15) << 7) + ((((lane >> 4) + 4) ^ (lane & 7)) << 4);  // ks=1
  int src_row = tid >> 3;
  int src_col = (tid & 7) ^ (src_row & 7);

  f32x4 acc[8][4];
  const f32x4 zz = {0.f, 0.f, 0.f, 0.f};
#pragma unroll
  for (int i = 0; i < 8; ++i)
#pragma unroll
    for (int j = 0; j < 4; ++j) acc[i][j] = zz;

  auto APTR = [&](int v) {
    const unsigned short* p = (v >= 16) ? Alo : Ahi;
    return p + (size_t)m0 * 512 + ((v & 7) << 6);
  };
  auto BPTR = [&](int v) {
    const unsigned short* p = (v >= 8 && v < 16) ? Blo : Bhi;
    return p + (size_t)n0 * 512 + ((v & 7) << 6);
  };
  auto STAGE = [&](const unsigned short* gbase, int R0, int ldsOff) {
    const unsigned short* ga = gbase + (size_t)(R0 + src_row) * 512 + (src_col << 3);
    char* la = lds + ldsOff + (R0 << 7) + (wv << 10);
    __builtin_amdgcn_global_load_lds((const __attribute__((address_space(1))) void*)ga,
                                     (__attribute__((address_space(3))) void*)la, 16, 0, 0);
  };
#define RDA(o, mi, ks) (*(const bf16x8*)(lds + (o) + (wm << 14) + ((mi) << 11) + aoff##ks))
#define RDB(o, ni, ks) (*(const bf16x8*)(lds + (o) + 32768 + (wn << 13) + ((ni) << 11) + aoff##ks))
#define MFMA_PAIR(mi0, A0, A1)                                                              \
  __builtin_amdgcn_s_setprio(1);                                                            \
  _Pragma("unroll") for (int ks = 0; ks < 2; ++ks) {                                        \
    _Pragma("unroll") for (int ni = 0; ni < 4; ++ni) {                                      \
      acc[mi0][ni] = __builtin_amdgcn_mfma_f32_16x16x32_bf16(A0[ks], b[ni][ks], acc[mi0][ni], 0, 0, 0);          \
      acc[mi0 + 1][ni] = __builtin_amdgcn_mfma_f32_16x16x32_bf16(A1[ks], b[ni][ks], acc[mi0 + 1][ni], 0, 0, 0);  \
    }                                                                                       \
  }                                                                                         \
  __builtin_amdgcn_s_setprio(0)

  STAGE(BPTR(0), 0, 32768);   STAGE(BPTR(0), 64, 32768);
  STAGE(BPTR(0), 128, 32768); STAGE(BPTR(0), 192, 32768);
  STAGE(APTR(0), 0, 0);       STAGE(APTR(0), 64, 0);
  STAGE(APTR(0), 128, 0);     STAGE(APTR(0), 192, 0);
  STAGE(BPTR(1), 0, 65536 + 32768);   STAGE(BPTR(1), 64, 65536 + 32768);
  STAGE(BPTR(1), 128, 65536 + 32768); STAGE(BPTR(1), 192, 65536 + 32768);
  STAGE(APTR(1), 0, 65536);           STAGE(APTR(1), 128, 65536);
  WAITV6();
  BARRIER();

  for (int t = 0; t < 24; ++t) {
    int o = (t & 1) << 16;
    int on = o ^ 65536;
    int t1 = (t + 1 < 24) ? t + 1 : 23;
    int t2 = (t + 2 < 24) ? t + 2 : 23;
    const unsigned short* a1p = APTR(t1);
    const unsigned short* a2p = APTR(t2);
    const unsigned short* b2p = BPTR(t2);

    bf16x8 b[4][2], aA[2][2];
#pragma unroll
    for (int ni = 0; ni < 4; ++ni) { b[ni][0] = RDB(o, ni, 0); b[ni][1] = RDB(o, ni, 1); }
    aA[0][0] = RDA(o, 0, 0); aA[0][1] = RDA(o, 0, 1);
    aA[1][0] = RDA(o, 1, 0); aA[1][1] = RDA(o, 1, 1);
    STAGE(a1p, 64, on); STAGE(a1p, 192, on);
    BARRIER();
    MFMA_PAIR(0, aA[0], aA[1]);
    BARRIER();

    aA[0][0] = RDA(o, 2, 0); aA[0][1] = RDA(o, 2, 1);
    aA[1][0] = RDA(o, 3, 0); aA[1][1] = RDA(o, 3, 1);
    STAGE(b2p, 0, o + 32768); STAGE(b2p, 64, o + 32768);
    BARRIER();
    MFMA_PAIR(2, aA[0], aA[1]);
    BARRIER();

    aA[0][0] = RDA(o, 4, 0); aA[0][1] = RDA(o, 4, 1);
    aA[1][0] = RDA(o, 5, 0); aA[1][1] = RDA(o, 5, 1);
    STAGE(b2p, 128, o + 32768); STAGE(b2p, 192, o + 32768);
    BARRIER();
    MFMA_PAIR(4, aA[0], aA[1]);
    BARRIER();

    aA[0][0] = RDA(o, 6, 0); aA[0][1] = RDA(o, 6, 1);
    aA[1][0] = RDA(o, 7, 0); aA[1][1] = RDA(o, 7, 1);
    STAGE(a2p, 0, o); STAGE(a2p, 128, o);
    BARRIER();
    MFMA_PAIR(6, aA[0], aA[1]);
    WAITV6();
    BARRIER();
  }
#undef RDA
#undef RDB
#undef MFMA_PAIR

#pragma unroll
  for (int mi = 0; mi < 8; ++mi) {
    int mrow0 = m0 + (wm << 7) + (mi << 4) + ((lane >> 4) << 2);
    int bq_ = mrow0 >> 12;
    int t0 = mrow0 & 4095;
#pragma unroll
    for (int ni = 0; ni < 4; ++ni) {
      int col = n0 + (wn << 6) + (ni << 4) + (lane & 15);
      float bv = bias[col];
      f32x4 v = acc[mi][ni];
      v.x += bv; v.y += bv; v.z += bv; v.w += bv;
      *(f32x4*)&C[((size_t)(bq_ * 512 + col)) * 4096 + t0] = v;
    }
  }
}

// ---------------- generic GEMM: V (mode 1, bf16 out) and OUT (mode 2, f32 out) ---------
// Double-buffered LDS + stage-next-before-compute (T3-min 2-phase): loads for K-tile
// t+1 stay in flight under tile t's ds_read+MFMA; one vmcnt(0)+barrier per tile.
__global__ __launch_bounds__(256, 2)
void gemm_bf16(const unsigned short* __restrict__ Ahi,
               const unsigned short* __restrict__ Bhi,
               const float* __restrict__ bias, float* __restrict__ Cf,
               unsigned short* __restrict__ Ch, int mode) {
  __shared__ short As[2][128 * 64];
  __shared__ short Bs[2][128 * 64];
  int bx = xcd_swz(blockIdx.x, 64);  // 512 wgs
  int bm = bx >> 2, bn = bx & 3;
  int m0 = bm << 7, n0 = bn << 7;
  int tid = threadIdx.x;
  int lane = tid & 63, wv = tid >> 6;
  int wm = wv >> 1, wn = wv & 1;

  const f32x4 zz = {0.f, 0.f, 0.f, 0.f};
  f32x4 acc[4][4];
#pragma unroll
  for (int i = 0; i < 4; ++i)
#pragma unroll
    for (int j = 0; j < 4; ++j) acc[i][j] = zz;

  int srow = tid >> 3;
  int sk = (tid & 7) << 3;
  auto STAGE = [&](int ks, int buf) {
    int kb = ks << 6;
#pragma unroll
    for (int i = 0; i < 4; ++i) {
      int r = (i << 5) + srow;
      const unsigned short* ga = Ahi + (size_t)(m0 + r) * 512 + kb + sk;
      const unsigned short* gb = Bhi + (size_t)(n0 + r) * 512 + kb + sk;
      char* la = (char*)As[buf] + (i << 12) + (wv << 10);
      char* lb = (char*)Bs[buf] + (i << 12) + (wv << 10);
      __builtin_amdgcn_global_load_lds((const __attribute__((address_space(1))) void*)ga,
                                       (__attribute__((address_space(3))) void*)la, 16, 0, 0);
      __builtin_amdgcn_global_load_lds((const __attribute__((address_space(1))) void*)gb,
                                       (__attribute__((address_space(3))) void*)lb, 16, 0, 0);
    }
  };

  STAGE(0, 0);
  __syncthreads();
  for (int ks = 0; ks < 8; ++ks) {
    int buf = ks & 1;
    if (ks < 7) STAGE(ks + 1, buf ^ 1);
#pragma unroll
    for (int kk = 0; kk < 2; ++kk) {
      bf16x8 af[4], bfr[4];
      int krd = (kk << 5) + ((lane >> 4) << 3);
#pragma unroll
      for (int mi = 0; mi < 4; ++mi)
        af[mi] = *(const bf16x8*)&As[buf][((wm << 6) + (mi << 4) + (lane & 15)) * 64 + krd];
#pragma unroll
      for (int ni = 0; ni < 4; ++ni)
        bfr[ni] = *(const bf16x8*)&Bs[buf][((wn << 6) + (ni << 4) + (lane & 15)) * 64 + krd];
#pragma unroll
      for (int mi = 0; mi < 4; ++mi)
#pragma unroll
        for (int ni = 0; ni < 4; ++ni)
          acc[mi][ni] = __builtin_amdgcn_mfma_f32_16x16x32_bf16(af[mi], bfr[ni], acc[mi][ni], 0, 0, 0);
    }
    __syncthreads();  // drains ks+1 loads; protects buf reuse at ks+2
  }

#pragma unroll
  for (int mi = 0; mi < 4; ++mi) {
    int mrow0 = m0 + (wm << 6) + (mi << 4) + ((lane >> 4) << 2);
    int bq_ = mrow0 >> 12;
    int t0 = mrow0 & 4095;
#pragma unroll
    for (int ni = 0; ni < 4; ++ni) {
      int col = n0 + (wn << 6) + (ni << 4) + (lane & 15);
      float bv = bias[col];
      f32x4 v = acc[mi][ni];
      v.x += bv; v.y += bv; v.z += bv; v.w += bv;
      if (mode == 1) {
        // V layout (bf16): Ch[((b*8+h)*4096+t)*64 + d]
        size_t base = (size_t)(bq_ * 8 + (col >> 6)) * 4096;
        int d = col & 63;
        Ch[(base + t0 + 0) * 64 + d] = f2bf(v.x);
        Ch[(base + t0 + 1) * 64 + d] = f2bf(v.y);
        Ch[(base + t0 + 2) * 64 + d] = f2bf(v.z);
        Ch[(base + t0 + 3) * 64 + d] = f2bf(v.w);
      } else {
        Cf[(size_t)(mrow0 + 0) * 512 + col] = v.x;
        Cf[(size_t)(mrow0 + 1) * 512 + col] = v.y;
        Cf[(size_t)(mrow0 + 2) * 512 + col] = v.z;
        Cf[(size_t)(mrow0 + 3) * 512 + col] = v.w;
      }
    }
  }
}

// ---------------- FFT: radix-16 superstages (stage pairs fused in registers) ----------
__device__ __forceinline__ void r4(float& x0r, float& x0i, float& x1r, float& x1i,
                                   float& x2r, float& x2i, float& x3r, float& x3i,
                                   float2 w1, float2 w2, float2 w3) {
  float Ar = x0r + x2r, Ai = x0i + x2i;
  float Br = x0r - x2r, Bi = x0i - x2i;
  float Cr = x1r + x3r, Ci = x1i + x3i;
  float Dr = x1i - x3i, Di = x3r - x1r;  // -i*(x1-x3)
  x0r = Ar + Cr; x0i = Ai + Ci;
  float tr = Br + Dr, ti = Bi + Di;
  x1r = tr * w1.x - ti * w1.y; x1i = tr * w1.y + ti * w1.x;
  tr = Ar - Cr; ti = Ai - Ci;
  x2r = tr * w2.x - ti * w2.y; x2i = tr * w2.y + ti * w2.x;
  tr = Br - Dr; ti = Bi - Di;
  x3r = tr * w3.x - ti * w3.y; x3i = tr * w3.y + ti * w3.x;
}

__device__ __forceinline__ void fft16_superstages(float* re, float* im,
                                                  const float2* __restrict__ TW,
                                                  int u, bool active) {
#pragma unroll
  for (int ss = 0; ss < 3; ++ss) {
    const int lm = 10 - 4 * ss;      // 10, 6, 2
    const int m = 1 << lm;
    const int m4 = m >> 2;
    const int stw = 1 << (4 * ss);   // 1, 16, 256
    const int stw4 = stw << 2;
    if (active) {
      int jj = u & (m4 - 1);
      int g = u >> (lm - 2);
      int base = (g << (lm + 2)) + jj;
      float xr[4][4], xi[4][4];
#pragma unroll
      for (int a = 0; a < 4; ++a)
#pragma unroll
        for (int b = 0; b < 4; ++b) {
          int p = IDX(base + a * m + b * m4);
          xr[a][b] = re[p]; xi[a][b] = im[p];
        }
#pragma unroll
      for (int b = 0; b < 4; ++b) {
        int j1 = (b * m4 + jj) * stw;
        float2 w1 = TW[j1], w2 = TW[2 * j1], w3 = TW[3 * j1];
        r4(xr[0][b], xi[0][b], xr[1][b], xi[1][b], xr[2][b], xi[2][b], xr[3][b], xi[3][b], w1, w2, w3);
      }
      {
        int j2 = jj * stw4;
        float2 v1 = TW[j2], v2 = TW[2 * j2], v3 = TW[3 * j2];
#pragma unroll
        for (int a = 0; a < 4; ++a)
          r4(xr[a][0], xi[a][0], xr[a][1], xi[a][1], xr[a][2], xi[a][2], xr[a][3], xi[a][3], v1, v2, v3);
      }
#pragma unroll
      for (int a = 0; a < 4; ++a)
#pragma unroll
        for (int b = 0; b < 4; ++b) {
          int p = IDX(base + a * m + b * m4);
          re[p] = xr[a][b]; im[p] = xi[a][b];
        }
    }
    __syncthreads();
  }
}

// Packed FFT of z = q + i*k per (b,h,d); one wg (512 thr) handles 4 d's as
// 2 rounds of 2 CONCURRENT FFTs (256 units each, wave-uniform split).
// 512 wgs = 32 bh x 16 parts; NO atomics.
__global__ __launch_bounds__(512, 2)
void fft_corr(const float* __restrict__ QT, const float* __restrict__ KT,
              const float2* __restrict__ TW, float* __restrict__ PpartRe,
              float* __restrict__ PpartIm) {
  __shared__ float re[2][LDSN];
  __shared__ float im[2][LDSN];
  int wg = blockIdx.x;
  int bh = wg >> 4;
  int d0 = (wg & 15) << 2;
  int tid = threadIdx.x;
  const float* qb = QT + (size_t)bh * 64 * 4096;
  const float* kb = KT + (size_t)bh * 64 * 4096;
  float accR[8], accI[8];
#pragma unroll
  for (int j = 0; j < 8; ++j) { accR[j] = 0.f; accI[j] = 0.f; }
  for (int rr = 0; rr < 2; ++rr) {
    if (rr) __syncthreads();  // prior extraction reads done
#pragma unroll
    for (int ff = 0; ff < 2; ++ff) {
      const float4* q4 = (const float4*)(qb + (size_t)(d0 + 2 * rr + ff) * 4096);
      const float4* k4 = (const float4*)(kb + (size_t)(d0 + 2 * rr + ff) * 4096);
#pragma unroll
      for (int i = 0; i < 2; ++i) {
        int e4 = tid + (i << 9);
        float4 qv = q4[e4], kv = k4[e4];
        int e = e4 << 2;
        re[ff][IDX(e + 0)] = qv.x; im[ff][IDX(e + 0)] = kv.x;
        re[ff][IDX(e + 1)] = qv.y; im[ff][IDX(e + 1)] = kv.y;
        re[ff][IDX(e + 2)] = qv.z; im[ff][IDX(e + 2)] = kv.z;
        re[ff][IDX(e + 3)] = qv.w; im[ff][IDX(e + 3)] = kv.w;
      }
    }
    __syncthreads();
    // wave-uniform FFT split: waves 0-3 -> fft 0, waves 4-7 -> fft 1
    fft16_superstages(re[tid >> 8], im[tid >> 8], TW, tid & 255, true);
#pragma unroll
    for (int ff = 0; ff < 2; ++ff) {
#pragma unroll
      for (int j = 0; j < 8; ++j) {
        int p = tid + (j << 9);
        int f = rev4_12(p);
        int fn = (4096 - f) & 4095;
        int pn = rev4_12(fn);
        float zr = re[ff][IDX(p)], zi = im[ff][IDX(p)];
        float wr = re[ff][IDX(pn)], wi = im[ff][IDX(pn)];
        float qre = 0.5f * (zr + wr), qim = 0.5f * (zi - wi);
        float kre = 0.5f * (zi + wi), kim = 0.5f * (wr - zr);
        accR[j] += qre * kre + qim * kim;   // Re(Qf*conj(Kf))
        accI[j] += qim * kre - qre * kim;   // Im(Qf*conj(Kf))
      }
    }
  }
  float* pR = PpartRe + (size_t)wg * 4096;
  float* pI = PpartIm + (size_t)wg * 4096;
#pragma unroll
  for (int j = 0; j < 8; ++j) {
    int p = tid + (j << 9);
    pR[p] = accR[j];
    pI[p] = accI[j];
  }
}

// Reduce 16 partials per (b,h) -> Psum, float4. Grid 128 = 32 bh x 4 chunks of 1024 p.
__global__ void reduce_p(const float* __restrict__ PpartRe, const float* __restrict__ PpartIm,
                         float* __restrict__ PsumRe, float* __restrict__ PsumIm) {
  int wg = blockIdx.x;
  int bh = wg >> 2;
  int p4 = ((wg & 3) << 8) + threadIdx.x;  // float4 index 0..1023
  const float4* bR = (const float4*)(PpartRe + (size_t)bh * 16 * 4096);
  const float4* bI = (const float4*)(PpartIm + (size_t)bh * 16 * 4096);
  float4 sr = make_float4(0.f, 0.f, 0.f, 0.f);
  float4 si = make_float4(0.f, 0.f, 0.f, 0.f);
#pragma unroll
  for (int part = 0; part < 16; ++part) {
    float4 a = bR[part * 1024 + p4];
    float4 b = bI[part * 1024 + p4];
    sr.x += a.x; sr.y += a.y; sr.z += a.z; sr.w += a.w;
    si.x += b.x; si.y += b.y; si.z += b.z; si.w += b.w;
  }
  ((float4*)(PsumRe + (size_t)bh * 4096))[p4] = sr;
  ((float4*)(PsumIm + (size_t)bh * 4096))[p4] = si;
}

// Inverse FFT via conj + forward DIF (radix-16); corr(tau=rev4(p)) = re[p]/(4096*64).
// Single-pass top-8: pack (value,tau) -> ordered u64 key; per-thread sort-8;
// 6-level shfl_xor butterfly with Batcher half-cleaner; final 8-list serial merge.
__global__ __launch_bounds__(512, 1)
void ifft_topk(const float* __restrict__ PsumRe, const float* __restrict__ PsumIm,
               const float2* __restrict__ TW, float* __restrict__ attnW, int* __restrict__ delays) {
  __shared__ float re[LDSN];
  __shared__ float im[LDSN];
  __shared__ unsigned long long sh[8][8];
  int bh = blockIdx.x, tid = threadIdx.x;
  int lane = tid & 63, wv = tid >> 6;
  const float4* pr4 = (const float4*)(PsumRe + (size_t)bh * 4096);
  const float4* pi4 = (const float4*)(PsumIm + (size_t)bh * 4096);
#pragma unroll
  for (int i = 0; i < 2; ++i) {
    int e4 = tid + (i << 9);
    float4 a = pr4[e4], b = pi4[e4];
    int fb = rev4_12(e4 << 2);  // rev4 of (e4*4 + j) = fb | (j<<10)
    re[IDX(fb + 0 * 1024)] = a.x; im[IDX(fb + 0 * 1024)] = -b.x;
    re[IDX(fb + 1 * 1024)] = a.y; im[IDX(fb + 1 * 1024)] = -b.y;
    re[IDX(fb + 2 * 1024)] = a.z; im[IDX(fb + 2 * 1024)] = -b.z;
    re[IDX(fb + 3 * 1024)] = a.w; im[IDX(fb + 3 * 1024)] = -b.w;
  }
  __syncthreads();
  fft16_superstages(re, im, TW, tid & 255, tid < 256);

  // build per-thread desc-sorted 8 keys (value desc, tau asc on ties)
  unsigned long long k[8];
#pragma unroll
  for (int i = 0; i < 8; ++i) {
    int p = tid + (i << 9);
    float v = re[IDX(p)];
    int tau = rev4_12(p);
    unsigned u = __float_as_uint(v);
    unsigned s = u ^ (unsigned)(((int)u >> 31) | 0x80000000);  // order-preserving map
    k[i] = ((unsigned long long)s << 12) | (unsigned)(4095 - tau);
  }
#define CSWAP(a, b) { if (k[a] < k[b]) { unsigned long long t_ = k[a]; k[a] = k[b]; k[b] = t_; } }
  // insertion network (28 comparators), descending
#pragma unroll
  for (int i = 1; i < 8; ++i)
#pragma unroll
    for (int j = 8 - 1; j >= 1; --j)
      if (j <= i) CSWAP(j - 1, j);
  // butterfly merge across 64 lanes: keep top-8 of pairwise unions
#pragma unroll
  for (int off = 1; off < 64; off <<= 1) {
    unsigned long long b[8];
#pragma unroll
    for (int i = 0; i < 8; ++i)
      b[i] = (unsigned long long)__shfl_xor((long long)k[i], off);
#pragma unroll
    for (int i = 0; i < 8; ++i) {
      unsigned long long m = b[7 - i];        // half-cleaner: max(A[i], B[7-i])
      k[i] = (k[i] > m) ? k[i] : m;
    }
    // bitonic clean (descending), distances 4, 2, 1
#pragma unroll
    for (int d = 4; d > 0; d >>= 1)
#pragma unroll
      for (int i = 0; i < 8; ++i)
        if ((i & d) == 0 && (i ^ d) < 8) CSWAP(i, i + d);
  }
#undef CSWAP
  if (lane == 0) {
#pragma unroll
    for (int i = 0; i < 8; ++i) sh[wv][i] = k[i];
  }
  __syncthreads();
  if (tid == 0) {
    const float SC = 1.0f / 262144.0f;  // 1/(L*Dh)
    int idx[8] = {0, 0, 0, 0, 0, 0, 0, 0};
    float topv[8]; int topi[8];
#pragma unroll
    for (int pass = 0; pass < 8; ++pass) {
      int bw = 0;
      unsigned long long bk = sh[0][idx[0]];
#pragma unroll
      for (int w = 1; w < 8; ++w) {
        unsigned long long c = sh[w][idx[w]];
        if (c > bk) { bk = c; bw = w; }
      }
      idx[bw]++;
      unsigned s = (unsigned)(bk >> 12);
      unsigned u = (s & 0x80000000u) ? (s ^ 0x80000000u) : ~s;
      topv[pass] = __uint_as_float(u) * SC;
      topi[pass] = 4095 - (int)(bk & 4095u);
    }
    float mx = topv[0];  // pass 0 = global max
    float ex[8], ssum = 0.f;
    for (int q = 0; q < 8; ++q) { ex[q] = expf(topv[q] - mx); ssum += ex[q]; }
    float inv = 1.0f / ssum;
    for (int q = 0; q < 8; ++q) {
      attnW[bh * 8 + q] = ex[q] * inv;
      delays[bh * 8 + q] = topi[q];
    }
  }
}

// out[b,h,t,:] = sum_k attn_k * V[b,h,(t-d_k)%L,:] (V bf16); write bf16 A for OUT gemm.
// Grid 4096 = 32 bh x 128 t-chunks of 32; thread handles 8 d's (16B loads/stores).
__global__ void gather_av(const unsigned short* __restrict__ Vh, const float* __restrict__ attnW,
                          const int* __restrict__ delays, unsigned short* __restrict__ Ahi) {
  int blk = blockIdx.x;
  int bh = blk >> 7, tb = blk & 127;
  int tid = threadIdx.x;
  int tt = tid >> 3, d8 = tid & 7;
  int t = (tb << 5) + tt;
  const unsigned short* Vb = Vh + (size_t)bh * 4096 * 64 + (d8 << 3);
  float w[8]; int dl[8];
#pragma unroll
  for (int kk = 0; kk < 8; ++kk) { w[kk] = attnW[bh * 8 + kk]; dl[kk] = delays[bh * 8 + kk]; }
  float a0 = 0.f, a1 = 0.f, a2 = 0.f, a3 = 0.f, a4 = 0.f, a5 = 0.f, a6 = 0.f, a7 = 0.f;
#pragma unroll
  for (int kk = 0; kk < 8; ++kk) {
    int row = (t - dl[kk]) & 4095;
    uint4 raw = *(const uint4*)(Vb + row * 64);
    float wk = w[kk];
    a0 += wk * bf2f((unsigned short)(raw.x & 0xFFFF));
    a1 += wk * bf2f((unsigned short)(raw.x >> 16));
    a2 += wk * bf2f((unsigned short)(raw.y & 0xFFFF));
    a3 += wk * bf2f((unsigned short)(raw.y >> 16));
    a4 += wk * bf2f((unsigned short)(raw.z & 0xFFFF));
    a5 += wk * bf2f((unsigned short)(raw.z >> 16));
    a6 += wk * bf2f((unsigned short)(raw.w & 0xFFFF));
    a7 += wk * bf2f((unsigned short)(raw.w >> 16));
  }
  int b = bh >> 3, h = bh & 7;
  size_t o = ((size_t)((b << 12) + t)) * 512 + (h << 6) + (d8 << 3);
  uint4 out;
  out.x = (unsigned)f2bf(a0) | ((unsigned)f2bf(a1) << 16);
  out.y = (unsigned)f2bf(a2) | ((unsigned)f2bf(a3) << 16);
  out.z = (unsigned)f2bf(a4) | ((unsigned)f2bf(a5) << 16);
  out.w = (unsigned)f2bf(a6) | ((unsigned)f2bf(a7) << 16);
  *(uint4*)(Ahi + o) = out;
}

// ---------------- orchestration ----------------
extern "C" void kernel_launch(void* const* d_in, const int* in_sizes, int n_in,
                              void* d_out, int out_size, void* d_ws, size_t ws_size,
                              hipStream_t stream) {
  (void)in_sizes; (void)n_in; (void)out_size; (void)ws_size;
  const float* x_q = (const float*)d_in[0];
  const float* x_kv = (const float*)d_in[1];
  const float* Wq = (const float*)d_in[2];
  const float* bq = (const float*)d_in[3];
  const float* Wk = (const float*)d_in[4];
  const float* bk = (const float*)d_in[5];
  const float* Wv = (const float*)d_in[6];
  const float* bv = (const float*)d_in[7];
  const float* Wo = (const float*)d_in[8];
  const float* bo = (const float*)d_in[9];
  float* out = (float*)d_out;
  char* ws = (char*)d_ws;

  // workspace layout (~137.1 MiB)
  unsigned short* AqHi  = (unsigned short*)(ws + 0 * MiB);
  unsigned short* AqLo  = (unsigned short*)(ws + 16 * MiB);
  unsigned short* Vbuf16 = (unsigned short*)(ws + 0 * MiB);
  unsigned short* AkvHi = (unsigned short*)(ws + 36 * MiB);
  unsigned short* AkvLo = (unsigned short*)(ws + 52 * MiB);
  float* PpartRe = (float*)(ws + 36 * MiB);
  float* PpartIm = (float*)(ws + 52 * MiB);
  unsigned short* Aattn = (unsigned short*)(ws + 36 * MiB);
  unsigned short* WTb   = (unsigned short*)(ws + 68 * MiB);
  float* QT    = (float*)(ws + 72 * MiB);
  float* KT    = (float*)(ws + 104 * MiB);
  float* PsumRe = (float*)(ws + 72 * MiB);
  float* PsumIm = (float*)(ws + 73 * MiB);
  float* attnW = (float*)(ws + 137 * MiB);
  int*   delays = (int*)(ws + 137 * MiB + 4096);
  float2* TW   = (float2*)(ws + 137 * MiB + 8192);

  int n4 = (16384 * 512) / 4;
  prep_all<<<dim3(16652), dim3(256), 0, stream>>>(x_q, x_kv, AqHi, AqLo, AkvHi, AkvLo,
                                                  Wq, Wk, Wv, Wo, WTb, TW, n4);

  // Q and K projections fused, 256^2 8-phase (256 wgs x 512 thr = 1 block/CU).
  qk_gemm8<<<dim3(256), dim3(512), 0, stream>>>(AqHi, AqLo, AkvHi, AkvLo, WTb, bq, bk, QT, KT);
  gemm_bf16<<<dim3(512), dim3(256), 0, stream>>>(AkvHi, WTb + 4 * 262144, bv, nullptr, Vbuf16, 1);

  fft_corr<<<dim3(512), dim3(512), 0, stream>>>(QT, KT, TW, PpartRe, PpartIm);
  reduce_p<<<dim3(128), dim3(256), 0, stream>>>(PpartRe, PpartIm, PsumRe, PsumIm);
  ifft_topk<<<dim3(32), dim3(512), 0, stream>>>(PsumRe, PsumIm, TW, attnW, delays);
  gather_av<<<dim3(4096), dim3(256), 0, stream>>>(Vbuf16, attnW, delays, Aattn);

  // out = gathered @ Wo + bo (plain bf16 -> f32 out)
  gemm_bf16<<<dim3(512), dim3(256), 0, stream>>>(Aattn, WTb + 6 * 262144, bo, out, nullptr, 2);
}

// Round 11
// 170.028 us; speedup vs baseline: 6.0356x; 1.0872x over previous
//
#include <hip/hip_runtime.h>
#include <hip/hip_bf16.h>

// AutoCorrelation layer: QKV proj (Q+K on a 256^2 8-phase counted-vmcnt MFMA
// schedule, bf16x2: Ahi*(Bhi+Blo) -- activation-lo segment dropped, its corr
// error is incoherent ~1e-5; V/OUT on dbuf-prefetch 128^2) -> packed FFT
// cross-corr (radix-16 superstages; partials + reduce + ifft, NO atomics) ->
// single-pass bitonic top-8 + softmax -> delay-gather of V (bf16) -> out proj.
// B=4, L=4096, D=512, H=8, Dh=64.

#define MiB (1024ull * 1024ull)

typedef __attribute__((ext_vector_type(8))) short bf16x8;
typedef __attribute__((ext_vector_type(4))) float f32x4;
static_assert(sizeof(bf16x8) == 16, "bf16x8 must be 16B");

__device__ __forceinline__ unsigned short f2bf(float f) {
  unsigned u = __float_as_uint(f);
  unsigned r = (u + 0x7FFFu + ((u >> 16) & 1u)) >> 16;  // RN-even
  return (unsigned short)r;
}
__device__ __forceinline__ float bf2f(unsigned short h) {
  return __uint_as_float(((unsigned)h) << 16);
}
// base-4 digit reversal of a 12-bit index (involution)
__device__ __forceinline__ int rev4_12(int x) {
  unsigned r = __brev((unsigned)x) >> 20;
  return (int)(((r & 0xAAAu) >> 1) | ((r & 0x555u) << 1));
}
// LDS pad: +1 float per 32 to break power-of-2 bank patterns
#define IDX(e) ((e) + ((e) >> 5))
#define LDSN (4095 + (4095 >> 5) + 1)

// XCD-aware bijective swizzle (nwg % 8 == 0): XCD x owns contiguous logical chunk.
__device__ __forceinline__ int xcd_swz(int bid, int cpx) {
  return (bid & 7) * cpx + (bid >> 3);
}

#define BARRIER() do { asm volatile("" ::: "memory"); __builtin_amdgcn_s_barrier(); asm volatile("" ::: "memory"); } while (0)
#define WAITV6() asm volatile("s_waitcnt vmcnt(6)" ::: "memory")

// ---------------- fused prep: x bf16 round + W hi/lo transposes + twiddle table -------
__global__ void prep_all(const float* __restrict__ xq, const float* __restrict__ xkv,
                         unsigned short* __restrict__ qhi, unsigned short* __restrict__ khi,
                         const float* __restrict__ W0, const float* __restrict__ W1,
                         const float* __restrict__ W2, const float* __restrict__ W3,
                         unsigned short* __restrict__ WT, float2* __restrict__ TWt, int n4) {
  __shared__ float t[64][65];
  int blk = blockIdx.x;
  int tid = threadIdx.x;
  if (blk < 16384) {
    int i = blk * 256 + tid;
    const float* x = (i < n4) ? xq : xkv;
    unsigned short* hi = (i < n4) ? qhi : khi;
    int ii = (i < n4) ? i : i - n4;
    float4 v = ((const float4*)x)[ii];
    ushort4 h;
    h.x = f2bf(v.x); h.y = f2bf(v.y); h.z = f2bf(v.z); h.w = f2bf(v.w);
    ((ushort4*)hi)[ii] = h;
  } else if (blk < 16640) {
    int bx = blk - 16384;
    int w = bx >> 6, tile = bx & 63;
    int k0 = (tile >> 3) << 6, n0 = (tile & 7) << 6;
    const float* W = (w == 0) ? W0 : (w == 1) ? W1 : (w == 2) ? W2 : W3;
    unsigned short* hi = WT + (size_t)(2 * w) * 262144;
    unsigned short* lo = hi + 262144;
#pragma unroll
    for (int j = 0; j < 4; ++j) {
      int i = tid + (j << 8);
      int rr = i >> 4, c4 = (i & 15) << 2;
      float4 v = *(const float4*)&W[(size_t)(k0 + rr) * 512 + n0 + c4];
      t[rr][c4 + 0] = v.x; t[rr][c4 + 1] = v.y;
      t[rr][c4 + 2] = v.z; t[rr][c4 + 3] = v.w;
    }
    __syncthreads();
#pragma unroll
    for (int j = 0; j < 4; ++j) {
      int i = tid + (j << 8);
      int nn = i >> 4, k4 = (i & 15) << 2;
      ushort4 h, l;
      float f;
      f = t[k4 + 0][nn]; h.x = f2bf(f); l.x = f2bf(f - bf2f(h.x));
      f = t[k4 + 1][nn]; h.y = f2bf(f); l.y = f2bf(f - bf2f(h.y));
      f = t[k4 + 2][nn]; h.z = f2bf(f); l.z = f2bf(f - bf2f(h.z));
      f = t[k4 + 3][nn]; h.w = f2bf(f); l.w = f2bf(f - bf2f(h.w));
      size_t o = (size_t)(n0 + nn) * 512 + k0 + k4;
      *(ushort4*)(hi + o) = h;
      *(ushort4*)(lo + o) = l;
    }
  } else {
    int r = (blk - 16640) * 256 + tid;
    if (r < 3072) {
      double a = -2.0 * 3.14159265358979323846 * (double)r / 4096.0;
      TWt[r] = make_float2((float)cos(a), (float)sin(a));
    }
  }
}

// ---------------- fused Q+K GEMM: 256^2 tile, 8-wave, 4-phase/K-tile, counted vmcnt ----
// bf16x2: 16 K-tiles (v 0..7 = Ahi*Bhi, v 8..15 = Ahi*Blo), K'=1024.
__global__ __launch_bounds__(512, 2)
void qk_gemm8(const unsigned short* __restrict__ AqHi, const unsigned short* __restrict__ AkvHi,
              const unsigned short* __restrict__ WT,
              const float* __restrict__ bq, const float* __restrict__ bk,
              float* __restrict__ QT, float* __restrict__ KT) {
  __shared__ __align__(16) char lds[131072];
  int tid = threadIdx.x;
  int lane = tid & 63, wv = tid >> 6;
  int wm = wv >> 2, wn = wv & 3;

  int sw = xcd_swz(blockIdx.x, 32);  // 256 wgs
  int op = sw >> 7;                  // 0 = Q, 1 = K
  int r = sw & 127;
  int m0 = (r >> 1) << 8;            // 64 M-tiles
  int n0 = (r & 1) << 8;             // 2 N-tiles

  const unsigned short* Ahi = op ? AkvHi : AqHi;
  const unsigned short* Bhi = WT + (op ? 2 * 262144 : 0);
  const unsigned short* Blo = Bhi + 262144;
  const float* bias = op ? bk : bq;
  float* C = op ? KT : QT;

  int aoff0 = ((lane & 15) << 7) + ((((lane >> 4) + 0) ^ (lane & 7)) << 4);  // ks=0
  int aoff1 = ((lane & 15) << 7) + ((((lane >> 4) + 4) ^ (lane & 7)) << 4);  // ks=1
  int src_row = tid >> 3;
  int src_col = (tid & 7) ^ (src_row & 7);

  f32x4 acc[8][4];
  const f32x4 zz = {0.f, 0.f, 0.f, 0.f};
#pragma unroll
  for (int i = 0; i < 8; ++i)
#pragma unroll
    for (int j = 0; j < 4; ++j) acc[i][j] = zz;

  auto APTR = [&](int v) {
    return Ahi + (size_t)m0 * 512 + ((v & 7) << 6);
  };
  auto BPTR = [&](int v) {
    const unsigned short* p = (v >= 8) ? Blo : Bhi;
    return p + (size_t)n0 * 512 + ((v & 7) << 6);
  };
  auto STAGE = [&](const unsigned short* gbase, int R0, int ldsOff) {
    const unsigned short* ga = gbase + (size_t)(R0 + src_row) * 512 + (src_col << 3);
    char* la = lds + ldsOff + (R0 << 7) + (wv << 10);
    __builtin_amdgcn_global_load_lds((const __attribute__((address_space(1))) void*)ga,
                                     (__attribute__((address_space(3))) void*)la, 16, 0, 0);
  };
#define RDA(o, mi, ks) (*(const bf16x8*)(lds + (o) + (wm << 14) + ((mi) << 11) + aoff##ks))
#define RDB(o, ni, ks) (*(const bf16x8*)(lds + (o) + 32768 + (wn << 13) + ((ni) << 11) + aoff##ks))
#define MFMA_PAIR(mi0, A0, A1)                                                              \
  __builtin_amdgcn_s_setprio(1);                                                            \
  _Pragma("unroll") for (int ks = 0; ks < 2; ++ks) {                                        \
    _Pragma("unroll") for (int ni = 0; ni < 4; ++ni) {                                      \
      acc[mi0][ni] = __builtin_amdgcn_mfma_f32_16x16x32_bf16(A0[ks], b[ni][ks], acc[mi0][ni], 0, 0, 0);          \
      acc[mi0 + 1][ni] = __builtin_amdgcn_mfma_f32_16x16x32_bf16(A1[ks], b[ni][ks], acc[mi0 + 1][ni], 0, 0, 0);  \
    }                                                                                       \
  }                                                                                         \
  __builtin_amdgcn_s_setprio(0)

  STAGE(BPTR(0), 0, 32768);   STAGE(BPTR(0), 64, 32768);
  STAGE(BPTR(0), 128, 32768); STAGE(BPTR(0), 192, 32768);
  STAGE(APTR(0), 0, 0);       STAGE(APTR(0), 64, 0);
  STAGE(APTR(0), 128, 0);     STAGE(APTR(0), 192, 0);
  STAGE(BPTR(1), 0, 65536 + 32768);   STAGE(BPTR(1), 64, 65536 + 32768);
  STAGE(BPTR(1), 128, 65536 + 32768); STAGE(BPTR(1), 192, 65536 + 32768);
  STAGE(APTR(1), 0, 65536);           STAGE(APTR(1), 128, 65536);
  WAITV6();
  BARRIER();

  for (int t = 0; t < 16; ++t) {
    int o = (t & 1) << 16;
    int on = o ^ 65536;
    int t1 = (t + 1 < 16) ? t + 1 : 15;
    int t2 = (t + 2 < 16) ? t + 2 : 15;
    const unsigned short* a1p = APTR(t1);
    const unsigned short* a2p = APTR(t2);
    const unsigned short* b2p = BPTR(t2);

    bf16x8 b[4][2], aA[2][2];
#pragma unroll
    for (int ni = 0; ni < 4; ++ni) { b[ni][0] = RDB(o, ni, 0); b[ni][1] = RDB(o, ni, 1); }
    aA[0][0] = RDA(o, 0, 0); aA[0][1] = RDA(o, 0, 1);
    aA[1][0] = RDA(o, 1, 0); aA[1][1] = RDA(o, 1, 1);
    STAGE(a1p, 64, on); STAGE(a1p, 192, on);
    BARRIER();
    MFMA_PAIR(0, aA[0], aA[1]);
    BARRIER();

    aA[0][0] = RDA(o, 2, 0); aA[0][1] = RDA(o, 2, 1);
    aA[1][0] = RDA(o, 3, 0); aA[1][1] = RDA(o, 3, 1);
    STAGE(b2p, 0, o + 32768); STAGE(b2p, 64, o + 32768);
    BARRIER();
    MFMA_PAIR(2, aA[0], aA[1]);
    BARRIER();

    aA[0][0] = RDA(o, 4, 0); aA[0][1] = RDA(o, 4, 1);
    aA[1][0] = RDA(o, 5, 0); aA[1][1] = RDA(o, 5, 1);
    STAGE(b2p, 128, o + 32768); STAGE(b2p, 192, o + 32768);
    BARRIER();
    MFMA_PAIR(4, aA[0], aA[1]);
    BARRIER();

    aA[0][0] = RDA(o, 6, 0); aA[0][1] = RDA(o, 6, 1);
    aA[1][0] = RDA(o, 7, 0); aA[1][1] = RDA(o, 7, 1);
    STAGE(a2p, 0, o); STAGE(a2p, 128, o);
    BARRIER();
    MFMA_PAIR(6, aA[0], aA[1]);
    WAITV6();
    BARRIER();
  }
#undef RDA
#undef RDB
#undef MFMA_PAIR

#pragma unroll
  for (int mi = 0; mi < 8; ++mi) {
    int mrow0 = m0 + (wm << 7) + (mi << 4) + ((lane >> 4) << 2);
    int bq_ = mrow0 >> 12;
    int t0 = mrow0 & 4095;
#pragma unroll
    for (int ni = 0; ni < 4; ++ni) {
      int col = n0 + (wn << 6) + (ni << 4) + (lane & 15);
      float bv = bias[col];
      f32x4 v = acc[mi][ni];
      v.x += bv; v.y += bv; v.z += bv; v.w += bv;
      *(f32x4*)&C[((size_t)(bq_ * 512 + col)) * 4096 + t0] = v;
    }
  }
}

// ---------------- generic GEMM: V (mode 1, bf16 out) and OUT (mode 2, f32 out) ---------
// Double-buffered LDS + stage-next-before-compute (T3-min 2-phase).
__global__ __launch_bounds__(256, 2)
void gemm_bf16(const unsigned short* __restrict__ Ahi,
               const unsigned short* __restrict__ Bhi,
               const float* __restrict__ bias, float* __restrict__ Cf,
               unsigned short* __restrict__ Ch, int mode) {
  __shared__ short As[2][128 * 64];
  __shared__ short Bs[2][128 * 64];
  int bx = xcd_swz(blockIdx.x, 64);  // 512 wgs
  int bm = bx >> 2, bn = bx & 3;
  int m0 = bm << 7, n0 = bn << 7;
  int tid = threadIdx.x;
  int lane = tid & 63, wv = tid >> 6;
  int wm = wv >> 1, wn = wv & 1;

  const f32x4 zz = {0.f, 0.f, 0.f, 0.f};
  f32x4 acc[4][4];
#pragma unroll
  for (int i = 0; i < 4; ++i)
#pragma unroll
    for (int j = 0; j < 4; ++j) acc[i][j] = zz;

  int srow = tid >> 3;
  int sk = (tid & 7) << 3;
  auto STAGE = [&](int ks, int buf) {
    int kb = ks << 6;
#pragma unroll
    for (int i = 0; i < 4; ++i) {
      int r = (i << 5) + srow;
      const unsigned short* ga = Ahi + (size_t)(m0 + r) * 512 + kb + sk;
      const unsigned short* gb = Bhi + (size_t)(n0 + r) * 512 + kb + sk;
      char* la = (char*)As[buf] + (i << 12) + (wv << 10);
      char* lb = (char*)Bs[buf] + (i << 12) + (wv << 10);
      __builtin_amdgcn_global_load_lds((const __attribute__((address_space(1))) void*)ga,
                                       (__attribute__((address_space(3))) void*)la, 16, 0, 0);
      __builtin_amdgcn_global_load_lds((const __attribute__((address_space(1))) void*)gb,
                                       (__attribute__((address_space(3))) void*)lb, 16, 0, 0);
    }
  };

  STAGE(0, 0);
  __syncthreads();
  for (int ks = 0; ks < 8; ++ks) {
    int buf = ks & 1;
    if (ks < 7) STAGE(ks + 1, buf ^ 1);
#pragma unroll
    for (int kk = 0; kk < 2; ++kk) {
      bf16x8 af[4], bfr[4];
      int krd = (kk << 5) + ((lane >> 4) << 3);
#pragma unroll
      for (int mi = 0; mi < 4; ++mi)
        af[mi] = *(const bf16x8*)&As[buf][((wm << 6) + (mi << 4) + (lane & 15)) * 64 + krd];
#pragma unroll
      for (int ni = 0; ni < 4; ++ni)
        bfr[ni] = *(const bf16x8*)&Bs[buf][((wn << 6) + (ni << 4) + (lane & 15)) * 64 + krd];
#pragma unroll
      for (int mi = 0; mi < 4; ++mi)
#pragma unroll
        for (int ni = 0; ni < 4; ++ni)
          acc[mi][ni] = __builtin_amdgcn_mfma_f32_16x16x32_bf16(af[mi], bfr[ni], acc[mi][ni], 0, 0, 0);
    }
    __syncthreads();  // drains ks+1 loads; protects buf reuse at ks+2
  }

#pragma unroll
  for (int mi = 0; mi < 4; ++mi) {
    int mrow0 = m0 + (wm << 6) + (mi << 4) + ((lane >> 4) << 2);
    int bq_ = mrow0 >> 12;
    int t0 = mrow0 & 4095;
#pragma unroll
    for (int ni = 0; ni < 4; ++ni) {
      int col = n0 + (wn << 6) + (ni << 4) + (lane & 15);
      float bv = bias[col];
      f32x4 v = acc[mi][ni];
      v.x += bv; v.y += bv; v.z += bv; v.w += bv;
      if (mode == 1) {
        // V layout (bf16): Ch[((b*8+h)*4096+t)*64 + d]
        size_t base = (size_t)(bq_ * 8 + (col >> 6)) * 4096;
        int d = col & 63;
        Ch[(base + t0 + 0) * 64 + d] = f2bf(v.x);
        Ch[(base + t0 + 1) * 64 + d] = f2bf(v.y);
        Ch[(base + t0 + 2) * 64 + d] = f2bf(v.z);
        Ch[(base + t0 + 3) * 64 + d] = f2bf(v.w);
      } else {
        Cf[(size_t)(mrow0 + 0) * 512 + col] = v.x;
        Cf[(size_t)(mrow0 + 1) * 512 + col] = v.y;
        Cf[(size_t)(mrow0 + 2) * 512 + col] = v.z;
        Cf[(size_t)(mrow0 + 3) * 512 + col] = v.w;
      }
    }
  }
}

// ---------------- FFT: radix-16 superstages (stage pairs fused in registers) ----------
__device__ __forceinline__ void r4(float& x0r, float& x0i, float& x1r, float& x1i,
                                   float& x2r, float& x2i, float& x3r, float& x3i,
                                   float2 w1, float2 w2, float2 w3) {
  float Ar = x0r + x2r, Ai = x0i + x2i;
  float Br = x0r - x2r, Bi = x0i - x2i;
  float Cr = x1r + x3r, Ci = x1i + x3i;
  float Dr = x1i - x3i, Di = x3r - x1r;  // -i*(x1-x3)
  x0r = Ar + Cr; x0i = Ai + Ci;
  float tr = Br + Dr, ti = Bi + Di;
  x1r = tr * w1.x - ti * w1.y; x1i = tr * w1.y + ti * w1.x;
  tr = Ar - Cr; ti = Ai - Ci;
  x2r = tr * w2.x - ti * w2.y; x2i = tr * w2.y + ti * w2.x;
  tr = Br - Dr; ti = Bi - Di;
  x3r = tr * w3.x - ti * w3.y; x3i = tr * w3.y + ti * w3.x;
}

__device__ __forceinline__ void fft16_superstages(float* re, float* im,
                                                  const float2* __restrict__ TW,
                                                  int u, bool active) {
#pragma unroll
  for (int ss = 0; ss < 3; ++ss) {
    const int lm = 10 - 4 * ss;      // 10, 6, 2
    const int m = 1 << lm;
    const int m4 = m >> 2;
    const int stw = 1 << (4 * ss);   // 1, 16, 256
    const int stw4 = stw << 2;
    if (active) {
      int jj = u & (m4 - 1);
      int g = u >> (lm - 2);
      int base = (g << (lm + 2)) + jj;
      float xr[4][4], xi[4][4];
#pragma unroll
      for (int a = 0; a < 4; ++a)
#pragma unroll
        for (int b = 0; b < 4; ++b) {
          int p = IDX(base + a * m + b * m4);
          xr[a][b] = re[p]; xi[a][b] = im[p];
        }
#pragma unroll
      for (int b = 0; b < 4; ++b) {
        int j1 = (b * m4 + jj) * stw;
        float2 w1 = TW[j1], w2 = TW[2 * j1], w3 = TW[3 * j1];
        r4(xr[0][b], xi[0][b], xr[1][b], xi[1][b], xr[2][b], xi[2][b], xr[3][b], xi[3][b], w1, w2, w3);
      }
      {
        int j2 = jj * stw4;
        float2 v1 = TW[j2], v2 = TW[2 * j2], v3 = TW[3 * j2];
#pragma unroll
        for (int a = 0; a < 4; ++a)
          r4(xr[a][0], xi[a][0], xr[a][1], xi[a][1], xr[a][2], xi[a][2], xr[a][3], xi[a][3], v1, v2, v3);
      }
#pragma unroll
      for (int a = 0; a < 4; ++a)
#pragma unroll
        for (int b = 0; b < 4; ++b) {
          int p = IDX(base + a * m + b * m4);
          re[p] = xr[a][b]; im[p] = xi[a][b];
        }
    }
    __syncthreads();
  }
}

// Packed FFT of z = q + i*k per (b,h,d); one wg (512 thr) handles 4 d's as
// 2 rounds of 2 CONCURRENT FFTs (256 units each, wave-uniform split).
// 512 wgs = 32 bh x 16 parts; NO atomics.
__global__ __launch_bounds__(512, 2)
void fft_corr(const float* __restrict__ QT, const float* __restrict__ KT,
              const float2* __restrict__ TW, float* __restrict__ PpartRe,
              float* __restrict__ PpartIm) {
  __shared__ float re[2][LDSN];
  __shared__ float im[2][LDSN];
  int wg = blockIdx.x;
  int bh = wg >> 4;
  int d0 = (wg & 15) << 2;
  int tid = threadIdx.x;
  const float* qb = QT + (size_t)bh * 64 * 4096;
  const float* kb = KT + (size_t)bh * 64 * 4096;
  float accR[8], accI[8];
#pragma unroll
  for (int j = 0; j < 8; ++j) { accR[j] = 0.f; accI[j] = 0.f; }
  for (int rr = 0; rr < 2; ++rr) {
    if (rr) __syncthreads();  // prior extraction reads done
#pragma unroll
    for (int ff = 0; ff < 2; ++ff) {
      const float4* q4 = (const float4*)(qb + (size_t)(d0 + 2 * rr + ff) * 4096);
      const float4* k4 = (const float4*)(kb + (size_t)(d0 + 2 * rr + ff) * 4096);
#pragma unroll
      for (int i = 0; i < 2; ++i) {
        int e4 = tid + (i << 9);
        float4 qv = q4[e4], kv = k4[e4];
        int e = e4 << 2;
        re[ff][IDX(e + 0)] = qv.x; im[ff][IDX(e + 0)] = kv.x;
        re[ff][IDX(e + 1)] = qv.y; im[ff][IDX(e + 1)] = kv.y;
        re[ff][IDX(e + 2)] = qv.z; im[ff][IDX(e + 2)] = kv.z;
        re[ff][IDX(e + 3)] = qv.w; im[ff][IDX(e + 3)] = kv.w;
      }
    }
    __syncthreads();
    // wave-uniform FFT split: waves 0-3 -> fft 0, waves 4-7 -> fft 1
    fft16_superstages(re[tid >> 8], im[tid >> 8], TW, tid & 255, true);
#pragma unroll
    for (int ff = 0; ff < 2; ++ff) {
#pragma unroll
      for (int j = 0; j < 8; ++j) {
        int p = tid + (j << 9);
        int f = rev4_12(p);
        int fn = (4096 - f) & 4095;
        int pn = rev4_12(fn);
        float zr = re[ff][IDX(p)], zi = im[ff][IDX(p)];
        float wr = re[ff][IDX(pn)], wi = im[ff][IDX(pn)];
        float qre = 0.5f * (zr + wr), qim = 0.5f * (zi - wi);
        float kre = 0.5f * (zi + wi), kim = 0.5f * (wr - zr);
        accR[j] += qre * kre + qim * kim;   // Re(Qf*conj(Kf))
        accI[j] += qim * kre - qre * kim;   // Im(Qf*conj(Kf))
      }
    }
  }
  float* pR = PpartRe + (size_t)wg * 4096;
  float* pI = PpartIm + (size_t)wg * 4096;
#pragma unroll
  for (int j = 0; j < 8; ++j) {
    int p = tid + (j << 9);
    pR[p] = accR[j];
    pI[p] = accI[j];
  }
}

// Reduce 16 partials per (b,h) -> Psum, float4. Grid 128 = 32 bh x 4 chunks of 1024 p.
__global__ void reduce_p(const float* __restrict__ PpartRe, const float* __restrict__ PpartIm,
                         float* __restrict__ PsumRe, float* __restrict__ PsumIm) {
  int wg = blockIdx.x;
  int bh = wg >> 2;
  int p4 = ((wg & 3) << 8) + threadIdx.x;  // float4 index 0..1023
  const float4* bR = (const float4*)(PpartRe + (size_t)bh * 16 * 4096);
  const float4* bI = (const float4*)(PpartIm + (size_t)bh * 16 * 4096);
  float4 sr = make_float4(0.f, 0.f, 0.f, 0.f);
  float4 si = make_float4(0.f, 0.f, 0.f, 0.f);
#pragma unroll
  for (int part = 0; part < 16; ++part) {
    float4 a = bR[part * 1024 + p4];
    float4 b = bI[part * 1024 + p4];
    sr.x += a.x; sr.y += a.y; sr.z += a.z; sr.w += a.w;
    si.x += b.x; si.y += b.y; si.z += b.z; si.w += b.w;
  }
  ((float4*)(PsumRe + (size_t)bh * 4096))[p4] = sr;
  ((float4*)(PsumIm + (size_t)bh * 4096))[p4] = si;
}

// Inverse FFT via conj + forward DIF (radix-16); corr(tau=rev4(p)) = re[p]/(4096*64).
// Single-pass top-8: pack (value,tau) -> ordered u64 key; per-thread sort-8;
// 6-level shfl_xor butterfly with Batcher half-cleaner; final 8-list serial merge.
__global__ __launch_bounds__(512, 1)
void ifft_topk(const float* __restrict__ PsumRe, const float* __restrict__ PsumIm,
               const float2* __restrict__ TW, float* __restrict__ attnW, int* __restrict__ delays) {
  __shared__ float re[LDSN];
  __shared__ float im[LDSN];
  __shared__ unsigned long long sh[8][8];
  int bh = blockIdx.x, tid = threadIdx.x;
  int lane = tid & 63, wv = tid >> 6;
  const float4* pr4 = (const float4*)(PsumRe + (size_t)bh * 4096);
  const float4* pi4 = (const float4*)(PsumIm + (size_t)bh * 4096);
#pragma unroll
  for (int i = 0; i < 2; ++i) {
    int e4 = tid + (i << 9);
    float4 a = pr4[e4], b = pi4[e4];
    int fb = rev4_12(e4 << 2);  // rev4 of (e4*4 + j) = fb | (j<<10)
    re[IDX(fb + 0 * 1024)] = a.x; im[IDX(fb + 0 * 1024)] = -b.x;
    re[IDX(fb + 1 * 1024)] = a.y; im[IDX(fb + 1 * 1024)] = -b.y;
    re[IDX(fb + 2 * 1024)] = a.z; im[IDX(fb + 2 * 1024)] = -b.z;
    re[IDX(fb + 3 * 1024)] = a.w; im[IDX(fb + 3 * 1024)] = -b.w;
  }
  __syncthreads();
  fft16_superstages(re, im, TW, tid & 255, tid < 256);

  // build per-thread desc-sorted 8 keys (value desc, tau asc on ties)
  unsigned long long k[8];
#pragma unroll
  for (int i = 0; i < 8; ++i) {
    int p = tid + (i << 9);
    float v = re[IDX(p)];
    int tau = rev4_12(p);
    unsigned u = __float_as_uint(v);
    unsigned s = u ^ (unsigned)(((int)u >> 31) | 0x80000000);  // order-preserving map
    k[i] = ((unsigned long long)s << 12) | (unsigned)(4095 - tau);
  }
#define CSWAP(a, b) { if (k[a] < k[b]) { unsigned long long t_ = k[a]; k[a] = k[b]; k[b] = t_; } }
  // insertion network (28 comparators), descending
#pragma unroll
  for (int i = 1; i < 8; ++i)
#pragma unroll
    for (int j = 8 - 1; j >= 1; --j)
      if (j <= i) CSWAP(j - 1, j);
  // butterfly merge across 64 lanes: keep top-8 of pairwise unions
#pragma unroll
  for (int off = 1; off < 64; off <<= 1) {
    unsigned long long b[8];
#pragma unroll
    for (int i = 0; i < 8; ++i)
      b[i] = (unsigned long long)__shfl_xor((long long)k[i], off);
#pragma unroll
    for (int i = 0; i < 8; ++i) {
      unsigned long long m = b[7 - i];        // half-cleaner: max(A[i], B[7-i])
      k[i] = (k[i] > m) ? k[i] : m;
    }
    // bitonic clean (descending), distances 4, 2, 1
#pragma unroll
    for (int d = 4; d > 0; d >>= 1)
#pragma unroll
      for (int i = 0; i < 8; ++i)
        if ((i & d) == 0 && (i ^ d) < 8) CSWAP(i, i + d);
  }
#undef CSWAP
  if (lane == 0) {
#pragma unroll
    for (int i = 0; i < 8; ++i) sh[wv][i] = k[i];
  }
  __syncthreads();
  if (tid == 0) {
    const float SC = 1.0f / 262144.0f;  // 1/(L*Dh)
    int idx[8] = {0, 0, 0, 0, 0, 0, 0, 0};
    float topv[8]; int topi[8];
#pragma unroll
    for (int pass = 0; pass < 8; ++pass) {
      int bw = 0;
      unsigned long long bk = sh[0][idx[0]];
#pragma unroll
      for (int w = 1; w < 8; ++w) {
        unsigned long long c = sh[w][idx[w]];
        if (c > bk) { bk = c; bw = w; }
      }
      idx[bw]++;
      unsigned s = (unsigned)(bk >> 12);
      unsigned u = (s & 0x80000000u) ? (s ^ 0x80000000u) : ~s;
      topv[pass] = __uint_as_float(u) * SC;
      topi[pass] = 4095 - (int)(bk & 4095u);
    }
    float mx = topv[0];  // pass 0 = global max
    float ex[8], ssum = 0.f;
    for (int q = 0; q < 8; ++q) { ex[q] = expf(topv[q] - mx); ssum += ex[q]; }
    float inv = 1.0f / ssum;
    for (int q = 0; q < 8; ++q) {
      attnW[bh * 8 + q] = ex[q] * inv;
      delays[bh * 8 + q] = topi[q];
    }
  }
}

// out[b,h,t,:] = sum_k attn_k * V[b,h,(t-d_k)%L,:] (V bf16); write bf16 A for OUT gemm.
// Grid 4096 = 32 bh x 128 t-chunks of 32; thread handles 8 d's (16B loads/stores).
__global__ void gather_av(const unsigned short* __restrict__ Vh, const float* __restrict__ attnW,
                          const int* __restrict__ delays, unsigned short* __restrict__ Ahi) {
  int blk = blockIdx.x;
  int bh = blk >> 7, tb = blk & 127;
  int tid = threadIdx.x;
  int tt = tid >> 3, d8 = tid & 7;
  int t = (tb << 5) + tt;
  const unsigned short* Vb = Vh + (size_t)bh * 4096 * 64 + (d8 << 3);
  float w[8]; int dl[8];
#pragma unroll
  for (int kk = 0; kk < 8; ++kk) { w[kk] = attnW[bh * 8 + kk]; dl[kk] = delays[bh * 8 + kk]; }
  float a0 = 0.f, a1 = 0.f, a2 = 0.f, a3 = 0.f, a4 = 0.f, a5 = 0.f, a6 = 0.f, a7 = 0.f;
#pragma unroll
  for (int kk = 0; kk < 8; ++kk) {
    int row = (t - dl[kk]) & 4095;
    uint4 raw = *(const uint4*)(Vb + row * 64);
    float wk = w[kk];
    a0 += wk * bf2f((unsigned short)(raw.x & 0xFFFF));
    a1 += wk * bf2f((unsigned short)(raw.x >> 16));
    a2 += wk * bf2f((unsigned short)(raw.y & 0xFFFF));
    a3 += wk * bf2f((unsigned short)(raw.y >> 16));
    a4 += wk * bf2f((unsigned short)(raw.z & 0xFFFF));
    a5 += wk * bf2f((unsigned short)(raw.z >> 16));
    a6 += wk * bf2f((unsigned short)(raw.w & 0xFFFF));
    a7 += wk * bf2f((unsigned short)(raw.w >> 16));
  }
  int b = bh >> 3, h = bh & 7;
  size_t o = ((size_t)((b << 12) + t)) * 512 + (h << 6) + (d8 << 3);
  uint4 out;
  out.x = (unsigned)f2bf(a0) | ((unsigned)f2bf(a1) << 16);
  out.y = (unsigned)f2bf(a2) | ((unsigned)f2bf(a3) << 16);
  out.z = (unsigned)f2bf(a4) | ((unsigned)f2bf(a5) << 16);
  out.w = (unsigned)f2bf(a6) | ((unsigned)f2bf(a7) << 16);
  *(uint4*)(Ahi + o) = out;
}

// ---------------- orchestration ----------------
extern "C" void kernel_launch(void* const* d_in, const int* in_sizes, int n_in,
                              void* d_out, int out_size, void* d_ws, size_t ws_size,
                              hipStream_t stream) {
  (void)in_sizes; (void)n_in; (void)out_size; (void)ws_size;
  const float* x_q = (const float*)d_in[0];
  const float* x_kv = (const float*)d_in[1];
  const float* Wq = (const float*)d_in[2];
  const float* bq = (const float*)d_in[3];
  const float* Wk = (const float*)d_in[4];
  const float* bk = (const float*)d_in[5];
  const float* Wv = (const float*)d_in[6];
  const float* bv = (const float*)d_in[7];
  const float* Wo = (const float*)d_in[8];
  const float* bo = (const float*)d_in[9];
  float* out = (float*)d_out;
  char* ws = (char*)d_ws;

  // workspace layout (~137.1 MiB; AqLo/AkvLo regions now unused)
  unsigned short* AqHi  = (unsigned short*)(ws + 0 * MiB);
  unsigned short* Vbuf16 = (unsigned short*)(ws + 0 * MiB);  // after qk_gemm8
  unsigned short* AkvHi = (unsigned short*)(ws + 36 * MiB);
  float* PpartRe = (float*)(ws + 36 * MiB);                  // after v_gemm
  float* PpartIm = (float*)(ws + 52 * MiB);
  unsigned short* Aattn = (unsigned short*)(ws + 36 * MiB);  // after reduce_p
  unsigned short* WTb   = (unsigned short*)(ws + 68 * MiB);
  float* QT    = (float*)(ws + 72 * MiB);
  float* KT    = (float*)(ws + 104 * MiB);
  float* PsumRe = (float*)(ws + 72 * MiB);
  float* PsumIm = (float*)(ws + 73 * MiB);
  float* attnW = (float*)(ws + 137 * MiB);
  int*   delays = (int*)(ws + 137 * MiB + 4096);
  float2* TW   = (float2*)(ws + 137 * MiB + 8192);

  int n4 = (16384 * 512) / 4;
  prep_all<<<dim3(16652), dim3(256), 0, stream>>>(x_q, x_kv, AqHi, AkvHi,
                                                  Wq, Wk, Wv, Wo, WTb, TW, n4);

  // Q and K projections fused, 256^2 8-phase bf16x2 (256 wgs x 512 thr).
  qk_gemm8<<<dim3(256), dim3(512), 0, stream>>>(AqHi, AkvHi, WTb, bq, bk, QT, KT);
  gemm_bf16<<<dim3(512), dim3(256), 0, stream>>>(AkvHi, WTb + 4 * 262144, bv, nullptr, Vbuf16, 1);

  fft_corr<<<dim3(512), dim3(512), 0, stream>>>(QT, KT, TW, PpartRe, PpartIm);
  reduce_p<<<dim3(128), dim3(256), 0, stream>>>(PpartRe, PpartIm, PsumRe, PsumIm);
  ifft_topk<<<dim3(32), dim3(512), 0, stream>>>(PsumRe, PsumIm, TW, attnW, delays);
  gather_av<<<dim3(4096), dim3(256), 0, stream>>>(Vbuf16, attnW, delays, Aattn);

  // out = gathered @ Wo + bo (plain bf16 -> f32 out)
  gemm_bf16<<<dim3(512), dim3(256), 0, stream>>>(Aattn, WTb + 6 * 262144, bo, out, nullptr, 2);
}

// Round 12
// 165.312 us; speedup vs baseline: 6.2078x; 1.0285x over previous
//
#include <hip/hip_runtime.h>
#include <hip/hip_bf16.h>

// AutoCorrelation layer: QKV proj (Q+K on a 256^2 8-phase counted-vmcnt MFMA
// schedule, bf16x2: Ahi*(Bhi+Blo); QT/KT stored bf16 -- incoherent rounding,
// corr noise ~8e-6; V/OUT on dbuf-prefetch 128^2) -> packed FFT cross-corr
// (radix-16 superstages; partials + reduce + ifft, NO atomics) -> single-pass
// bitonic top-8 + softmax -> delay-gather of V (bf16) -> output proj.
// B=4, L=4096, D=512, H=8, Dh=64.

#define MiB (1024ull * 1024ull)

typedef __attribute__((ext_vector_type(8))) short bf16x8;
typedef __attribute__((ext_vector_type(4))) float f32x4;
static_assert(sizeof(bf16x8) == 16, "bf16x8 must be 16B");

__device__ __forceinline__ unsigned short f2bf(float f) {
  unsigned u = __float_as_uint(f);
  unsigned r = (u + 0x7FFFu + ((u >> 16) & 1u)) >> 16;  // RN-even
  return (unsigned short)r;
}
__device__ __forceinline__ float bf2f(unsigned short h) {
  return __uint_as_float(((unsigned)h) << 16);
}
// base-4 digit reversal of a 12-bit index (involution)
__device__ __forceinline__ int rev4_12(int x) {
  unsigned r = __brev((unsigned)x) >> 20;
  return (int)(((r & 0xAAAu) >> 1) | ((r & 0x555u) << 1));
}
// LDS pad: +1 float per 32 to break power-of-2 bank patterns
#define IDX(e) ((e) + ((e) >> 5))
#define LDSN (4095 + (4095 >> 5) + 1)

// XCD-aware bijective swizzle (nwg % 8 == 0): XCD x owns contiguous logical chunk.
__device__ __forceinline__ int xcd_swz(int bid, int cpx) {
  return (bid & 7) * cpx + (bid >> 3);
}

#define BARRIER() do { asm volatile("" ::: "memory"); __builtin_amdgcn_s_barrier(); asm volatile("" ::: "memory"); } while (0)
#define WAITV6() asm volatile("s_waitcnt vmcnt(6)" ::: "memory")

// ---------------- fused prep: x bf16 round + W hi/lo transposes + twiddle table -------
__global__ void prep_all(const float* __restrict__ xq, const float* __restrict__ xkv,
                         unsigned short* __restrict__ qhi, unsigned short* __restrict__ khi,
                         const float* __restrict__ W0, const float* __restrict__ W1,
                         const float* __restrict__ W2, const float* __restrict__ W3,
                         unsigned short* __restrict__ WT, float2* __restrict__ TWt, int n4) {
  __shared__ float t[64][65];
  int blk = blockIdx.x;
  int tid = threadIdx.x;
  if (blk < 16384) {
    int i = blk * 256 + tid;
    const float* x = (i < n4) ? xq : xkv;
    unsigned short* hi = (i < n4) ? qhi : khi;
    int ii = (i < n4) ? i : i - n4;
    float4 v = ((const float4*)x)[ii];
    ushort4 h;
    h.x = f2bf(v.x); h.y = f2bf(v.y); h.z = f2bf(v.z); h.w = f2bf(v.w);
    ((ushort4*)hi)[ii] = h;
  } else if (blk < 16640) {
    int bx = blk - 16384;
    int w = bx >> 6, tile = bx & 63;
    int k0 = (tile >> 3) << 6, n0 = (tile & 7) << 6;
    const float* W = (w == 0) ? W0 : (w == 1) ? W1 : (w == 2) ? W2 : W3;
    unsigned short* hi = WT + (size_t)(2 * w) * 262144;
    unsigned short* lo = hi + 262144;
#pragma unroll
    for (int j = 0; j < 4; ++j) {
      int i = tid + (j << 8);
      int rr = i >> 4, c4 = (i & 15) << 2;
      float4 v = *(const float4*)&W[(size_t)(k0 + rr) * 512 + n0 + c4];
      t[rr][c4 + 0] = v.x; t[rr][c4 + 1] = v.y;
      t[rr][c4 + 2] = v.z; t[rr][c4 + 3] = v.w;
    }
    __syncthreads();
#pragma unroll
    for (int j = 0; j < 4; ++j) {
      int i = tid + (j << 8);
      int nn = i >> 4, k4 = (i & 15) << 2;
      ushort4 h, l;
      float f;
      f = t[k4 + 0][nn]; h.x = f2bf(f); l.x = f2bf(f - bf2f(h.x));
      f = t[k4 + 1][nn]; h.y = f2bf(f); l.y = f2bf(f - bf2f(h.y));
      f = t[k4 + 2][nn]; h.z = f2bf(f); l.z = f2bf(f - bf2f(h.z));
      f = t[k4 + 3][nn]; h.w = f2bf(f); l.w = f2bf(f - bf2f(h.w));
      size_t o = (size_t)(n0 + nn) * 512 + k0 + k4;
      *(ushort4*)(hi + o) = h;
      *(ushort4*)(lo + o) = l;
    }
  } else {
    int r = (blk - 16640) * 256 + tid;
    if (r < 3072) {
      double a = -2.0 * 3.14159265358979323846 * (double)r / 4096.0;
      TWt[r] = make_float2((float)cos(a), (float)sin(a));
    }
  }
}

// ---------------- fused Q+K GEMM: 256^2 tile, 8-wave, 4-phase/K-tile, counted vmcnt ----
// bf16x2: 16 K-tiles (v 0..7 = Ahi*Bhi, v 8..15 = Ahi*Blo), K'=1024. Output bf16.
__global__ __launch_bounds__(512, 2)
void qk_gemm8(const unsigned short* __restrict__ AqHi, const unsigned short* __restrict__ AkvHi,
              const unsigned short* __restrict__ WT,
              const float* __restrict__ bq, const float* __restrict__ bk,
              unsigned short* __restrict__ QT, unsigned short* __restrict__ KT) {
  __shared__ __align__(16) char lds[131072];
  int tid = threadIdx.x;
  int lane = tid & 63, wv = tid >> 6;
  int wm = wv >> 2, wn = wv & 3;

  int sw = xcd_swz(blockIdx.x, 32);  // 256 wgs
  int op = sw >> 7;                  // 0 = Q, 1 = K
  int r = sw & 127;
  int m0 = (r >> 1) << 8;            // 64 M-tiles
  int n0 = (r & 1) << 8;             // 2 N-tiles

  const unsigned short* Ahi = op ? AkvHi : AqHi;
  const unsigned short* Bhi = WT + (op ? 2 * 262144 : 0);
  const unsigned short* Blo = Bhi + 262144;
  const float* bias = op ? bk : bq;
  unsigned short* C = op ? KT : QT;

  int aoff0 = ((lane & 15) << 7) + ((((lane >> 4) + 0) ^ (lane & 7)) << 4);  // ks=0
  int aoff1 = ((lane & 15) << 7) + ((((lane >> 4) + 4) ^ (lane & 7)) << 4);  // ks=1
  int src_row = tid >> 3;
  int src_col = (tid & 7) ^ (src_row & 7);

  f32x4 acc[8][4];
  const f32x4 zz = {0.f, 0.f, 0.f, 0.f};
#pragma unroll
  for (int i = 0; i < 8; ++i)
#pragma unroll
    for (int j = 0; j < 4; ++j) acc[i][j] = zz;

  auto APTR = [&](int v) {
    return Ahi + (size_t)m0 * 512 + ((v & 7) << 6);
  };
  auto BPTR = [&](int v) {
    const unsigned short* p = (v >= 8) ? Blo : Bhi;
    return p + (size_t)n0 * 512 + ((v & 7) << 6);
  };
  auto STAGE = [&](const unsigned short* gbase, int R0, int ldsOff) {
    const unsigned short* ga = gbase + (size_t)(R0 + src_row) * 512 + (src_col << 3);
    char* la = lds + ldsOff + (R0 << 7) + (wv << 10);
    __builtin_amdgcn_global_load_lds((const __attribute__((address_space(1))) void*)ga,
                                     (__attribute__((address_space(3))) void*)la, 16, 0, 0);
  };
#define RDA(o, mi, ks) (*(const bf16x8*)(lds + (o) + (wm << 14) + ((mi) << 11) + aoff##ks))
#define RDB(o, ni, ks) (*(const bf16x8*)(lds + (o) + 32768 + (wn << 13) + ((ni) << 11) + aoff##ks))
#define MFMA_PAIR(mi0, A0, A1)                                                              \
  __builtin_amdgcn_s_setprio(1);                                                            \
  _Pragma("unroll") for (int ks = 0; ks < 2; ++ks) {                                        \
    _Pragma("unroll") for (int ni = 0; ni < 4; ++ni) {                                      \
      acc[mi0][ni] = __builtin_amdgcn_mfma_f32_16x16x32_bf16(A0[ks], b[ni][ks], acc[mi0][ni], 0, 0, 0);          \
      acc[mi0 + 1][ni] = __builtin_amdgcn_mfma_f32_16x16x32_bf16(A1[ks], b[ni][ks], acc[mi0 + 1][ni], 0, 0, 0);  \
    }                                                                                       \
  }                                                                                         \
  __builtin_amdgcn_s_setprio(0)

  STAGE(BPTR(0), 0, 32768);   STAGE(BPTR(0), 64, 32768);
  STAGE(BPTR(0), 128, 32768); STAGE(BPTR(0), 192, 32768);
  STAGE(APTR(0), 0, 0);       STAGE(APTR(0), 64, 0);
  STAGE(APTR(0), 128, 0);     STAGE(APTR(0), 192, 0);
  STAGE(BPTR(1), 0, 65536 + 32768);   STAGE(BPTR(1), 64, 65536 + 32768);
  STAGE(BPTR(1), 128, 65536 + 32768); STAGE(BPTR(1), 192, 65536 + 32768);
  STAGE(APTR(1), 0, 65536);           STAGE(APTR(1), 128, 65536);
  WAITV6();
  BARRIER();

  for (int t = 0; t < 16; ++t) {
    int o = (t & 1) << 16;
    int on = o ^ 65536;
    int t1 = (t + 1 < 16) ? t + 1 : 15;
    int t2 = (t + 2 < 16) ? t + 2 : 15;
    const unsigned short* a1p = APTR(t1);
    const unsigned short* a2p = APTR(t2);
    const unsigned short* b2p = BPTR(t2);

    bf16x8 b[4][2], aA[2][2];
#pragma unroll
    for (int ni = 0; ni < 4; ++ni) { b[ni][0] = RDB(o, ni, 0); b[ni][1] = RDB(o, ni, 1); }
    aA[0][0] = RDA(o, 0, 0); aA[0][1] = RDA(o, 0, 1);
    aA[1][0] = RDA(o, 1, 0); aA[1][1] = RDA(o, 1, 1);
    STAGE(a1p, 64, on); STAGE(a1p, 192, on);
    BARRIER();
    MFMA_PAIR(0, aA[0], aA[1]);
    BARRIER();

    aA[0][0] = RDA(o, 2, 0); aA[0][1] = RDA(o, 2, 1);
    aA[1][0] = RDA(o, 3, 0); aA[1][1] = RDA(o, 3, 1);
    STAGE(b2p, 0, o + 32768); STAGE(b2p, 64, o + 32768);
    BARRIER();
    MFMA_PAIR(2, aA[0], aA[1]);
    BARRIER();

    aA[0][0] = RDA(o, 4, 0); aA[0][1] = RDA(o, 4, 1);
    aA[1][0] = RDA(o, 5, 0); aA[1][1] = RDA(o, 5, 1);
    STAGE(b2p, 128, o + 32768); STAGE(b2p, 192, o + 32768);
    BARRIER();
    MFMA_PAIR(4, aA[0], aA[1]);
    BARRIER();

    aA[0][0] = RDA(o, 6, 0); aA[0][1] = RDA(o, 6, 1);
    aA[1][0] = RDA(o, 7, 0); aA[1][1] = RDA(o, 7, 1);
    STAGE(a2p, 0, o); STAGE(a2p, 128, o);
    BARRIER();
    MFMA_PAIR(6, aA[0], aA[1]);
    WAITV6();
    BARRIER();
  }
#undef RDA
#undef RDB
#undef MFMA_PAIR

  // epilogue: bf16 C[(b*512+col)*4096 + t], ushort4 (8B) per lane
#pragma unroll
  for (int mi = 0; mi < 8; ++mi) {
    int mrow0 = m0 + (wm << 7) + (mi << 4) + ((lane >> 4) << 2);
    int bq_ = mrow0 >> 12;
    int t0 = mrow0 & 4095;
#pragma unroll
    for (int ni = 0; ni < 4; ++ni) {
      int col = n0 + (wn << 6) + (ni << 4) + (lane & 15);
      float bv = bias[col];
      f32x4 v = acc[mi][ni];
      ushort4 hv;
      hv.x = f2bf(v.x + bv); hv.y = f2bf(v.y + bv);
      hv.z = f2bf(v.z + bv); hv.w = f2bf(v.w + bv);
      *(ushort4*)&C[((size_t)(bq_ * 512 + col)) * 4096 + t0] = hv;
    }
  }
}

// ---------------- generic GEMM: V (mode 1, bf16 out) and OUT (mode 2, f32 out) ---------
// Double-buffered LDS + stage-next-before-compute (T3-min 2-phase).
__global__ __launch_bounds__(256, 2)
void gemm_bf16(const unsigned short* __restrict__ Ahi,
               const unsigned short* __restrict__ Bhi,
               const float* __restrict__ bias, float* __restrict__ Cf,
               unsigned short* __restrict__ Ch, int mode) {
  __shared__ short As[2][128 * 64];
  __shared__ short Bs[2][128 * 64];
  int bx = xcd_swz(blockIdx.x, 64);  // 512 wgs
  int bm = bx >> 2, bn = bx & 3;
  int m0 = bm << 7, n0 = bn << 7;
  int tid = threadIdx.x;
  int lane = tid & 63, wv = tid >> 6;
  int wm = wv >> 1, wn = wv & 1;

  const f32x4 zz = {0.f, 0.f, 0.f, 0.f};
  f32x4 acc[4][4];
#pragma unroll
  for (int i = 0; i < 4; ++i)
#pragma unroll
    for (int j = 0; j < 4; ++j) acc[i][j] = zz;

  int srow = tid >> 3;
  int sk = (tid & 7) << 3;
  auto STAGE = [&](int ks, int buf) {
    int kb = ks << 6;
#pragma unroll
    for (int i = 0; i < 4; ++i) {
      int r = (i << 5) + srow;
      const unsigned short* ga = Ahi + (size_t)(m0 + r) * 512 + kb + sk;
      const unsigned short* gb = Bhi + (size_t)(n0 + r) * 512 + kb + sk;
      char* la = (char*)As[buf] + (i << 12) + (wv << 10);
      char* lb = (char*)Bs[buf] + (i << 12) + (wv << 10);
      __builtin_amdgcn_global_load_lds((const __attribute__((address_space(1))) void*)ga,
                                       (__attribute__((address_space(3))) void*)la, 16, 0, 0);
      __builtin_amdgcn_global_load_lds((const __attribute__((address_space(1))) void*)gb,
                                       (__attribute__((address_space(3))) void*)lb, 16, 0, 0);
    }
  };

  STAGE(0, 0);
  __syncthreads();
  for (int ks = 0; ks < 8; ++ks) {
    int buf = ks & 1;
    if (ks < 7) STAGE(ks + 1, buf ^ 1);
#pragma unroll
    for (int kk = 0; kk < 2; ++kk) {
      bf16x8 af[4], bfr[4];
      int krd = (kk << 5) + ((lane >> 4) << 3);
#pragma unroll
      for (int mi = 0; mi < 4; ++mi)
        af[mi] = *(const bf16x8*)&As[buf][((wm << 6) + (mi << 4) + (lane & 15)) * 64 + krd];
#pragma unroll
      for (int ni = 0; ni < 4; ++ni)
        bfr[ni] = *(const bf16x8*)&Bs[buf][((wn << 6) + (ni << 4) + (lane & 15)) * 64 + krd];
#pragma unroll
      for (int mi = 0; mi < 4; ++mi)
#pragma unroll
        for (int ni = 0; ni < 4; ++ni)
          acc[mi][ni] = __builtin_amdgcn_mfma_f32_16x16x32_bf16(af[mi], bfr[ni], acc[mi][ni], 0, 0, 0);
    }
    __syncthreads();  // drains ks+1 loads; protects buf reuse at ks+2
  }

#pragma unroll
  for (int mi = 0; mi < 4; ++mi) {
    int mrow0 = m0 + (wm << 6) + (mi << 4) + ((lane >> 4) << 2);
    int bq_ = mrow0 >> 12;
    int t0 = mrow0 & 4095;
#pragma unroll
    for (int ni = 0; ni < 4; ++ni) {
      int col = n0 + (wn << 6) + (ni << 4) + (lane & 15);
      float bv = bias[col];
      f32x4 v = acc[mi][ni];
      v.x += bv; v.y += bv; v.z += bv; v.w += bv;
      if (mode == 1) {
        // V layout (bf16): Ch[((b*8+h)*4096+t)*64 + d]
        size_t base = (size_t)(bq_ * 8 + (col >> 6)) * 4096;
        int d = col & 63;
        Ch[(base + t0 + 0) * 64 + d] = f2bf(v.x);
        Ch[(base + t0 + 1) * 64 + d] = f2bf(v.y);
        Ch[(base + t0 + 2) * 64 + d] = f2bf(v.z);
        Ch[(base + t0 + 3) * 64 + d] = f2bf(v.w);
      } else {
        Cf[(size_t)(mrow0 + 0) * 512 + col] = v.x;
        Cf[(size_t)(mrow0 + 1) * 512 + col] = v.y;
        Cf[(size_t)(mrow0 + 2) * 512 + col] = v.z;
        Cf[(size_t)(mrow0 + 3) * 512 + col] = v.w;
      }
    }
  }
}

// ---------------- FFT: radix-16 superstages (stage pairs fused in registers) ----------
__device__ __forceinline__ void r4(float& x0r, float& x0i, float& x1r, float& x1i,
                                   float& x2r, float& x2i, float& x3r, float& x3i,
                                   float2 w1, float2 w2, float2 w3) {
  float Ar = x0r + x2r, Ai = x0i + x2i;
  float Br = x0r - x2r, Bi = x0i - x2i;
  float Cr = x1r + x3r, Ci = x1i + x3i;
  float Dr = x1i - x3i, Di = x3r - x1r;  // -i*(x1-x3)
  x0r = Ar + Cr; x0i = Ai + Ci;
  float tr = Br + Dr, ti = Bi + Di;
  x1r = tr * w1.x - ti * w1.y; x1i = tr * w1.y + ti * w1.x;
  tr = Ar - Cr; ti = Ai - Ci;
  x2r = tr * w2.x - ti * w2.y; x2i = tr * w2.y + ti * w2.x;
  tr = Br - Dr; ti = Bi - Di;
  x3r = tr * w3.x - ti * w3.y; x3i = tr * w3.y + ti * w3.x;
}

__device__ __forceinline__ void fft16_superstages(float* re, float* im,
                                                  const float2* __restrict__ TW,
                                                  int u, bool active) {
#pragma unroll
  for (int ss = 0; ss < 3; ++ss) {
    const int lm = 10 - 4 * ss;      // 10, 6, 2
    const int m = 1 << lm;
    const int m4 = m >> 2;
    const int stw = 1 << (4 * ss);   // 1, 16, 256
    const int stw4 = stw << 2;
    if (active) {
      int jj = u & (m4 - 1);
      int g = u >> (lm - 2);
      int base = (g << (lm + 2)) + jj;
      float xr[4][4], xi[4][4];
#pragma unroll
      for (int a = 0; a < 4; ++a)
#pragma unroll
        for (int b = 0; b < 4; ++b) {
          int p = IDX(base + a * m + b * m4);
          xr[a][b] = re[p]; xi[a][b] = im[p];
        }
#pragma unroll
      for (int b = 0; b < 4; ++b) {
        int j1 = (b * m4 + jj) * stw;
        float2 w1 = TW[j1], w2 = TW[2 * j1], w3 = TW[3 * j1];
        r4(xr[0][b], xi[0][b], xr[1][b], xi[1][b], xr[2][b], xi[2][b], xr[3][b], xi[3][b], w1, w2, w3);
      }
      {
        int j2 = jj * stw4;
        float2 v1 = TW[j2], v2 = TW[2 * j2], v3 = TW[3 * j2];
#pragma unroll
        for (int a = 0; a < 4; ++a)
          r4(xr[a][0], xi[a][0], xr[a][1], xi[a][1], xr[a][2], xi[a][2], xr[a][3], xi[a][3], v1, v2, v3);
      }
#pragma unroll
      for (int a = 0; a < 4; ++a)
#pragma unroll
        for (int b = 0; b < 4; ++b) {
          int p = IDX(base + a * m + b * m4);
          re[p] = xr[a][b]; im[p] = xi[a][b];
        }
    }
    __syncthreads();
  }
}

// Packed FFT of z = q + i*k per (b,h,d) with bf16 Q/K inputs; one wg (512 thr)
// handles 4 d's as 2 rounds of 2 CONCURRENT FFTs (256 units each, wave-uniform).
// 512 wgs = 32 bh x 16 parts; NO atomics.
__global__ __launch_bounds__(512, 2)
void fft_corr(const unsigned short* __restrict__ QT, const unsigned short* __restrict__ KT,
              const float2* __restrict__ TW, float* __restrict__ PpartRe,
              float* __restrict__ PpartIm) {
  __shared__ float re[2][LDSN];
  __shared__ float im[2][LDSN];
  int wg = blockIdx.x;
  int bh = wg >> 4;
  int d0 = (wg & 15) << 2;
  int tid = threadIdx.x;
  const unsigned short* qb = QT + (size_t)bh * 64 * 4096;
  const unsigned short* kb = KT + (size_t)bh * 64 * 4096;
  float accR[8], accI[8];
#pragma unroll
  for (int j = 0; j < 8; ++j) { accR[j] = 0.f; accI[j] = 0.f; }
  for (int rr = 0; rr < 2; ++rr) {
    if (rr) __syncthreads();  // prior extraction reads done
#pragma unroll
    for (int ff = 0; ff < 2; ++ff) {
      const unsigned short* q8 = qb + (size_t)(d0 + 2 * rr + ff) * 4096;
      const unsigned short* k8 = kb + (size_t)(d0 + 2 * rr + ff) * 4096;
      uint4 qraw = *(const uint4*)(q8 + ((size_t)tid << 3));  // 8 bf16
      uint4 kraw = *(const uint4*)(k8 + ((size_t)tid << 3));
      int e = tid << 3;
      re[ff][IDX(e + 0)] = bf2f((unsigned short)(qraw.x & 0xFFFF));
      re[ff][IDX(e + 1)] = bf2f((unsigned short)(qraw.x >> 16));
      re[ff][IDX(e + 2)] = bf2f((unsigned short)(qraw.y & 0xFFFF));
      re[ff][IDX(e + 3)] = bf2f((unsigned short)(qraw.y >> 16));
      re[ff][IDX(e + 4)] = bf2f((unsigned short)(qraw.z & 0xFFFF));
      re[ff][IDX(e + 5)] = bf2f((unsigned short)(qraw.z >> 16));
      re[ff][IDX(e + 6)] = bf2f((unsigned short)(qraw.w & 0xFFFF));
      re[ff][IDX(e + 7)] = bf2f((unsigned short)(qraw.w >> 16));
      im[ff][IDX(e + 0)] = bf2f((unsigned short)(kraw.x & 0xFFFF));
      im[ff][IDX(e + 1)] = bf2f((unsigned short)(kraw.x >> 16));
      im[ff][IDX(e + 2)] = bf2f((unsigned short)(kraw.y & 0xFFFF));
      im[ff][IDX(e + 3)] = bf2f((unsigned short)(kraw.y >> 16));
      im[ff][IDX(e + 4)] = bf2f((unsigned short)(kraw.z & 0xFFFF));
      im[ff][IDX(e + 5)] = bf2f((unsigned short)(kraw.z >> 16));
      im[ff][IDX(e + 6)] = bf2f((unsigned short)(kraw.w & 0xFFFF));
      im[ff][IDX(e + 7)] = bf2f((unsigned short)(kraw.w >> 16));
    }
    __syncthreads();
    // wave-uniform FFT split: waves 0-3 -> fft 0, waves 4-7 -> fft 1
    fft16_superstages(re[tid >> 8], im[tid >> 8], TW, tid & 255, true);
#pragma unroll
    for (int ff = 0; ff < 2; ++ff) {
#pragma unroll
      for (int j = 0; j < 8; ++j) {
        int p = tid + (j << 9);
        int f = rev4_12(p);
        int fn = (4096 - f) & 4095;
        int pn = rev4_12(fn);
        float zr = re[ff][IDX(p)], zi = im[ff][IDX(p)];
        float wr = re[ff][IDX(pn)], wi = im[ff][IDX(pn)];
        float qre = 0.5f * (zr + wr), qim = 0.5f * (zi - wi);
        float kre = 0.5f * (zi + wi), kim = 0.5f * (wr - zr);
        accR[j] += qre * kre + qim * kim;   // Re(Qf*conj(Kf))
        accI[j] += qim * kre - qre * kim;   // Im(Qf*conj(Kf))
      }
    }
  }
  float* pR = PpartRe + (size_t)wg * 4096;
  float* pI = PpartIm + (size_t)wg * 4096;
#pragma unroll
  for (int j = 0; j < 8; ++j) {
    int p = tid + (j << 9);
    pR[p] = accR[j];
    pI[p] = accI[j];
  }
}

// Reduce 16 partials per (b,h) -> Psum, float4. Grid 128 = 32 bh x 4 chunks of 1024 p.
__global__ void reduce_p(const float* __restrict__ PpartRe, const float* __restrict__ PpartIm,
                         float* __restrict__ PsumRe, float* __restrict__ PsumIm) {
  int wg = blockIdx.x;
  int bh = wg >> 2;
  int p4 = ((wg & 3) << 8) + threadIdx.x;  // float4 index 0..1023
  const float4* bR = (const float4*)(PpartRe + (size_t)bh * 16 * 4096);
  const float4* bI = (const float4*)(PpartIm + (size_t)bh * 16 * 4096);
  float4 sr = make_float4(0.f, 0.f, 0.f, 0.f);
  float4 si = make_float4(0.f, 0.f, 0.f, 0.f);
#pragma unroll
  for (int part = 0; part < 16; ++part) {
    float4 a = bR[part * 1024 + p4];
    float4 b = bI[part * 1024 + p4];
    sr.x += a.x; sr.y += a.y; sr.z += a.z; sr.w += a.w;
    si.x += b.x; si.y += b.y; si.z += b.z; si.w += b.w;
  }
  ((float4*)(PsumRe + (size_t)bh * 4096))[p4] = sr;
  ((float4*)(PsumIm + (size_t)bh * 4096))[p4] = si;
}

// Inverse FFT via conj + forward DIF (radix-16); corr(tau=rev4(p)) = re[p]/(4096*64).
// Single-pass top-8: pack (value,tau) -> ordered u64 key; per-thread sort-8;
// 6-level shfl_xor butterfly with Batcher half-cleaner; final 8-list serial merge.
__global__ __launch_bounds__(512, 1)
void ifft_topk(const float* __restrict__ PsumRe, const float* __restrict__ PsumIm,
               const float2* __restrict__ TW, float* __restrict__ attnW, int* __restrict__ delays) {
  __shared__ float re[LDSN];
  __shared__ float im[LDSN];
  __shared__ unsigned long long sh[8][8];
  int bh = blockIdx.x, tid = threadIdx.x;
  int lane = tid & 63, wv = tid >> 6;
  const float4* pr4 = (const float4*)(PsumRe + (size_t)bh * 4096);
  const float4* pi4 = (const float4*)(PsumIm + (size_t)bh * 4096);
#pragma unroll
  for (int i = 0; i < 2; ++i) {
    int e4 = tid + (i << 9);
    float4 a = pr4[e4], b = pi4[e4];
    int fb = rev4_12(e4 << 2);  // rev4 of (e4*4 + j) = fb | (j<<10)
    re[IDX(fb + 0 * 1024)] = a.x; im[IDX(fb + 0 * 1024)] = -b.x;
    re[IDX(fb + 1 * 1024)] = a.y; im[IDX(fb + 1 * 1024)] = -b.y;
    re[IDX(fb + 2 * 1024)] = a.z; im[IDX(fb + 2 * 1024)] = -b.z;
    re[IDX(fb + 3 * 1024)] = a.w; im[IDX(fb + 3 * 1024)] = -b.w;
  }
  __syncthreads();
  fft16_superstages(re, im, TW, tid & 255, tid < 256);

  // build per-thread desc-sorted 8 keys (value desc, tau asc on ties)
  unsigned long long k[8];
#pragma unroll
  for (int i = 0; i < 8; ++i) {
    int p = tid + (i << 9);
    float v = re[IDX(p)];
    int tau = rev4_12(p);
    unsigned u = __float_as_uint(v);
    unsigned s = u ^ (unsigned)(((int)u >> 31) | 0x80000000);  // order-preserving map
    k[i] = ((unsigned long long)s << 12) | (unsigned)(4095 - tau);
  }
#define CSWAP(a, b) { if (k[a] < k[b]) { unsigned long long t_ = k[a]; k[a] = k[b]; k[b] = t_; } }
  // insertion network (28 comparators), descending
#pragma unroll
  for (int i = 1; i < 8; ++i)
#pragma unroll
    for (int j = 8 - 1; j >= 1; --j)
      if (j <= i) CSWAP(j - 1, j);
  // butterfly merge across 64 lanes: keep top-8 of pairwise unions
#pragma unroll
  for (int off = 1; off < 64; off <<= 1) {
    unsigned long long b[8];
#pragma unroll
    for (int i = 0; i < 8; ++i)
      b[i] = (unsigned long long)__shfl_xor((long long)k[i], off);
#pragma unroll
    for (int i = 0; i < 8; ++i) {
      unsigned long long m = b[7 - i];        // half-cleaner: max(A[i], B[7-i])
      k[i] = (k[i] > m) ? k[i] : m;
    }
    // bitonic clean (descending), distances 4, 2, 1
#pragma unroll
    for (int d = 4; d > 0; d >>= 1)
#pragma unroll
      for (int i = 0; i < 8; ++i)
        if ((i & d) == 0 && (i ^ d) < 8) CSWAP(i, i + d);
  }
#undef CSWAP
  if (lane == 0) {
#pragma unroll
    for (int i = 0; i < 8; ++i) sh[wv][i] = k[i];
  }
  __syncthreads();
  if (tid == 0) {
    const float SC = 1.0f / 262144.0f;  // 1/(L*Dh)
    int idx[8] = {0, 0, 0, 0, 0, 0, 0, 0};
    float topv[8]; int topi[8];
#pragma unroll
    for (int pass = 0; pass < 8; ++pass) {
      int bw = 0;
      unsigned long long bk = sh[0][idx[0]];
#pragma unroll
      for (int w = 1; w < 8; ++w) {
        unsigned long long c = sh[w][idx[w]];
        if (c > bk) { bk = c; bw = w; }
      }
      idx[bw]++;
      unsigned s = (unsigned)(bk >> 12);
      unsigned u = (s & 0x80000000u) ? (s ^ 0x80000000u) : ~s;
      topv[pass] = __uint_as_float(u) * SC;
      topi[pass] = 4095 - (int)(bk & 4095u);
    }
    float mx = topv[0];  // pass 0 = global max
    float ex[8], ssum = 0.f;
    for (int q = 0; q < 8; ++q) { ex[q] = expf(topv[q] - mx); ssum += ex[q]; }
    float inv = 1.0f / ssum;
    for (int q = 0; q < 8; ++q) {
      attnW[bh * 8 + q] = ex[q] * inv;
      delays[bh * 8 + q] = topi[q];
    }
  }
}

// out[b,h,t,:] = sum_k attn_k * V[b,h,(t-d_k)%L,:] (V bf16); write bf16 A for OUT gemm.
// Grid 4096 = 32 bh x 128 t-chunks of 32; thread handles 8 d's (16B loads/stores).
__global__ void gather_av(const unsigned short* __restrict__ Vh, const float* __restrict__ attnW,
                          const int* __restrict__ delays, unsigned short* __restrict__ Ahi) {
  int blk = blockIdx.x;
  int bh = blk >> 7, tb = blk & 127;
  int tid = threadIdx.x;
  int tt = tid >> 3, d8 = tid & 7;
  int t = (tb << 5) + tt;
  const unsigned short* Vb = Vh + (size_t)bh * 4096 * 64 + (d8 << 3);
  float w[8]; int dl[8];
#pragma unroll
  for (int kk = 0; kk < 8; ++kk) { w[kk] = attnW[bh * 8 + kk]; dl[kk] = delays[bh * 8 + kk]; }
  float a0 = 0.f, a1 = 0.f, a2 = 0.f, a3 = 0.f, a4 = 0.f, a5 = 0.f, a6 = 0.f, a7 = 0.f;
#pragma unroll
  for (int kk = 0; kk < 8; ++kk) {
    int row = (t - dl[kk]) & 4095;
    uint4 raw = *(const uint4*)(Vb + row * 64);
    float wk = w[kk];
    a0 += wk * bf2f((unsigned short)(raw.x & 0xFFFF));
    a1 += wk * bf2f((unsigned short)(raw.x >> 16));
    a2 += wk * bf2f((unsigned short)(raw.y & 0xFFFF));
    a3 += wk * bf2f((unsigned short)(raw.y >> 16));
    a4 += wk * bf2f((unsigned short)(raw.z & 0xFFFF));
    a5 += wk * bf2f((unsigned short)(raw.z >> 16));
    a6 += wk * bf2f((unsigned short)(raw.w & 0xFFFF));
    a7 += wk * bf2f((unsigned short)(raw.w >> 16));
  }
  int b = bh >> 3, h = bh & 7;
  size_t o = ((size_t)((b << 12) + t)) * 512 + (h << 6) + (d8 << 3);
  uint4 out;
  out.x = (unsigned)f2bf(a0) | ((unsigned)f2bf(a1) << 16);
  out.y = (unsigned)f2bf(a2) | ((unsigned)f2bf(a3) << 16);
  out.z = (unsigned)f2bf(a4) | ((unsigned)f2bf(a5) << 16);
  out.w = (unsigned)f2bf(a6) | ((unsigned)f2bf(a7) << 16);
  *(uint4*)(Ahi + o) = out;
}

// ---------------- orchestration ----------------
extern "C" void kernel_launch(void* const* d_in, const int* in_sizes, int n_in,
                              void* d_out, int out_size, void* d_ws, size_t ws_size,
                              hipStream_t stream) {
  (void)in_sizes; (void)n_in; (void)out_size; (void)ws_size;
  const float* x_q = (const float*)d_in[0];
  const float* x_kv = (const float*)d_in[1];
  const float* Wq = (const float*)d_in[2];
  const float* bq = (const float*)d_in[3];
  const float* Wk = (const float*)d_in[4];
  const float* bk = (const float*)d_in[5];
  const float* Wv = (const float*)d_in[6];
  const float* bv = (const float*)d_in[7];
  const float* Wo = (const float*)d_in[8];
  const float* bo = (const float*)d_in[9];
  float* out = (float*)d_out;
  char* ws = (char*)d_ws;

  // workspace layout (~137.1 MiB)
  // 0-16    AqHi          -> Vbuf16 (bf16, after qk_gemm8)
  // 36-52   AkvHi         -> PpartRe (8 MB, after v_gemm) -> Aattn (after reduce_p)
  // 52-68   (PpartIm 8 MB)
  // 68-72   WTb (8 x 512x512 bf16)
  // 72-88   QT (bf16 16 MB) -> PsumRe/PsumIm (after fft_corr)
  // 104-120 KT (bf16 16 MB)
  // 137+    attnW, delays, TW
  unsigned short* AqHi  = (unsigned short*)(ws + 0 * MiB);
  unsigned short* Vbuf16 = (unsigned short*)(ws + 0 * MiB);  // after qk_gemm8
  unsigned short* AkvHi = (unsigned short*)(ws + 36 * MiB);
  float* PpartRe = (float*)(ws + 36 * MiB);                  // after v_gemm
  float* PpartIm = (float*)(ws + 52 * MiB);
  unsigned short* Aattn = (unsigned short*)(ws + 36 * MiB);  // after reduce_p
  unsigned short* WTb   = (unsigned short*)(ws + 68 * MiB);
  unsigned short* QT    = (unsigned short*)(ws + 72 * MiB);
  unsigned short* KT    = (unsigned short*)(ws + 104 * MiB);
  float* PsumRe = (float*)(ws + 72 * MiB);
  float* PsumIm = (float*)(ws + 73 * MiB);
  float* attnW = (float*)(ws + 137 * MiB);
  int*   delays = (int*)(ws + 137 * MiB + 4096);
  float2* TW   = (float2*)(ws + 137 * MiB + 8192);

  int n4 = (16384 * 512) / 4;
  prep_all<<<dim3(16652), dim3(256), 0, stream>>>(x_q, x_kv, AqHi, AkvHi,
                                                  Wq, Wk, Wv, Wo, WTb, TW, n4);

  // Q and K projections fused, 256^2 8-phase bf16x2 (256 wgs x 512 thr).
  qk_gemm8<<<dim3(256), dim3(512), 0, stream>>>(AqHi, AkvHi, WTb, bq, bk, QT, KT);
  gemm_bf16<<<dim3(512), dim3(256), 0, stream>>>(AkvHi, WTb + 4 * 262144, bv, nullptr, Vbuf16, 1);

  fft_corr<<<dim3(512), dim3(512), 0, stream>>>(QT, KT, TW, PpartRe, PpartIm);
  reduce_p<<<dim3(128), dim3(256), 0, stream>>>(PpartRe, PpartIm, PsumRe, PsumIm);
  ifft_topk<<<dim3(32), dim3(512), 0, stream>>>(PsumRe, PsumIm, TW, attnW, delays);
  gather_av<<<dim3(4096), dim3(256), 0, stream>>>(Vbuf16, attnW, delays, Aattn);

  // out = gathered @ Wo + bo (plain bf16 -> f32 out)
  gemm_bf16<<<dim3(512), dim3(256), 0, stream>>>(Aattn, WTb + 6 * 262144, bo, out, nullptr, 2);
}